// Round 1
// baseline (848.696 us; speedup 1.0000x reference)
//
#include <hip/hip_runtime.h>
#include <hip/hip_bf16.h>

// Problem constants
#define TT 12608          // 4*B*N rows of hs
#define NC 3152           // B*N cache rows (= 16*197)
#define DIM 768
#define NPOS 197
#define NH 12
#define HD 64
#define MROWS 15760       // NC + TT
#define FB_N 64           // 4*B
#define FF 3072
#define INNER_D 64

typedef __bf16 bf16x8 __attribute__((ext_vector_type(8)));
typedef float f32x4 __attribute__((ext_vector_type(4)));

__device__ inline float wred_sum(float v){
  #pragma unroll
  for (int o = 32; o > 0; o >>= 1) v += __shfl_down(v, o, 64);
  return v;
}
__device__ inline float wred_max(float v){
  #pragma unroll
  for (int o = 32; o > 0; o >>= 1) v = fmaxf(v, __shfl_down(v, o, 64));
  return v;
}

// ---------------------------------------------------------------------------
// K1: normalize reuse_map to uint8 regardless of harness dtype (int32/int8/f32).
// Detection: within first 12608 bytes, int32 layout has all bytes at off%4!=0
// zero; f32 layout has all bytes at off%4==0 zero; int8/bool has both nonzero.
__global__ void mask_norm_kernel(const unsigned char* __restrict__ rm,
                                 unsigned char* __restrict__ mask)
{
  __shared__ int flagA, flagB;
  if (threadIdx.x == 0) { flagA = 0; flagB = 0; }
  __syncthreads();
  int la = 0, lb = 0;
  for (int i = threadIdx.x; i < TT; i += blockDim.x) {
    unsigned char v = rm[i];
    if (v) { if (i & 3) la = 1; else lb = 1; }
  }
  if (la) atomicOr(&flagA, 1);
  if (lb) atomicOr(&flagB, 1);
  __syncthreads();
  int mode = (!flagA) ? 0 : (flagB ? 1 : 2); // 0=int32, 1=byte, 2=f32
  for (int i = threadIdx.x; i < TT; i += blockDim.x) {
    unsigned char m;
    if (mode == 0)      m = ((const int*)rm)[i] != 0;
    else if (mode == 1) m = rm[i] != 0;
    else                m = ((const float*)rm)[i] != 0.0f;
    mask[i] = m;
  }
}

// ---------------------------------------------------------------------------
// K2/K9: row LayerNorm over 768 cols. BF=true -> bf16 out, else f32.
template<bool BF>
__launch_bounds__(256)
__global__ void ln_kernel(const float* __restrict__ in, const float* __restrict__ g,
                          const float* __restrict__ b, void* __restrict__ outp)
{
  int row = blockIdx.x, t = threadIdx.x;
  const float* x = in + (size_t)row * DIM;
  float v0 = x[t], v1 = x[t + 256], v2 = x[t + 512];
  float s = wred_sum(v0 + v1 + v2);
  float q = wred_sum(v0*v0 + v1*v1 + v2*v2);
  __shared__ float red[8];
  int wv = t >> 6, ln = t & 63;
  if (ln == 0) { red[wv] = s; red[4 + wv] = q; }
  __syncthreads();
  float mean = (red[0]+red[1]+red[2]+red[3]) * (1.f/DIM);
  float var  = (red[4]+red[5]+red[6]+red[7]) * (1.f/DIM) - mean*mean;
  float rr = rsqrtf(var + 1e-5f);
  #pragma unroll
  for (int j = 0; j < 3; j++) {
    int c = t + j*256;
    float v = (j==0) ? v0 : (j==1) ? v1 : v2;
    float o = (v - mean) * rr * g[c] + b[c];
    if (BF) ((__bf16*)outp)[(size_t)row*DIM + c] = (__bf16)o;
    else    ((float*)outp)[(size_t)row*DIM + c] = o;
  }
}

// ---------------------------------------------------------------------------
// K3: transpose wk/wv (768x768 f32) -> bf16 B^T layout for MFMA B-fragments.
__global__ void transpose_w_kernel(const float* __restrict__ wk, const float* __restrict__ wv,
                                   __bf16* __restrict__ wkT, __bf16* __restrict__ wvT)
{
  const float* src = blockIdx.z ? wv : wk;
  __bf16* dst = blockIdx.z ? wvT : wkT;
  __shared__ float tile[32][33];
  int bx = blockIdx.x, by = blockIdx.y;
  int tx = threadIdx.x, ty = threadIdx.y;
  #pragma unroll
  for (int i = 0; i < 32; i += 8)
    tile[ty + i][tx] = src[(size_t)(by*32 + ty + i) * DIM + bx*32 + tx];
  __syncthreads();
  #pragma unroll
  for (int i = 0; i < 32; i += 8)
    dst[(size_t)(bx*32 + ty + i) * DIM + by*32 + tx] = (__bf16)tile[tx][ty + i];
}

// ---------------------------------------------------------------------------
// K4: k_new = x@wk + bk, v_new = x@wv + bv  via bf16 MFMA 16x16x32.
// Tile 64x64, 4 waves (each 16 rows x 64 cols), K-step 32, bf16 outputs.
__launch_bounds__(256)
__global__ void kv_gemm_kernel(const __bf16* __restrict__ xbf, const __bf16* __restrict__ wkT,
                               const __bf16* __restrict__ wvT, const float* __restrict__ bk,
                               const float* __restrict__ bv, __bf16* __restrict__ k_new,
                               __bf16* __restrict__ v_new)
{
  __shared__ __align__(16) __bf16 As[64][40];   // +8 pad: conflict-free b128 frag reads
  __shared__ __align__(16) __bf16 Bks[64][40];
  __shared__ __align__(16) __bf16 Bvs[64][40];
  int t = threadIdx.x;
  int wv = t >> 6, lane = t & 63;
  int fr = lane & 15, fg = lane >> 4;
  int row0 = blockIdx.x * 64, col0 = blockIdx.y * 64;
  int lr = t >> 2, lk = (t & 3) << 3;
  const __bf16* aS = xbf + (size_t)(row0 + lr) * DIM + lk;
  const __bf16* kS = wkT + (size_t)(col0 + lr) * DIM + lk;
  const __bf16* vS = wvT + (size_t)(col0 + lr) * DIM + lk;
  f32x4 zero = {0.f, 0.f, 0.f, 0.f};
  f32x4 aK[4], aV[4];
  #pragma unroll
  for (int i = 0; i < 4; i++) { aK[i] = zero; aV[i] = zero; }
  for (int k0 = 0; k0 < DIM; k0 += 32) {
    *(uint4*)&As[lr][lk]  = *(const uint4*)(aS + k0);
    *(uint4*)&Bks[lr][lk] = *(const uint4*)(kS + k0);
    *(uint4*)&Bvs[lr][lk] = *(const uint4*)(vS + k0);
    __syncthreads();
    bf16x8 af = *(const bf16x8*)&As[wv*16 + fr][fg << 3];
    #pragma unroll
    for (int n = 0; n < 4; n++) {
      bf16x8 b1 = *(const bf16x8*)&Bks[n*16 + fr][fg << 3];
      bf16x8 b2 = *(const bf16x8*)&Bvs[n*16 + fr][fg << 3];
      aK[n] = __builtin_amdgcn_mfma_f32_16x16x32_bf16(af, b1, aK[n], 0, 0, 0);
      aV[n] = __builtin_amdgcn_mfma_f32_16x16x32_bf16(af, b2, aV[n], 0, 0, 0);
    }
    __syncthreads();
  }
  // C/D layout: col = lane&15, row = (lane>>4)*4 + reg  [verified m89/m91]
  int orow = row0 + wv*16 + fg*4;
  #pragma unroll
  for (int n = 0; n < 4; n++) {
    int col = col0 + n*16 + fr;
    float bkc = bk[col], bvc = bv[col];
    #pragma unroll
    for (int r = 0; r < 4; r++) {
      size_t off = (size_t)(orow + r) * DIM + col;
      k_new[off] = (__bf16)(aK[n][r] + bkc);
      v_new[off] = (__bf16)(aV[n][r] + bvc);
    }
  }
}

// ---------------------------------------------------------------------------
// K5: inner = gelu_tanh(diff_pre_proj @ rest_w1)   (12608 x 64)
__launch_bounds__(256)
__global__ void inner_kernel(const float* __restrict__ dpp, const float* __restrict__ w1,
                             float* __restrict__ inner)
{
  __shared__ __align__(16) float Xs[64][68];
  __shared__ __align__(16) float Ws[64][64];
  int t = threadIdx.x;
  int r = t >> 2, c0 = (t & 3) << 4;
  int row0 = blockIdx.x * 64;
  float acc[16];
  #pragma unroll
  for (int i = 0; i < 16; i++) acc[i] = 0.f;
  for (int k0 = 0; k0 < DIM; k0 += 64) {
    #pragma unroll
    for (int j = 0; j < 4; j++) {
      int v = t + 256*j;
      int rr = v >> 4, c4 = (v & 15) << 2;
      *(float4*)&Xs[rr][c4] = *(const float4*)&dpp[(size_t)(row0 + rr)*DIM + k0 + c4];
      *(float4*)&Ws[rr][c4] = *(const float4*)&w1[(size_t)(k0 + rr)*INNER_D + c4];
    }
    __syncthreads();
    for (int kk = 0; kk < 64; kk++) {
      float xv = Xs[r][kk];
      #pragma unroll
      for (int c = 0; c < 16; c++) acc[c] += xv * Ws[kk][c0 + c];
    }
    __syncthreads();
  }
  #pragma unroll
  for (int c = 0; c < 16; c++) {
    float x = acc[c];
    float u = 0.7978845608028654f * (x + 0.044715f * x * x * x);
    inner[(size_t)(row0 + r)*INNER_D + c0 + c] = 0.5f * x * (1.0f + tanhf(u));
  }
}

// ---------------------------------------------------------------------------
// K6: per (f,b): h_cls row (gather + masked hd) and q0 row (gather/compute q + masked qd, scaled)
__launch_bounds__(256)
__global__ void cls_prep_kernel(const float* __restrict__ hs, const float* __restrict__ hqkv,
                                const __bf16* __restrict__ xbf, const float* __restrict__ wq,
                                const float* __restrict__ bq, const float* __restrict__ w2,
                                const float* __restrict__ inner, const int* __restrict__ gidx,
                                const unsigned char* __restrict__ mask,
                                float* __restrict__ h_cls, float* __restrict__ q0s)
{
  int fb = blockIdx.x, t = threadIdx.x;
  int g0 = fb * NPOS;
  int idx = gidx[g0];
  int m = mask[g0];
  const float* q_cache = hqkv + (size_t)NC * DIM;   // hqkv[1]
  __shared__ float xrow[DIM];
  __shared__ float inn[INNER_D];
  if (t < INNER_D) inn[t] = inner[(size_t)g0 * INNER_D + t];
  bool fresh = idx >= NC;
  if (fresh) {
    for (int c = t; c < DIM; c += 256)
      xrow[c] = (float)xbf[(size_t)(idx - NC) * DIM + c];
  }
  __syncthreads();
  for (int c = t; c < DIM; c += 256) {
    float hv = fresh ? hs[(size_t)(idx - NC)*DIM + c] : hqkv[(size_t)idx*DIM + c];
    float qv;
    if (fresh) {
      float s = bq[c];
      for (int k = 0; k < DIM; k++) s += xrow[k] * wq[(size_t)k*DIM + c];
      qv = s;
    } else {
      qv = q_cache[(size_t)idx*DIM + c];
    }
    if (m) {
      float hd = 0.f, qd = 0.f;
      #pragma unroll 8
      for (int j = 0; j < INNER_D; j++) {
        float iv = inn[j];
        hd += iv * w2[(size_t)j*FF + c];
        qd += iv * w2[(size_t)j*FF + DIM + c];
      }
      hv += hd; qv += qd;
    }
    h_cls[(size_t)fb*DIM + c] = hv;
    q0s[(size_t)fb*DIM + c] = qv * 0.125f;   // SCALE = 64^-0.5
  }
}

// ---------------------------------------------------------------------------
// K7: CLS-row attention with low-rank diff folded in algebraically.
// block = (fb, h); scores over 197 keys; output 64 dims.
__launch_bounds__(256)
__global__ void attn_cls_kernel(const float* __restrict__ hqkv, const __bf16* __restrict__ k_new,
                                const __bf16* __restrict__ v_new, const float* __restrict__ w2,
                                const float* __restrict__ inner, const int* __restrict__ gidx,
                                const unsigned char* __restrict__ mask,
                                const float* __restrict__ q0s, float* __restrict__ pre_cls)
{
  int bid = blockIdx.x;
  int fb = bid / NH, h = bid % NH;
  int t = threadIdx.x;
  int lane = t & 63, wv = t >> 6;
  const float* k_cache = hqkv + (size_t)2 * NC * DIM;
  const float* v_cache = hqkv + (size_t)3 * NC * DIM;
  __shared__ float q0[HD], w2q[INNER_D], tj[INNER_D];
  __shared__ float p[200];
  __shared__ int sidx[200];
  __shared__ unsigned char smk[200];
  __shared__ float red[16];
  __shared__ float pacc[4][64];
  if (t < HD) q0[t] = q0s[(size_t)fb*DIM + h*HD + t];
  __syncthreads();
  if (t < INNER_D) {
    const float* wr = w2 + (size_t)t*FF + 2*DIM + h*HD;  // kd columns
    float s = 0.f;
    for (int d = 0; d < HD; d++) s += q0[d] * wr[d];
    w2q[t] = s;
  }
  __syncthreads();
  if (t < NPOS) {
    int g = fb * NPOS + t;
    int idx = gidx[g];
    unsigned char m = mask[g];
    sidx[t] = idx; smk[t] = m;
    float s = 0.f;
    if (idx >= NC) {
      const __bf16* kr = k_new + (size_t)(idx - NC)*DIM + h*HD;
      for (int d = 0; d < HD; d++) s += q0[d] * (float)kr[d];
    } else {
      const float* kr = k_cache + (size_t)idx*DIM + h*HD;
      for (int d = 0; d < HD; d++) s += q0[d] * kr[d];
    }
    if (m) {
      const float* ir = inner + (size_t)g * INNER_D;
      float s2 = 0.f;
      for (int j = 0; j < INNER_D; j++) s2 += ir[j] * w2q[j];
      s += s2;
    }
    p[t] = s;
  }
  __syncthreads();
  // softmax (unnormalized p, divide at the end)
  float lm = (t < NPOS) ? p[t] : -1e30f;
  lm = wred_max(lm);
  if (lane == 0) red[wv] = lm;
  __syncthreads();
  float mx = fmaxf(fmaxf(red[0], red[1]), fmaxf(red[2], red[3]));
  float lp = 0.f;
  if (t < NPOS) { lp = __expf(p[t] - mx); p[t] = lp; }
  float ls = wred_sum(lp);
  if (lane == 0) red[8 + wv] = ls;
  __syncthreads();
  float inv = 1.0f / (red[8] + red[9] + red[10] + red[11]);
  // t[j] = sum_n p_n * m_n * inner[g_n][j]
  float tp = 0.f;
  for (int n = wv; n < NPOS; n += 4) {
    if (smk[n]) tp += p[n] * inner[(size_t)(fb*NPOS + n)*INNER_D + lane];
  }
  pacc[wv][lane] = tp;
  __syncthreads();
  if (t < INNER_D) tj[t] = pacc[0][t] + pacc[1][t] + pacc[2][t] + pacc[3][t];
  __syncthreads();
  // gathered V accumulation
  float va = 0.f;
  for (int n = wv; n < NPOS; n += 4) {
    float pn = p[n];
    int idx = sidx[n];
    float vvv;
    if (idx >= NC) vvv = (float)v_new[(size_t)(idx - NC)*DIM + h*HD + lane];
    else           vvv = v_cache[(size_t)idx*DIM + h*HD + lane];
    va += pn * vvv;
  }
  __syncthreads();           // pacc reuse guard
  pacc[wv][lane] = va;
  __syncthreads();
  if (t < HD) {
    float o = pacc[0][t] + pacc[1][t] + pacc[2][t] + pacc[3][t];
    const float* wv2 = w2 + 3*DIM + h*HD + t;   // vd columns
    float dd = 0.f;
    for (int j = 0; j < INNER_D; j++) dd += tj[j] * wv2[(size_t)j*FF];
    pre_cls[(size_t)fb*DIM + h*HD + t] = (o + dd) * inv;
  }
}

// ---------------------------------------------------------------------------
// K8/K10/K11: small-M (M=64) GEMM: out = act(X@W + bias) [+ addend], or K-split partials.
__launch_bounds__(1024)
__global__ void headgemm_kernel(const float* __restrict__ X, const float* __restrict__ W,
                                const float* __restrict__ bias, const float* __restrict__ addend,
                                float* __restrict__ out, int N, int K, int kSplit, int act)
{
  int col = blockIdx.x * 64 + (threadIdx.x & 63);
  int rg = threadIdx.x >> 6;               // 0..15
  int kChunk = K / kSplit;
  int k0base = blockIdx.y * kChunk;
  __shared__ __align__(16) float Xs[64][68];
  float acc[4] = {0.f, 0.f, 0.f, 0.f};
  for (int k0 = k0base; k0 < k0base + kChunk; k0 += 64) {
    for (int v = threadIdx.x; v < 64*16; v += 1024) {
      int rr = v >> 4, c4 = (v & 15) << 2;
      *(float4*)&Xs[rr][c4] = *(const float4*)&X[(size_t)rr*K + k0 + c4];
    }
    __syncthreads();
    #pragma unroll 8
    for (int kk = 0; kk < 64; kk++) {
      float w = W[(size_t)(k0 + kk)*N + col];
      #pragma unroll
      for (int i = 0; i < 4; i++) acc[i] += Xs[rg + 16*i][kk] * w;
    }
    __syncthreads();
  }
  #pragma unroll
  for (int i = 0; i < 4; i++) {
    int r = rg + 16*i;
    float v = acc[i];
    if (kSplit == 1) {
      v += bias[col];
      if (addend) v += addend[(size_t)r*N + col];
      if (act == 1) v = v / (1.0f + __expf(-1.702f * v));   // quick_gelu
      out[(size_t)r*N + col] = v;
    } else {
      out[(size_t)(blockIdx.y*64 + r)*N + col] = v;         // partial slab
    }
  }
}

// K12: d_out = resid(out0) + fc2_b + sum of 4 K-split partials
__global__ void final_reduce_kernel(const float* __restrict__ out0, const float* __restrict__ b2,
                                    const float* __restrict__ partC, float* __restrict__ dout)
{
  int i = blockIdx.x * 256 + threadIdx.x;   // < 49152
  int c = i % DIM;
  dout[i] = out0[i] + b2[c] + partC[i] + partC[49152 + i] + partC[2*49152 + i] + partC[3*49152 + i];
}

// ---------------------------------------------------------------------------
extern "C" void kernel_launch(void* const* d_in, const int* in_sizes, int n_in,
                              void* d_out, int out_size, void* d_ws, size_t ws_size,
                              hipStream_t stream)
{
  const float* hs   = (const float*)d_in[0];
  const float* dpp  = (const float*)d_in[1];
  const float* hqkv = (const float*)d_in[2];
  const float* ln1g = (const float*)d_in[3];
  const float* ln1b = (const float*)d_in[4];
  const float* wq   = (const float*)d_in[5];
  const float* bq   = (const float*)d_in[6];
  const float* wk   = (const float*)d_in[7];
  const float* bk   = (const float*)d_in[8];
  const float* wvw  = (const float*)d_in[9];
  const float* bv   = (const float*)d_in[10];
  const float* w1   = (const float*)d_in[11];
  const float* w2   = (const float*)d_in[12];
  const float* wo   = (const float*)d_in[13];
  const float* bo   = (const float*)d_in[14];
  const float* ln2g = (const float*)d_in[15];
  const float* ln2b = (const float*)d_in[16];
  const float* fc1w = (const float*)d_in[17];
  const float* fc1b = (const float*)d_in[18];
  const float* fc2w = (const float*)d_in[19];
  const float* fc2b = (const float*)d_in[20];
  const int*   gidx = (const int*)d_in[21];
  const unsigned char* rmap = (const unsigned char*)d_in[22];
  float* outp = (float*)d_out;

  char* ws = (char*)d_ws;
  size_t off = 0;
  auto alloc = [&](size_t bytes) { void* p = ws + off; off += (bytes + 255) & ~(size_t)255; return p; };
  unsigned char* mask = (unsigned char*)alloc(TT);
  __bf16* xbf   = (__bf16*)alloc((size_t)TT * DIM * 2);
  __bf16* wkT   = (__bf16*)alloc((size_t)DIM * DIM * 2);
  __bf16* wvT   = (__bf16*)alloc((size_t)DIM * DIM * 2);
  __bf16* k_new = (__bf16*)alloc((size_t)TT * DIM * 2);
  __bf16* v_new = (__bf16*)alloc((size_t)TT * DIM * 2);
  float* inner  = (float*)alloc((size_t)TT * INNER_D * 4);
  float* h_cls  = (float*)alloc((size_t)FB_N * DIM * 4);
  float* q0s    = (float*)alloc((size_t)FB_N * DIM * 4);
  float* precls = (float*)alloc((size_t)FB_N * DIM * 4);
  float* out0   = (float*)alloc((size_t)FB_N * DIM * 4);
  float* yln    = (float*)alloc((size_t)FB_N * DIM * 4);
  float* t1     = (float*)alloc((size_t)FB_N * FF * 4);
  float* partC  = (float*)alloc((size_t)4 * FB_N * DIM * 4);
  (void)ws_size; (void)in_sizes; (void)n_in; (void)out_size;

  mask_norm_kernel<<<1, 256, 0, stream>>>(rmap, mask);
  ln_kernel<true><<<TT, 256, 0, stream>>>(hs, ln1g, ln1b, xbf);
  transpose_w_kernel<<<dim3(24, 24, 2), dim3(32, 8), 0, stream>>>(wk, wvw, wkT, wvT);
  kv_gemm_kernel<<<dim3(TT/64, DIM/64), 256, 0, stream>>>(xbf, wkT, wvT, bk, bv, k_new, v_new);
  inner_kernel<<<TT/64, 256, 0, stream>>>(dpp, w1, inner);
  cls_prep_kernel<<<FB_N, 256, 0, stream>>>(hs, hqkv, xbf, wq, bq, w2, inner, gidx, mask, h_cls, q0s);
  attn_cls_kernel<<<FB_N * NH, 256, 0, stream>>>(hqkv, k_new, v_new, w2, inner, gidx, mask, q0s, precls);
  headgemm_kernel<<<dim3(DIM/64, 1), 1024, 0, stream>>>(precls, wo, bo, h_cls, out0, DIM, DIM, 1, 0);
  ln_kernel<false><<<FB_N, 256, 0, stream>>>(out0, ln2g, ln2b, yln);
  headgemm_kernel<<<dim3(FF/64, 1), 1024, 0, stream>>>(yln, fc1w, fc1b, nullptr, t1, FF, DIM, 1, 1);
  headgemm_kernel<<<dim3(DIM/64, 4), 1024, 0, stream>>>(t1, fc2w, nullptr, nullptr, partC, DIM, FF, 4, 0);
  final_reduce_kernel<<<192, 256, 0, stream>>>(out0, fc2b, partC, outp);
}

// Round 2
// 372.338 us; speedup vs baseline: 2.2794x; 2.2794x over previous
//
#include <hip/hip_runtime.h>
#include <hip/hip_bf16.h>

// Problem constants
#define TT 12608          // 4*B*N rows of hs
#define NC 3152           // B*N cache rows (= 16*197)
#define DIM 768
#define NPOS 197
#define NH 12
#define HD 64
#define FB_N 64           // 4*B
#define FF 3072
#define INNER_D 64

typedef __bf16 bf16x8 __attribute__((ext_vector_type(8)));
typedef float f32x4 __attribute__((ext_vector_type(4)));

__device__ inline float wred_sum(float v){
  #pragma unroll
  for (int o = 32; o > 0; o >>= 1) v += __shfl_down(v, o, 64);
  return v;
}
__device__ inline float wred_max(float v){
  #pragma unroll
  for (int o = 32; o > 0; o >>= 1) v = fmaxf(v, __shfl_down(v, o, 64));
  return v;
}

// ---------------------------------------------------------------------------
// K1: normalize reuse_map to uint8 regardless of harness dtype (int32/int8/f32).
__global__ void mask_norm_kernel(const unsigned char* __restrict__ rm,
                                 unsigned char* __restrict__ mask)
{
  __shared__ int flagA, flagB;
  if (threadIdx.x == 0) { flagA = 0; flagB = 0; }
  __syncthreads();
  int la = 0, lb = 0;
  for (int i = threadIdx.x; i < TT; i += blockDim.x) {
    unsigned char v = rm[i];
    if (v) { if (i & 3) la = 1; else lb = 1; }
  }
  if (la) atomicOr(&flagA, 1);
  if (lb) atomicOr(&flagB, 1);
  __syncthreads();
  int mode = (!flagA) ? 0 : (flagB ? 1 : 2); // 0=int32, 1=byte, 2=f32
  for (int i = threadIdx.x; i < TT; i += blockDim.x) {
    unsigned char m;
    if (mode == 0)      m = ((const int*)rm)[i] != 0;
    else if (mode == 1) m = rm[i] != 0;
    else                m = ((const float*)rm)[i] != 0.0f;
    mask[i] = m;
  }
}

// ---------------------------------------------------------------------------
// K2: row LayerNorm over 768 cols -> bf16.
__launch_bounds__(256)
__global__ void ln_kernel(const float* __restrict__ in, const float* __restrict__ g,
                          const float* __restrict__ b, __bf16* __restrict__ outp)
{
  int row = blockIdx.x, t = threadIdx.x;
  const float* x = in + (size_t)row * DIM;
  float v0 = x[t], v1 = x[t + 256], v2 = x[t + 512];
  float s = wred_sum(v0 + v1 + v2);
  float q = wred_sum(v0*v0 + v1*v1 + v2*v2);
  __shared__ float red[8];
  int wv = t >> 6, ln = t & 63;
  if (ln == 0) { red[wv] = s; red[4 + wv] = q; }
  __syncthreads();
  float mean = (red[0]+red[1]+red[2]+red[3]) * (1.f/DIM);
  float var  = (red[4]+red[5]+red[6]+red[7]) * (1.f/DIM) - mean*mean;
  float rr = rsqrtf(var + 1e-5f);
  #pragma unroll
  for (int j = 0; j < 3; j++) {
    int c = t + j*256;
    float v = (j==0) ? v0 : (j==1) ? v1 : v2;
    outp[(size_t)row*DIM + c] = (__bf16)((v - mean) * rr * g[c] + b[c]);
  }
}

// ---------------------------------------------------------------------------
// K3: transpose wk/wv (768x768 f32) -> bf16 B^T layout for MFMA B-fragments.
__global__ void transpose_w_kernel(const float* __restrict__ wk, const float* __restrict__ wv,
                                   __bf16* __restrict__ wkT, __bf16* __restrict__ wvT)
{
  const float* src = blockIdx.z ? wv : wk;
  __bf16* dst = blockIdx.z ? wvT : wkT;
  __shared__ float tile[32][33];
  int bx = blockIdx.x, by = blockIdx.y;
  int tx = threadIdx.x, ty = threadIdx.y;
  #pragma unroll
  for (int i = 0; i < 32; i += 8)
    tile[ty + i][tx] = src[(size_t)(by*32 + ty + i) * DIM + bx*32 + tx];
  __syncthreads();
  #pragma unroll
  for (int i = 0; i < 32; i += 8)
    dst[(size_t)(bx*32 + ty + i) * DIM + by*32 + tx] = (__bf16)tile[tx][ty + i];
}

// ---------------------------------------------------------------------------
// K4: k_new = x@wk + bk, v_new = x@wv + bv  via bf16 MFMA 16x16x32.
__launch_bounds__(256)
__global__ void kv_gemm_kernel(const __bf16* __restrict__ xbf, const __bf16* __restrict__ wkT,
                               const __bf16* __restrict__ wvT, const float* __restrict__ bk,
                               const float* __restrict__ bv, __bf16* __restrict__ k_new,
                               __bf16* __restrict__ v_new)
{
  __shared__ __align__(16) __bf16 As[64][40];
  __shared__ __align__(16) __bf16 Bks[64][40];
  __shared__ __align__(16) __bf16 Bvs[64][40];
  int t = threadIdx.x;
  int wv = t >> 6, lane = t & 63;
  int fr = lane & 15, fg = lane >> 4;
  int row0 = blockIdx.x * 64, col0 = blockIdx.y * 64;
  int lr = t >> 2, lk = (t & 3) << 3;
  const __bf16* aS = xbf + (size_t)(row0 + lr) * DIM + lk;
  const __bf16* kS = wkT + (size_t)(col0 + lr) * DIM + lk;
  const __bf16* vS = wvT + (size_t)(col0 + lr) * DIM + lk;
  f32x4 zero = {0.f, 0.f, 0.f, 0.f};
  f32x4 aK[4], aV[4];
  #pragma unroll
  for (int i = 0; i < 4; i++) { aK[i] = zero; aV[i] = zero; }
  for (int k0 = 0; k0 < DIM; k0 += 32) {
    *(uint4*)&As[lr][lk]  = *(const uint4*)(aS + k0);
    *(uint4*)&Bks[lr][lk] = *(const uint4*)(kS + k0);
    *(uint4*)&Bvs[lr][lk] = *(const uint4*)(vS + k0);
    __syncthreads();
    bf16x8 af = *(const bf16x8*)&As[wv*16 + fr][fg << 3];
    #pragma unroll
    for (int n = 0; n < 4; n++) {
      bf16x8 b1 = *(const bf16x8*)&Bks[n*16 + fr][fg << 3];
      bf16x8 b2 = *(const bf16x8*)&Bvs[n*16 + fr][fg << 3];
      aK[n] = __builtin_amdgcn_mfma_f32_16x16x32_bf16(af, b1, aK[n], 0, 0, 0);
      aV[n] = __builtin_amdgcn_mfma_f32_16x16x32_bf16(af, b2, aV[n], 0, 0, 0);
    }
    __syncthreads();
  }
  int orow = row0 + wv*16 + fg*4;
  #pragma unroll
  for (int n = 0; n < 4; n++) {
    int col = col0 + n*16 + fr;
    float bkc = bk[col], bvc = bv[col];
    #pragma unroll
    for (int r = 0; r < 4; r++) {
      size_t off = (size_t)(orow + r) * DIM + col;
      k_new[off] = (__bf16)(aK[n][r] + bkc);
      v_new[off] = (__bf16)(aV[n][r] + bvc);
    }
  }
}

// ---------------------------------------------------------------------------
// K5: inner = gelu_tanh(diff_pre_proj @ rest_w1)   (12608 x 64)
__launch_bounds__(256)
__global__ void inner_kernel(const float* __restrict__ dpp, const float* __restrict__ w1,
                             float* __restrict__ inner)
{
  __shared__ __align__(16) float Xs[64][68];
  __shared__ __align__(16) float Ws[64][64];
  int t = threadIdx.x;
  int r = t >> 2, c0 = (t & 3) << 4;
  int row0 = blockIdx.x * 64;
  float acc[16];
  #pragma unroll
  for (int i = 0; i < 16; i++) acc[i] = 0.f;
  for (int k0 = 0; k0 < DIM; k0 += 64) {
    #pragma unroll
    for (int j = 0; j < 4; j++) {
      int v = t + 256*j;
      int rr = v >> 4, c4 = (v & 15) << 2;
      *(float4*)&Xs[rr][c4] = *(const float4*)&dpp[(size_t)(row0 + rr)*DIM + k0 + c4];
      *(float4*)&Ws[rr][c4] = *(const float4*)&w1[(size_t)(k0 + rr)*INNER_D + c4];
    }
    __syncthreads();
    for (int kk = 0; kk < 64; kk++) {
      float xv = Xs[r][kk];
      #pragma unroll
      for (int c = 0; c < 16; c++) acc[c] += xv * Ws[kk][c0 + c];
    }
    __syncthreads();
  }
  #pragma unroll
  for (int c = 0; c < 16; c++) {
    float x = acc[c];
    float u = 0.7978845608028654f * (x + 0.044715f * x * x * x);
    inner[(size_t)(row0 + r)*INNER_D + c0 + c] = 0.5f * x * (1.0f + tanhf(u));
  }
}

// ---------------------------------------------------------------------------
// K6: per (f,b): h_cls row (gather + masked hd), qbase row (cache/bias + masked qd),
//     and compact Xq row (fresh LN row, else zero) for the batched Q GEMM.
__launch_bounds__(256)
__global__ void cls_gather_kernel(const float* __restrict__ hs, const float* __restrict__ hqkv,
                                  const __bf16* __restrict__ xbf, const float* __restrict__ bq,
                                  const float* __restrict__ w2, const float* __restrict__ inner,
                                  const int* __restrict__ gidx, const unsigned char* __restrict__ mask,
                                  float* __restrict__ h_cls, float* __restrict__ qbase,
                                  float* __restrict__ Xq)
{
  int fb = blockIdx.x, t = threadIdx.x;
  int g0 = fb * NPOS;
  int idx = gidx[g0];
  int m = mask[g0];
  const float* q_cache = hqkv + (size_t)NC * DIM;
  __shared__ float inn[INNER_D];
  if (t < INNER_D) inn[t] = inner[(size_t)g0 * INNER_D + t];
  __syncthreads();
  bool fresh = idx >= NC;
  for (int c = t; c < DIM; c += 256) {
    float xv = fresh ? (float)xbf[(size_t)(idx - NC)*DIM + c] : 0.f;
    Xq[(size_t)fb*DIM + c] = xv;
    float hv = fresh ? hs[(size_t)(idx - NC)*DIM + c] : hqkv[(size_t)idx*DIM + c];
    float qb = fresh ? bq[c] : q_cache[(size_t)idx*DIM + c];
    if (m) {
      float hd = 0.f, qd = 0.f;
      #pragma unroll 8
      for (int j = 0; j < INNER_D; j++) {
        float iv = inn[j];
        hd += iv * w2[(size_t)j*FF + c];
        qd += iv * w2[(size_t)j*FF + DIM + c];
      }
      hv += hd; qb += qd;
    }
    h_cls[(size_t)fb*DIM + c] = hv;
    qbase[(size_t)fb*DIM + c] = qb;
  }
}

// ---------------------------------------------------------------------------
// K7: partial GEMM, M=64 fixed. grid (N/64, K/kChunk), 256 thr.
// part[ks][64][N] += X[64 x kChunk] @ W[kChunk x N]-slice.
__launch_bounds__(256)
__global__ void pgemm_kernel(const float* __restrict__ X, const float* __restrict__ W,
                             float* __restrict__ part, int N, int K, int kChunk)
{
  int t = threadIdx.x;
  int c4 = (t & 15) << 2;            // 4 cols within the 64-col tile
  int rb = t >> 4;                   // 0..15 -> rows rb*4 .. rb*4+3
  int col0 = blockIdx.x * 64;
  int k0base = blockIdx.y * kChunk;
  __shared__ __align__(16) float Xs[64][68];
  float4 acc[4];
  #pragma unroll
  for (int i = 0; i < 4; i++) acc[i] = make_float4(0.f, 0.f, 0.f, 0.f);
  for (int k0 = k0base; k0 < k0base + kChunk; k0 += 64) {
    #pragma unroll
    for (int j = 0; j < 4; j++) {
      int v = t + 256*j;
      int rr = v >> 4, cc = (v & 15) << 2;
      *(float4*)&Xs[rr][cc] = *(const float4*)&X[(size_t)rr*K + k0 + cc];
    }
    __syncthreads();
    #pragma unroll 4
    for (int kk = 0; kk < 64; kk++) {
      float4 w4 = *(const float4*)&W[(size_t)(k0 + kk)*N + col0 + c4];
      #pragma unroll
      for (int i = 0; i < 4; i++) {
        float xv = Xs[rb*4 + i][kk];
        acc[i].x += xv * w4.x; acc[i].y += xv * w4.y;
        acc[i].z += xv * w4.z; acc[i].w += xv * w4.w;
      }
    }
    __syncthreads();
  }
  #pragma unroll
  for (int i = 0; i < 4; i++) {
    int r = rb*4 + i;
    *(float4*)&part[((size_t)blockIdx.y*64 + r)*N + col0 + c4] = acc[i];
  }
}

// K7b: q0s = (qbase + sum_s partQ) * SCALE
__global__ void reduce_q_kernel(const float* __restrict__ qbase, const float* __restrict__ partQ,
                                float* __restrict__ q0s)
{
  int i = blockIdx.x * 256 + threadIdx.x;   // < 49152
  float v = qbase[i];
  #pragma unroll
  for (int s = 0; s < 12; s++) v += partQ[(size_t)s*FB_N*DIM + i];
  q0s[i] = v * 0.125f;
}

// ---------------------------------------------------------------------------
// K8: CLS-row attention with low-rank diff folded in algebraically.
__launch_bounds__(256)
__global__ void attn_cls_kernel(const float* __restrict__ hqkv, const __bf16* __restrict__ k_new,
                                const __bf16* __restrict__ v_new, const float* __restrict__ w2,
                                const float* __restrict__ inner, const int* __restrict__ gidx,
                                const unsigned char* __restrict__ mask,
                                const float* __restrict__ q0s, float* __restrict__ pre_cls)
{
  int bid = blockIdx.x;
  int fb = bid / NH, h = bid % NH;
  int t = threadIdx.x;
  int lane = t & 63, wv = t >> 6;
  const float* k_cache = hqkv + (size_t)2 * NC * DIM;
  const float* v_cache = hqkv + (size_t)3 * NC * DIM;
  __shared__ float q0[HD], w2q[INNER_D], tj[INNER_D];
  __shared__ float p[200];
  __shared__ int sidx[200];
  __shared__ unsigned char smk[200];
  __shared__ float red[16];
  __shared__ float pacc[4][64];
  if (t < HD) q0[t] = q0s[(size_t)fb*DIM + h*HD + t];
  __syncthreads();
  if (t < INNER_D) {
    const float* wr = w2 + (size_t)t*FF + 2*DIM + h*HD;  // kd columns
    float s = 0.f;
    for (int d = 0; d < HD; d++) s += q0[d] * wr[d];
    w2q[t] = s;
  }
  __syncthreads();
  if (t < NPOS) {
    int g = fb * NPOS + t;
    int idx = gidx[g];
    unsigned char m = mask[g];
    sidx[t] = idx; smk[t] = m;
    float s = 0.f;
    if (idx >= NC) {
      const __bf16* kr = k_new + (size_t)(idx - NC)*DIM + h*HD;
      for (int d = 0; d < HD; d++) s += q0[d] * (float)kr[d];
    } else {
      const float* kr = k_cache + (size_t)idx*DIM + h*HD;
      for (int d = 0; d < HD; d++) s += q0[d] * kr[d];
    }
    if (m) {
      const float* ir = inner + (size_t)g * INNER_D;
      float s2 = 0.f;
      for (int j = 0; j < INNER_D; j++) s2 += ir[j] * w2q[j];
      s += s2;
    }
    p[t] = s;
  }
  __syncthreads();
  float lm = (t < NPOS) ? p[t] : -1e30f;
  lm = wred_max(lm);
  if (lane == 0) red[wv] = lm;
  __syncthreads();
  float mx = fmaxf(fmaxf(red[0], red[1]), fmaxf(red[2], red[3]));
  float lp = 0.f;
  if (t < NPOS) { lp = __expf(p[t] - mx); p[t] = lp; }
  float ls = wred_sum(lp);
  if (lane == 0) red[8 + wv] = ls;
  __syncthreads();
  float inv = 1.0f / (red[8] + red[9] + red[10] + red[11]);
  float tp = 0.f;
  for (int n = wv; n < NPOS; n += 4) {
    if (smk[n]) tp += p[n] * inner[(size_t)(fb*NPOS + n)*INNER_D + lane];
  }
  pacc[wv][lane] = tp;
  __syncthreads();
  if (t < INNER_D) tj[t] = pacc[0][t] + pacc[1][t] + pacc[2][t] + pacc[3][t];
  __syncthreads();
  float va = 0.f;
  for (int n = wv; n < NPOS; n += 4) {
    float pn = p[n];
    int idx = sidx[n];
    float vvv;
    if (idx >= NC) vvv = (float)v_new[(size_t)(idx - NC)*DIM + h*HD + lane];
    else           vvv = v_cache[(size_t)idx*DIM + h*HD + lane];
    va += pn * vvv;
  }
  __syncthreads();
  pacc[wv][lane] = va;
  __syncthreads();
  if (t < HD) {
    float o = pacc[0][t] + pacc[1][t] + pacc[2][t] + pacc[3][t];
    const float* wv2 = w2 + 3*DIM + h*HD + t;   // vd columns
    float dd = 0.f;
    for (int j = 0; j < INNER_D; j++) dd += tj[j] * wv2[(size_t)j*FF];
    pre_cls[(size_t)fb*DIM + h*HD + t] = (o + dd) * inv;
  }
}

// ---------------------------------------------------------------------------
// K9: out0 = h_cls + (sum_s partW) + bo;  yln = LN2(out0).  One block per row.
__launch_bounds__(256)
__global__ void reduce_wo_ln_kernel(const float* __restrict__ partW, const float* __restrict__ bo,
                                    const float* __restrict__ h_cls, const float* __restrict__ g,
                                    const float* __restrict__ b, float* __restrict__ out0,
                                    float* __restrict__ yln)
{
  int row = blockIdx.x, t = threadIdx.x;
  float v[3];
  #pragma unroll
  for (int j = 0; j < 3; j++) {
    int c = t + j*256;
    float s = h_cls[(size_t)row*DIM + c] + bo[c];
    #pragma unroll
    for (int ks = 0; ks < 12; ks++) s += partW[((size_t)ks*FB_N + row)*DIM + c];
    v[j] = s;
    out0[(size_t)row*DIM + c] = s;
  }
  float sm = wred_sum(v[0] + v[1] + v[2]);
  float sq = wred_sum(v[0]*v[0] + v[1]*v[1] + v[2]*v[2]);
  __shared__ float red[8];
  int wv = t >> 6, ln = t & 63;
  if (ln == 0) { red[wv] = sm; red[4 + wv] = sq; }
  __syncthreads();
  float mean = (red[0]+red[1]+red[2]+red[3]) * (1.f/DIM);
  float var  = (red[4]+red[5]+red[6]+red[7]) * (1.f/DIM) - mean*mean;
  float rr = rsqrtf(var + 1e-5f);
  #pragma unroll
  for (int j = 0; j < 3; j++) {
    int c = t + j*256;
    yln[(size_t)row*DIM + c] = (v[j] - mean) * rr * g[c] + b[c];
  }
}

// K10: t1 = quick_gelu(sum_s partF1 + fc1b)
__global__ void reduce_gelu_kernel(const float* __restrict__ partF1, const float* __restrict__ b1,
                                   float* __restrict__ t1)
{
  int i = blockIdx.x * 256 + threadIdx.x;   // < 196608
  int c = i % FF;
  float v = b1[c];
  #pragma unroll
  for (int s = 0; s < 4; s++) v += partF1[(size_t)s*FB_N*FF + i];
  t1[i] = v / (1.0f + __expf(-1.702f * v));
}

// K11: d_out = out0 + fc2_b + sum_s partF2
__global__ void final_reduce_kernel(const float* __restrict__ out0, const float* __restrict__ b2,
                                    const float* __restrict__ partF2, float* __restrict__ dout)
{
  int i = blockIdx.x * 256 + threadIdx.x;   // < 49152
  int c = i % DIM;
  float v = out0[i] + b2[c];
  #pragma unroll
  for (int s = 0; s < 16; s++) v += partF2[(size_t)s*FB_N*DIM + i];
  dout[i] = v;
}

// ---------------------------------------------------------------------------
extern "C" void kernel_launch(void* const* d_in, const int* in_sizes, int n_in,
                              void* d_out, int out_size, void* d_ws, size_t ws_size,
                              hipStream_t stream)
{
  const float* hs   = (const float*)d_in[0];
  const float* dpp  = (const float*)d_in[1];
  const float* hqkv = (const float*)d_in[2];
  const float* ln1g = (const float*)d_in[3];
  const float* ln1b = (const float*)d_in[4];
  const float* wq   = (const float*)d_in[5];
  const float* bq   = (const float*)d_in[6];
  const float* wk   = (const float*)d_in[7];
  const float* bk   = (const float*)d_in[8];
  const float* wvw  = (const float*)d_in[9];
  const float* bv   = (const float*)d_in[10];
  const float* w1   = (const float*)d_in[11];
  const float* w2   = (const float*)d_in[12];
  const float* wo   = (const float*)d_in[13];
  const float* bo   = (const float*)d_in[14];
  const float* ln2g = (const float*)d_in[15];
  const float* ln2b = (const float*)d_in[16];
  const float* fc1w = (const float*)d_in[17];
  const float* fc1b = (const float*)d_in[18];
  const float* fc2w = (const float*)d_in[19];
  const float* fc2b = (const float*)d_in[20];
  const int*   gidx = (const int*)d_in[21];
  const unsigned char* rmap = (const unsigned char*)d_in[22];
  float* outp = (float*)d_out;

  char* ws = (char*)d_ws;
  size_t off = 0;
  auto alloc = [&](size_t bytes) { void* p = ws + off; off += (bytes + 255) & ~(size_t)255; return p; };
  unsigned char* mask = (unsigned char*)alloc(TT);
  __bf16* xbf   = (__bf16*)alloc((size_t)TT * DIM * 2);
  __bf16* wkT   = (__bf16*)alloc((size_t)DIM * DIM * 2);
  __bf16* wvT   = (__bf16*)alloc((size_t)DIM * DIM * 2);
  __bf16* k_new = (__bf16*)alloc((size_t)TT * DIM * 2);
  __bf16* v_new = (__bf16*)alloc((size_t)TT * DIM * 2);
  float* inner  = (float*)alloc((size_t)TT * INNER_D * 4);
  float* h_cls  = (float*)alloc((size_t)FB_N * DIM * 4);
  float* qbase  = (float*)alloc((size_t)FB_N * DIM * 4);
  float* Xq     = (float*)alloc((size_t)FB_N * DIM * 4);
  float* q0s    = (float*)alloc((size_t)FB_N * DIM * 4);
  float* precls = (float*)alloc((size_t)FB_N * DIM * 4);
  float* out0   = (float*)alloc((size_t)FB_N * DIM * 4);
  float* yln    = (float*)alloc((size_t)FB_N * DIM * 4);
  float* t1     = (float*)alloc((size_t)FB_N * FF * 4);
  float* partQ  = (float*)alloc((size_t)12 * FB_N * DIM * 4);
  float* partW  = (float*)alloc((size_t)12 * FB_N * DIM * 4);
  float* partF1 = (float*)alloc((size_t)4  * FB_N * FF  * 4);
  float* partF2 = (float*)alloc((size_t)16 * FB_N * DIM * 4);
  (void)ws_size; (void)in_sizes; (void)n_in; (void)out_size;

  mask_norm_kernel<<<1, 256, 0, stream>>>(rmap, mask);
  ln_kernel<<<TT, 256, 0, stream>>>(hs, ln1g, ln1b, xbf);
  transpose_w_kernel<<<dim3(24, 24, 2), dim3(32, 8), 0, stream>>>(wk, wvw, wkT, wvT);
  kv_gemm_kernel<<<dim3(TT/64, DIM/64), 256, 0, stream>>>(xbf, wkT, wvT, bk, bv, k_new, v_new);
  inner_kernel<<<TT/64, 256, 0, stream>>>(dpp, w1, inner);
  cls_gather_kernel<<<FB_N, 256, 0, stream>>>(hs, hqkv, xbf, bq, w2, inner, gidx, mask,
                                              h_cls, qbase, Xq);
  // q0s = (qbase + Xq @ wq) * SCALE   (zero Xq rows for cached fb's)
  pgemm_kernel<<<dim3(12, 12), 256, 0, stream>>>(Xq, wq, partQ, DIM, DIM, 64);
  reduce_q_kernel<<<192, 256, 0, stream>>>(qbase, partQ, q0s);
  attn_cls_kernel<<<FB_N * NH, 256, 0, stream>>>(hqkv, k_new, v_new, w2, inner, gidx, mask, q0s, precls);
  // out0 = h_cls + precls@wo + bo ; yln = LN2(out0)
  pgemm_kernel<<<dim3(12, 12), 256, 0, stream>>>(precls, wo, partW, DIM, DIM, 64);
  reduce_wo_ln_kernel<<<FB_N, 256, 0, stream>>>(partW, bo, h_cls, ln2g, ln2b, out0, yln);
  // t1 = qgelu(yln@fc1w + fc1b)
  pgemm_kernel<<<dim3(48, 4), 256, 0, stream>>>(yln, fc1w, partF1, FF, DIM, 192);
  reduce_gelu_kernel<<<768, 256, 0, stream>>>(partF1, fc1b, t1);
  // d_out = out0 + t1@fc2w + fc2b
  pgemm_kernel<<<dim3(12, 16), 256, 0, stream>>>(t1, fc2w, partF2, DIM, FF, 192);
  final_reduce_kernel<<<192, 256, 0, stream>>>(out0, fc2b, partF2, outp);
}

// Round 3
// 301.007 us; speedup vs baseline: 2.8195x; 1.2370x over previous
//
#include <hip/hip_runtime.h>
#include <hip/hip_bf16.h>

// Problem constants
#define TT 12608          // 4*B*N rows of hs
#define NC 3152           // B*N cache rows (= 16*197)
#define DIM 768
#define NPOS 197
#define NH 12
#define HD 64
#define FB_N 64           // 4*B
#define FF 3072
#define INNER_D 64

typedef __bf16 bf16x8 __attribute__((ext_vector_type(8)));
typedef float f32x4 __attribute__((ext_vector_type(4)));

__device__ inline float wred_sum(float v){
  #pragma unroll
  for (int o = 32; o > 0; o >>= 1) v += __shfl_down(v, o, 64);
  return v;
}
__device__ inline float wred_max(float v){
  #pragma unroll
  for (int o = 32; o > 0; o >>= 1) v = fmaxf(v, __shfl_down(v, o, 64));
  return v;
}

// ---------------------------------------------------------------------------
// K1: normalize reuse_map to uint8 regardless of harness dtype (int32/int8/f32).
__global__ void mask_norm_kernel(const unsigned char* __restrict__ rm,
                                 unsigned char* __restrict__ mask)
{
  __shared__ int flagA, flagB;
  if (threadIdx.x == 0) { flagA = 0; flagB = 0; }
  __syncthreads();
  int la = 0, lb = 0;
  for (int i = threadIdx.x; i < TT; i += blockDim.x) {
    unsigned char v = rm[i];
    if (v) { if (i & 3) la = 1; else lb = 1; }
  }
  if (la) atomicOr(&flagA, 1);
  if (lb) atomicOr(&flagB, 1);
  __syncthreads();
  int mode = (!flagA) ? 0 : (flagB ? 1 : 2); // 0=int32, 1=byte, 2=f32
  for (int i = threadIdx.x; i < TT; i += blockDim.x) {
    unsigned char m;
    if (mode == 0)      m = ((const int*)rm)[i] != 0;
    else if (mode == 1) m = rm[i] != 0;
    else                m = ((const float*)rm)[i] != 0.0f;
    mask[i] = m;
  }
}

// ---------------------------------------------------------------------------
// K2: row LayerNorm over 768 cols -> bf16.
__launch_bounds__(256)
__global__ void ln_kernel(const float* __restrict__ in, const float* __restrict__ g,
                          const float* __restrict__ b, __bf16* __restrict__ outp)
{
  int row = blockIdx.x, t = threadIdx.x;
  const float* x = in + (size_t)row * DIM;
  float v0 = x[t], v1 = x[t + 256], v2 = x[t + 512];
  float s = wred_sum(v0 + v1 + v2);
  float q = wred_sum(v0*v0 + v1*v1 + v2*v2);
  __shared__ float red[8];
  int wv = t >> 6, ln = t & 63;
  if (ln == 0) { red[wv] = s; red[4 + wv] = q; }
  __syncthreads();
  float mean = (red[0]+red[1]+red[2]+red[3]) * (1.f/DIM);
  float var  = (red[4]+red[5]+red[6]+red[7]) * (1.f/DIM) - mean*mean;
  float rr = rsqrtf(var + 1e-5f);
  #pragma unroll
  for (int j = 0; j < 3; j++) {
    int c = t + j*256;
    float v = (j==0) ? v0 : (j==1) ? v1 : v2;
    outp[(size_t)row*DIM + c] = (__bf16)((v - mean) * rr * g[c] + b[c]);
  }
}

// ---------------------------------------------------------------------------
// K3: transpose wk/wv (768x768 f32) -> bf16 B^T layout for MFMA B-fragments.
__global__ void transpose_w_kernel(const float* __restrict__ wk, const float* __restrict__ wv,
                                   __bf16* __restrict__ wkT, __bf16* __restrict__ wvT)
{
  const float* src = blockIdx.z ? wv : wk;
  __bf16* dst = blockIdx.z ? wvT : wkT;
  __shared__ float tile[32][33];
  int bx = blockIdx.x, by = blockIdx.y;
  int tx = threadIdx.x, ty = threadIdx.y;
  #pragma unroll
  for (int i = 0; i < 32; i += 8)
    tile[ty + i][tx] = src[(size_t)(by*32 + ty + i) * DIM + bx*32 + tx];
  __syncthreads();
  #pragma unroll
  for (int i = 0; i < 32; i += 8)
    dst[(size_t)(bx*32 + ty + i) * DIM + by*32 + tx] = (__bf16)tile[tx][ty + i];
}

// ---------------------------------------------------------------------------
// K4: k_new = x@wk + bk, v_new = x@wv + bv  via bf16 MFMA 16x16x32.
__launch_bounds__(256)
__global__ void kv_gemm_kernel(const __bf16* __restrict__ xbf, const __bf16* __restrict__ wkT,
                               const __bf16* __restrict__ wvT, const float* __restrict__ bk,
                               const float* __restrict__ bv, __bf16* __restrict__ k_new,
                               __bf16* __restrict__ v_new)
{
  __shared__ __align__(16) __bf16 As[64][40];
  __shared__ __align__(16) __bf16 Bks[64][40];
  __shared__ __align__(16) __bf16 Bvs[64][40];
  int t = threadIdx.x;
  int wv = t >> 6, lane = t & 63;
  int fr = lane & 15, fg = lane >> 4;
  int row0 = blockIdx.x * 64, col0 = blockIdx.y * 64;
  int lr = t >> 2, lk = (t & 3) << 3;
  const __bf16* aS = xbf + (size_t)(row0 + lr) * DIM + lk;
  const __bf16* kS = wkT + (size_t)(col0 + lr) * DIM + lk;
  const __bf16* vS = wvT + (size_t)(col0 + lr) * DIM + lk;
  f32x4 zero = {0.f, 0.f, 0.f, 0.f};
  f32x4 aK[4], aV[4];
  #pragma unroll
  for (int i = 0; i < 4; i++) { aK[i] = zero; aV[i] = zero; }
  for (int k0 = 0; k0 < DIM; k0 += 32) {
    *(uint4*)&As[lr][lk]  = *(const uint4*)(aS + k0);
    *(uint4*)&Bks[lr][lk] = *(const uint4*)(kS + k0);
    *(uint4*)&Bvs[lr][lk] = *(const uint4*)(vS + k0);
    __syncthreads();
    bf16x8 af = *(const bf16x8*)&As[wv*16 + fr][fg << 3];
    #pragma unroll
    for (int n = 0; n < 4; n++) {
      bf16x8 b1 = *(const bf16x8*)&Bks[n*16 + fr][fg << 3];
      bf16x8 b2 = *(const bf16x8*)&Bvs[n*16 + fr][fg << 3];
      aK[n] = __builtin_amdgcn_mfma_f32_16x16x32_bf16(af, b1, aK[n], 0, 0, 0);
      aV[n] = __builtin_amdgcn_mfma_f32_16x16x32_bf16(af, b2, aV[n], 0, 0, 0);
    }
    __syncthreads();
  }
  int orow = row0 + wv*16 + fg*4;
  #pragma unroll
  for (int n = 0; n < 4; n++) {
    int col = col0 + n*16 + fr;
    float bkc = bk[col], bvc = bv[col];
    #pragma unroll
    for (int r = 0; r < 4; r++) {
      size_t off = (size_t)(orow + r) * DIM + col;
      k_new[off] = (__bf16)(aK[n][r] + bkc);
      v_new[off] = (__bf16)(aV[n][r] + bvc);
    }
  }
}

// ---------------------------------------------------------------------------
// K5: inner = gelu_tanh(diff_pre_proj @ rest_w1)   (12608 x 64)
__launch_bounds__(256)
__global__ void inner_kernel(const float* __restrict__ dpp, const float* __restrict__ w1,
                             float* __restrict__ inner)
{
  __shared__ __align__(16) float Xs[64][68];
  __shared__ __align__(16) float Ws[64][64];
  int t = threadIdx.x;
  int r = t >> 2, c0 = (t & 3) << 4;
  int row0 = blockIdx.x * 64;
  float acc[16];
  #pragma unroll
  for (int i = 0; i < 16; i++) acc[i] = 0.f;
  for (int k0 = 0; k0 < DIM; k0 += 64) {
    #pragma unroll
    for (int j = 0; j < 4; j++) {
      int v = t + 256*j;
      int rr = v >> 4, c4 = (v & 15) << 2;
      *(float4*)&Xs[rr][c4] = *(const float4*)&dpp[(size_t)(row0 + rr)*DIM + k0 + c4];
      *(float4*)&Ws[rr][c4] = *(const float4*)&w1[(size_t)(k0 + rr)*INNER_D + c4];
    }
    __syncthreads();
    for (int kk = 0; kk < 64; kk++) {
      float xv = Xs[r][kk];
      #pragma unroll
      for (int c = 0; c < 16; c++) acc[c] += xv * Ws[kk][c0 + c];
    }
    __syncthreads();
  }
  #pragma unroll
  for (int c = 0; c < 16; c++) {
    float x = acc[c];
    float u = 0.7978845608028654f * (x + 0.044715f * x * x * x);
    inner[(size_t)(row0 + r)*INNER_D + c0 + c] = 0.5f * x * (1.0f + tanhf(u));
  }
}

// ---------------------------------------------------------------------------
// K6: per (f,b): h_cls row (gather + masked hd), qbase row (cache/bias + masked qd),
//     and compact Xq row (fresh LN row, else zero) for the batched Q GEMM.
__launch_bounds__(256)
__global__ void cls_gather_kernel(const float* __restrict__ hs, const float* __restrict__ hqkv,
                                  const __bf16* __restrict__ xbf, const float* __restrict__ bq,
                                  const float* __restrict__ w2, const float* __restrict__ inner,
                                  const int* __restrict__ gidx, const unsigned char* __restrict__ mask,
                                  float* __restrict__ h_cls, float* __restrict__ qbase,
                                  float* __restrict__ Xq)
{
  int fb = blockIdx.x, t = threadIdx.x;
  int g0 = fb * NPOS;
  int idx = gidx[g0];
  int m = mask[g0];
  const float* q_cache = hqkv + (size_t)NC * DIM;
  __shared__ float inn[INNER_D];
  if (t < INNER_D) inn[t] = inner[(size_t)g0 * INNER_D + t];
  __syncthreads();
  bool fresh = idx >= NC;
  for (int c = t; c < DIM; c += 256) {
    float xv = fresh ? (float)xbf[(size_t)(idx - NC)*DIM + c] : 0.f;
    Xq[(size_t)fb*DIM + c] = xv;
    float hv = fresh ? hs[(size_t)(idx - NC)*DIM + c] : hqkv[(size_t)idx*DIM + c];
    float qb = fresh ? bq[c] : q_cache[(size_t)idx*DIM + c];
    if (m) {
      float hd = 0.f, qd = 0.f;
      #pragma unroll 8
      for (int j = 0; j < INNER_D; j++) {
        float iv = inn[j];
        hd += iv * w2[(size_t)j*FF + c];
        qd += iv * w2[(size_t)j*FF + DIM + c];
      }
      hv += hd; qb += qd;
    }
    h_cls[(size_t)fb*DIM + c] = hv;
    qbase[(size_t)fb*DIM + c] = qb;
  }
}

// ---------------------------------------------------------------------------
// K7: partial GEMM, M=64 fixed. grid (N/64, K/kChunk), 256 thr.
// Thread = (column c = t&63, wave rq = t>>6 handling rows rq*16..rq*16+15).
// W streamed with per-lane scalar loads (coalesced 256B/wave, independent);
// X tile in LDS, consumed via broadcast float4 reads.
__launch_bounds__(256)
__global__ void pgemm_kernel(const float* __restrict__ X, const float* __restrict__ W,
                             float* __restrict__ part, int N, int K, int kChunk)
{
  int t = threadIdx.x;
  int c = t & 63;
  int rq = t >> 6;
  int col0 = blockIdx.x * 64;
  int k0base = blockIdx.y * kChunk;
  __shared__ __align__(16) float Xs[64][68];
  float acc[16];
  #pragma unroll
  for (int i = 0; i < 16; i++) acc[i] = 0.f;
  for (int k0 = k0base; k0 < k0base + kChunk; k0 += 64) {
    #pragma unroll
    for (int j = 0; j < 4; j++) {
      int v = t + 256*j;
      int rr = v >> 4, cc = (v & 15) << 2;
      *(float4*)&Xs[rr][cc] = *(const float4*)&X[(size_t)rr*K + k0 + cc];
    }
    __syncthreads();
    const float* Wp = W + (size_t)k0*N + col0 + c;
    #pragma unroll 4
    for (int kk = 0; kk < 64; kk += 4) {
      float w0 = Wp[(size_t)(kk+0)*N];
      float w1 = Wp[(size_t)(kk+1)*N];
      float w2 = Wp[(size_t)(kk+2)*N];
      float w3 = Wp[(size_t)(kk+3)*N];
      #pragma unroll
      for (int r = 0; r < 16; r++) {
        float4 xv = *(const float4*)&Xs[rq*16 + r][kk];
        acc[r] += xv.x*w0 + xv.y*w1 + xv.z*w2 + xv.w*w3;
      }
    }
    __syncthreads();
  }
  #pragma unroll
  for (int r = 0; r < 16; r++)
    part[((size_t)blockIdx.y*64 + rq*16 + r)*N + col0 + c] = acc[r];
}

// K7b: q0s = (qbase + sum_s partQ) * SCALE     (12 slabs)
__global__ void reduce_q_kernel(const float* __restrict__ qbase, const float* __restrict__ partQ,
                                float* __restrict__ q0s)
{
  int i = blockIdx.x * 256 + threadIdx.x;   // < 49152
  float v = qbase[i];
  #pragma unroll
  for (int s = 0; s < 12; s++) v += partQ[(size_t)s*FB_N*DIM + i];
  q0s[i] = v * 0.125f;
}

// ---------------------------------------------------------------------------
// K8: CLS-row attention with low-rank diff folded in algebraically.
__launch_bounds__(256)
__global__ void attn_cls_kernel(const float* __restrict__ hqkv, const __bf16* __restrict__ k_new,
                                const __bf16* __restrict__ v_new, const float* __restrict__ w2,
                                const float* __restrict__ inner, const int* __restrict__ gidx,
                                const unsigned char* __restrict__ mask,
                                const float* __restrict__ q0s, float* __restrict__ pre_cls)
{
  int bid = blockIdx.x;
  int fb = bid / NH, h = bid % NH;
  int t = threadIdx.x;
  int lane = t & 63, wv = t >> 6;
  const float* k_cache = hqkv + (size_t)2 * NC * DIM;
  const float* v_cache = hqkv + (size_t)3 * NC * DIM;
  __shared__ float q0[HD], w2q[INNER_D], tj[INNER_D];
  __shared__ float p[200];
  __shared__ int sidx[200];
  __shared__ unsigned char smk[200];
  __shared__ float red[16];
  __shared__ float pacc[4][64];
  if (t < HD) q0[t] = q0s[(size_t)fb*DIM + h*HD + t];
  __syncthreads();
  if (t < INNER_D) {
    const float* wr = w2 + (size_t)t*FF + 2*DIM + h*HD;  // kd columns
    float s = 0.f;
    for (int d = 0; d < HD; d++) s += q0[d] * wr[d];
    w2q[t] = s;
  }
  __syncthreads();
  if (t < NPOS) {
    int g = fb * NPOS + t;
    int idx = gidx[g];
    unsigned char m = mask[g];
    sidx[t] = idx; smk[t] = m;
    float s = 0.f;
    if (idx >= NC) {
      const __bf16* kr = k_new + (size_t)(idx - NC)*DIM + h*HD;
      for (int d = 0; d < HD; d++) s += q0[d] * (float)kr[d];
    } else {
      const float* kr = k_cache + (size_t)idx*DIM + h*HD;
      for (int d = 0; d < HD; d++) s += q0[d] * kr[d];
    }
    if (m) {
      const float* ir = inner + (size_t)g * INNER_D;
      float s2 = 0.f;
      for (int j = 0; j < INNER_D; j++) s2 += ir[j] * w2q[j];
      s += s2;
    }
    p[t] = s;
  }
  __syncthreads();
  float lm = (t < NPOS) ? p[t] : -1e30f;
  lm = wred_max(lm);
  if (lane == 0) red[wv] = lm;
  __syncthreads();
  float mx = fmaxf(fmaxf(red[0], red[1]), fmaxf(red[2], red[3]));
  float lp = 0.f;
  if (t < NPOS) { lp = __expf(p[t] - mx); p[t] = lp; }
  float ls = wred_sum(lp);
  if (lane == 0) red[8 + wv] = ls;
  __syncthreads();
  float inv = 1.0f / (red[8] + red[9] + red[10] + red[11]);
  float tp = 0.f;
  for (int n = wv; n < NPOS; n += 4) {
    if (smk[n]) tp += p[n] * inner[(size_t)(fb*NPOS + n)*INNER_D + lane];
  }
  pacc[wv][lane] = tp;
  __syncthreads();
  if (t < INNER_D) tj[t] = pacc[0][t] + pacc[1][t] + pacc[2][t] + pacc[3][t];
  __syncthreads();
  float va = 0.f;
  for (int n = wv; n < NPOS; n += 4) {
    float pn = p[n];
    int idx = sidx[n];
    float vvv;
    if (idx >= NC) vvv = (float)v_new[(size_t)(idx - NC)*DIM + h*HD + lane];
    else           vvv = v_cache[(size_t)idx*DIM + h*HD + lane];
    va += pn * vvv;
  }
  __syncthreads();
  pacc[wv][lane] = va;
  __syncthreads();
  if (t < HD) {
    float o = pacc[0][t] + pacc[1][t] + pacc[2][t] + pacc[3][t];
    const float* wv2 = w2 + 3*DIM + h*HD + t;   // vd columns
    float dd = 0.f;
    for (int j = 0; j < INNER_D; j++) dd += tj[j] * wv2[(size_t)j*FF];
    pre_cls[(size_t)fb*DIM + h*HD + t] = (o + dd) * inv;
  }
}

// ---------------------------------------------------------------------------
// K9: out0 = h_cls + (sum_s partW) + bo;  yln = LN2(out0).  One block per row. (12 slabs)
__launch_bounds__(256)
__global__ void reduce_wo_ln_kernel(const float* __restrict__ partW, const float* __restrict__ bo,
                                    const float* __restrict__ h_cls, const float* __restrict__ g,
                                    const float* __restrict__ b, float* __restrict__ out0,
                                    float* __restrict__ yln)
{
  int row = blockIdx.x, t = threadIdx.x;
  float v[3];
  #pragma unroll
  for (int j = 0; j < 3; j++) {
    int c = t + j*256;
    float s = h_cls[(size_t)row*DIM + c] + bo[c];
    #pragma unroll
    for (int ks = 0; ks < 12; ks++) s += partW[((size_t)ks*FB_N + row)*DIM + c];
    v[j] = s;
    out0[(size_t)row*DIM + c] = s;
  }
  float sm = wred_sum(v[0] + v[1] + v[2]);
  float sq = wred_sum(v[0]*v[0] + v[1]*v[1] + v[2]*v[2]);
  __shared__ float red[8];
  int wv = t >> 6, ln = t & 63;
  if (ln == 0) { red[wv] = sm; red[4 + wv] = sq; }
  __syncthreads();
  float mean = (red[0]+red[1]+red[2]+red[3]) * (1.f/DIM);
  float var  = (red[4]+red[5]+red[6]+red[7]) * (1.f/DIM) - mean*mean;
  float rr = rsqrtf(var + 1e-5f);
  #pragma unroll
  for (int j = 0; j < 3; j++) {
    int c = t + j*256;
    yln[(size_t)row*DIM + c] = (v[j] - mean) * rr * g[c] + b[c];
  }
}

// K10: t1 = quick_gelu(sum_s partF1 + fc1b)    (6 slabs)
__global__ void reduce_gelu_kernel(const float* __restrict__ partF1, const float* __restrict__ b1,
                                   float* __restrict__ t1)
{
  int i = blockIdx.x * 256 + threadIdx.x;   // < 196608
  int c = i % FF;
  float v = b1[c];
  #pragma unroll
  for (int s = 0; s < 6; s++) v += partF1[(size_t)s*FB_N*FF + i];
  t1[i] = v / (1.0f + __expf(-1.702f * v));
}

// K11: d_out = out0 + fc2_b + sum_s partF2     (24 slabs)
__global__ void final_reduce_kernel(const float* __restrict__ out0, const float* __restrict__ b2,
                                    const float* __restrict__ partF2, float* __restrict__ dout)
{
  int i = blockIdx.x * 256 + threadIdx.x;   // < 49152
  int c = i % DIM;
  float v = out0[i] + b2[c];
  #pragma unroll
  for (int s = 0; s < 24; s++) v += partF2[(size_t)s*FB_N*DIM + i];
  dout[i] = v;
}

// ---------------------------------------------------------------------------
extern "C" void kernel_launch(void* const* d_in, const int* in_sizes, int n_in,
                              void* d_out, int out_size, void* d_ws, size_t ws_size,
                              hipStream_t stream)
{
  const float* hs   = (const float*)d_in[0];
  const float* dpp  = (const float*)d_in[1];
  const float* hqkv = (const float*)d_in[2];
  const float* ln1g = (const float*)d_in[3];
  const float* ln1b = (const float*)d_in[4];
  const float* wq   = (const float*)d_in[5];
  const float* bq   = (const float*)d_in[6];
  const float* wk   = (const float*)d_in[7];
  const float* bk   = (const float*)d_in[8];
  const float* wvw  = (const float*)d_in[9];
  const float* bv   = (const float*)d_in[10];
  const float* w1   = (const float*)d_in[11];
  const float* w2   = (const float*)d_in[12];
  const float* wo   = (const float*)d_in[13];
  const float* bo   = (const float*)d_in[14];
  const float* ln2g = (const float*)d_in[15];
  const float* ln2b = (const float*)d_in[16];
  const float* fc1w = (const float*)d_in[17];
  const float* fc1b = (const float*)d_in[18];
  const float* fc2w = (const float*)d_in[19];
  const float* fc2b = (const float*)d_in[20];
  const int*   gidx = (const int*)d_in[21];
  const unsigned char* rmap = (const unsigned char*)d_in[22];
  float* outp = (float*)d_out;

  char* ws = (char*)d_ws;
  size_t off = 0;
  auto alloc = [&](size_t bytes) { void* p = ws + off; off += (bytes + 255) & ~(size_t)255; return p; };
  unsigned char* mask = (unsigned char*)alloc(TT);
  __bf16* xbf   = (__bf16*)alloc((size_t)TT * DIM * 2);
  __bf16* wkT   = (__bf16*)alloc((size_t)DIM * DIM * 2);
  __bf16* wvT   = (__bf16*)alloc((size_t)DIM * DIM * 2);
  __bf16* k_new = (__bf16*)alloc((size_t)TT * DIM * 2);
  __bf16* v_new = (__bf16*)alloc((size_t)TT * DIM * 2);
  float* inner  = (float*)alloc((size_t)TT * INNER_D * 4);
  float* h_cls  = (float*)alloc((size_t)FB_N * DIM * 4);
  float* qbase  = (float*)alloc((size_t)FB_N * DIM * 4);
  float* Xq     = (float*)alloc((size_t)FB_N * DIM * 4);
  float* q0s    = (float*)alloc((size_t)FB_N * DIM * 4);
  float* precls = (float*)alloc((size_t)FB_N * DIM * 4);
  float* out0   = (float*)alloc((size_t)FB_N * DIM * 4);
  float* yln    = (float*)alloc((size_t)FB_N * DIM * 4);
  float* t1     = (float*)alloc((size_t)FB_N * FF * 4);
  float* partQ  = (float*)alloc((size_t)12 * FB_N * DIM * 4);
  float* partW  = (float*)alloc((size_t)12 * FB_N * DIM * 4);
  float* partF1 = (float*)alloc((size_t)6  * FB_N * FF  * 4);
  float* partF2 = (float*)alloc((size_t)24 * FB_N * DIM * 4);
  (void)ws_size; (void)in_sizes; (void)n_in; (void)out_size;

  mask_norm_kernel<<<1, 256, 0, stream>>>(rmap, mask);
  ln_kernel<<<TT, 256, 0, stream>>>(hs, ln1g, ln1b, xbf);
  transpose_w_kernel<<<dim3(24, 24, 2), dim3(32, 8), 0, stream>>>(wk, wvw, wkT, wvT);
  kv_gemm_kernel<<<dim3(TT/64, DIM/64), 256, 0, stream>>>(xbf, wkT, wvT, bk, bv, k_new, v_new);
  inner_kernel<<<TT/64, 256, 0, stream>>>(dpp, w1, inner);
  cls_gather_kernel<<<FB_N, 256, 0, stream>>>(hs, hqkv, xbf, bq, w2, inner, gidx, mask,
                                              h_cls, qbase, Xq);
  // q0s = (qbase + Xq @ wq) * SCALE   (zero Xq rows for cached fb's)
  pgemm_kernel<<<dim3(12, 12), 256, 0, stream>>>(Xq, wq, partQ, DIM, DIM, 64);
  reduce_q_kernel<<<192, 256, 0, stream>>>(qbase, partQ, q0s);
  attn_cls_kernel<<<FB_N * NH, 256, 0, stream>>>(hqkv, k_new, v_new, w2, inner, gidx, mask, q0s, precls);
  // out0 = h_cls + precls@wo + bo ; yln = LN2(out0)
  pgemm_kernel<<<dim3(12, 12), 256, 0, stream>>>(precls, wo, partW, DIM, DIM, 64);
  reduce_wo_ln_kernel<<<FB_N, 256, 0, stream>>>(partW, bo, h_cls, ln2g, ln2b, out0, yln);
  // t1 = qgelu(yln@fc1w + fc1b)
  pgemm_kernel<<<dim3(48, 6), 256, 0, stream>>>(yln, fc1w, partF1, FF, DIM, 128);
  reduce_gelu_kernel<<<768, 256, 0, stream>>>(partF1, fc1b, t1);
  // d_out = out0 + t1@fc2w + fc2b
  pgemm_kernel<<<dim3(12, 24), 256, 0, stream>>>(t1, fc2w, partF2, DIM, FF, 128);
  final_reduce_kernel<<<192, 256, 0, stream>>>(out0, fc2b, partF2, outp);
}

// Round 4
// 295.371 us; speedup vs baseline: 2.8733x; 1.0191x over previous
//
#include <hip/hip_runtime.h>
#include <hip/hip_bf16.h>

// Problem constants
#define TT 12608          // 4*B*N rows of hs
#define NC 3152           // B*N cache rows (= 16*197)
#define DIM 768
#define NPOS 197
#define NH 12
#define HD 64
#define FB_N 64           // 4*B
#define FF 3072
#define INNER_D 64
#define NCOLS 1536        // K cols + V cols combined

typedef __bf16 bf16x8 __attribute__((ext_vector_type(8)));
typedef float f32x4 __attribute__((ext_vector_type(4)));

__device__ inline float wred_sum(float v){
  #pragma unroll
  for (int o = 32; o > 0; o >>= 1) v += __shfl_down(v, o, 64);
  return v;
}
__device__ inline float wred_max(float v){
  #pragma unroll
  for (int o = 32; o > 0; o >>= 1) v = fmaxf(v, __shfl_down(v, o, 64));
  return v;
}

// ---------------------------------------------------------------------------
// K1: normalize reuse_map to uint8 regardless of harness dtype (int32/int8/f32).
__global__ void mask_norm_kernel(const unsigned char* __restrict__ rm,
                                 unsigned char* __restrict__ mask)
{
  __shared__ int flagA, flagB;
  if (threadIdx.x == 0) { flagA = 0; flagB = 0; }
  __syncthreads();
  int la = 0, lb = 0;
  for (int i = threadIdx.x; i < TT; i += blockDim.x) {
    unsigned char v = rm[i];
    if (v) { if (i & 3) la = 1; else lb = 1; }
  }
  if (la) atomicOr(&flagA, 1);
  if (lb) atomicOr(&flagB, 1);
  __syncthreads();
  int mode = (!flagA) ? 0 : (flagB ? 1 : 2); // 0=int32, 1=byte, 2=f32
  for (int i = threadIdx.x; i < TT; i += blockDim.x) {
    unsigned char m;
    if (mode == 0)      m = ((const int*)rm)[i] != 0;
    else if (mode == 1) m = rm[i] != 0;
    else                m = ((const float*)rm)[i] != 0.0f;
    mask[i] = m;
  }
}

// ---------------------------------------------------------------------------
// K2: row LayerNorm over 768 cols -> bf16.
__launch_bounds__(256)
__global__ void ln_kernel(const float* __restrict__ in, const float* __restrict__ g,
                          const float* __restrict__ b, __bf16* __restrict__ outp)
{
  int row = blockIdx.x, t = threadIdx.x;
  const float* x = in + (size_t)row * DIM;
  float v0 = x[t], v1 = x[t + 256], v2 = x[t + 512];
  float s = wred_sum(v0 + v1 + v2);
  float q = wred_sum(v0*v0 + v1*v1 + v2*v2);
  __shared__ float red[8];
  int wv = t >> 6, ln = t & 63;
  if (ln == 0) { red[wv] = s; red[4 + wv] = q; }
  __syncthreads();
  float mean = (red[0]+red[1]+red[2]+red[3]) * (1.f/DIM);
  float var  = (red[4]+red[5]+red[6]+red[7]) * (1.f/DIM) - mean*mean;
  float rr = rsqrtf(var + 1e-5f);
  #pragma unroll
  for (int j = 0; j < 3; j++) {
    int c = t + j*256;
    float v = (j==0) ? v0 : (j==1) ? v1 : v2;
    outp[(size_t)row*DIM + c] = (__bf16)((v - mean) * rr * g[c] + b[c]);
  }
}

// ---------------------------------------------------------------------------
// K3: transpose wk/wv (768x768 f32) -> combined bf16 B^T buffer wcatT[1536][768].
__global__ void transpose_w_kernel(const float* __restrict__ wk, const float* __restrict__ wv,
                                   __bf16* __restrict__ wcatT)
{
  const float* src = blockIdx.z ? wv : wk;
  __bf16* dst = wcatT + (blockIdx.z ? (size_t)768 * DIM : 0);
  __shared__ float tile[32][33];
  int bx = blockIdx.x, by = blockIdx.y;
  int tx = threadIdx.x, ty = threadIdx.y;
  #pragma unroll
  for (int i = 0; i < 32; i += 8)
    tile[ty + i][tx] = src[(size_t)(by*32 + ty + i) * DIM + bx*32 + tx];
  __syncthreads();
  #pragma unroll
  for (int i = 0; i < 32; i += 8)
    dst[(size_t)(bx*32 + ty + i) * DIM + by*32 + tx] = (__bf16)tile[tx][ty + i];
}

// ---------------------------------------------------------------------------
// K4: [k_new | v_new] = xbf @ wcatT^T (+bias) via bf16 MFMA 16x16x32.
// Tile 128x256, 8 waves (2x4 grid, each 64x64 = 4x4 frags), BK=64.
// Padded LDS [r][72] -> conflict-free b128 reads/writes. Reg-staged dbuf.
// Block remap: all 6 col-tiles of a row-panel run consecutively on one XCD
// so the A panel is fetched from HBM once (L2-resident thereafter).
__launch_bounds__(512)
__global__ void kv_gemm_kernel(const __bf16* __restrict__ xbf, const __bf16* __restrict__ wcatT,
                               const float* __restrict__ bk, const float* __restrict__ bv,
                               __bf16* __restrict__ k_new, __bf16* __restrict__ v_new)
{
  // ---- block remap: 99 row-panels x 6 col-tiles, panel->XCD bijective split
  int bid = blockIdx.x;              // grid = 8 * 78 = 624
  int xcd = bid & 7, slot = bid >> 3;
  int pstart, pcnt;                  // 99 panels: q=12, r=3
  if (xcd < 3) { pstart = xcd * 13; pcnt = 13; }
  else         { pstart = 39 + (xcd - 3) * 12; pcnt = 12; }
  if (slot >= pcnt * 6) return;
  int row0 = (pstart + slot / 6) * 128;
  int col0 = (slot % 6) * 256;

  __shared__ __align__(16) __bf16 As[128][72];
  __shared__ __align__(16) __bf16 Bs[256][72];
  int t = threadIdx.x;
  int lane = t & 63, wid = t >> 6;
  int wr = wid >> 2, wc = wid & 3;      // 2 x 4 wave grid
  int fr = lane & 15, fg = lane >> 4;

  // staging: each thread 2 A-loads + 4 B-loads of 16B per K-step
  int sar = t >> 3;                     // 0..63
  int sac = (t & 7) * 8;                // bf16 col
  const __bf16* aG0 = xbf + (size_t)(row0 + sar) * DIM + sac;                 // rows <= 12607 always
  const __bf16* aG1 = xbf + (size_t)min(row0 + 64 + sar, TT - 1) * DIM + sac; // clamp tail
  const __bf16* bG  = wcatT + (size_t)(col0 + sar) * DIM + sac;

  f32x4 acc[4][4];
  #pragma unroll
  for (int m = 0; m < 4; m++)
    #pragma unroll
    for (int n = 0; n < 4; n++) acc[m][n] = (f32x4){0.f, 0.f, 0.f, 0.f};

  // prologue: tile 0
  uint4 ra0 = *(const uint4*)(aG0);
  uint4 ra1 = *(const uint4*)(aG1);
  uint4 rb0 = *(const uint4*)(bG);
  uint4 rb1 = *(const uint4*)(bG + (size_t)64 * DIM);
  uint4 rb2 = *(const uint4*)(bG + (size_t)128 * DIM);
  uint4 rb3 = *(const uint4*)(bG + (size_t)192 * DIM);
  *(uint4*)&As[sar][sac] = ra0;
  *(uint4*)&As[sar + 64][sac] = ra1;
  *(uint4*)&Bs[sar][sac] = rb0;
  *(uint4*)&Bs[sar + 64][sac] = rb1;
  *(uint4*)&Bs[sar + 128][sac] = rb2;
  *(uint4*)&Bs[sar + 192][sac] = rb3;
  __syncthreads();

  for (int k0 = 0; k0 < DIM; k0 += 64) {
    int kn = k0 + 64;
    bool more = kn < DIM;
    if (more) {           // issue next-tile loads early; latency hides under MFMAs
      ra0 = *(const uint4*)(aG0 + kn);
      ra1 = *(const uint4*)(aG1 + kn);
      rb0 = *(const uint4*)(bG + kn);
      rb1 = *(const uint4*)(bG + (size_t)64 * DIM + kn);
      rb2 = *(const uint4*)(bG + (size_t)128 * DIM + kn);
      rb3 = *(const uint4*)(bG + (size_t)192 * DIM + kn);
    }
    #pragma unroll
    for (int kk = 0; kk < 2; kk++) {
      bf16x8 af[4], bf[4];
      #pragma unroll
      for (int m = 0; m < 4; m++)
        af[m] = *(const bf16x8*)&As[wr*64 + m*16 + fr][kk*32 + (fg << 3)];
      #pragma unroll
      for (int n = 0; n < 4; n++)
        bf[n] = *(const bf16x8*)&Bs[wc*64 + n*16 + fr][kk*32 + (fg << 3)];
      #pragma unroll
      for (int m = 0; m < 4; m++)
        #pragma unroll
        for (int n = 0; n < 4; n++)
          acc[m][n] = __builtin_amdgcn_mfma_f32_16x16x32_bf16(af[m], bf[n], acc[m][n], 0, 0, 0);
    }
    __syncthreads();
    if (more) {
      *(uint4*)&As[sar][sac] = ra0;
      *(uint4*)&As[sar + 64][sac] = ra1;
      *(uint4*)&Bs[sar][sac] = rb0;
      *(uint4*)&Bs[sar + 64][sac] = rb1;
      *(uint4*)&Bs[sar + 128][sac] = rb2;
      *(uint4*)&Bs[sar + 192][sac] = rb3;
      __syncthreads();
    }
  }

  // epilogue: C/D layout col=lane&15, row=(lane>>4)*4+reg  [verified m89/m91]
  bool isK = (col0 < 768);               // uniform per block (col range is 256 wide)
  #pragma unroll
  for (int n = 0; n < 4; n++) {
    int ocol = col0 + wc*64 + n*16 + fr;
    float bias = isK ? bk[ocol] : bv[ocol - 768];
    __bf16* dst = isK ? k_new : v_new;
    int dcol = isK ? ocol : ocol - 768;
    #pragma unroll
    for (int m = 0; m < 4; m++) {
      int orow = row0 + wr*64 + m*16 + fg*4;
      #pragma unroll
      for (int r = 0; r < 4; r++) {
        int rr = orow + r;
        if (rr < TT) dst[(size_t)rr * DIM + dcol] = (__bf16)(acc[m][n][r] + bias);
      }
    }
  }
}

// ---------------------------------------------------------------------------
// K5: inner = gelu_tanh(diff_pre_proj @ rest_w1)   (12608 x 64)
__launch_bounds__(256)
__global__ void inner_kernel(const float* __restrict__ dpp, const float* __restrict__ w1,
                             float* __restrict__ inner)
{
  __shared__ __align__(16) float Xs[64][68];
  __shared__ __align__(16) float Ws[64][64];
  int t = threadIdx.x;
  int r = t >> 2, c0 = (t & 3) << 4;
  int row0 = blockIdx.x * 64;
  float acc[16];
  #pragma unroll
  for (int i = 0; i < 16; i++) acc[i] = 0.f;
  for (int k0 = 0; k0 < DIM; k0 += 64) {
    #pragma unroll
    for (int j = 0; j < 4; j++) {
      int v = t + 256*j;
      int rr = v >> 4, c4 = (v & 15) << 2;
      *(float4*)&Xs[rr][c4] = *(const float4*)&dpp[(size_t)(row0 + rr)*DIM + k0 + c4];
      *(float4*)&Ws[rr][c4] = *(const float4*)&w1[(size_t)(k0 + rr)*INNER_D + c4];
    }
    __syncthreads();
    for (int kk = 0; kk < 64; kk++) {
      float xv = Xs[r][kk];
      #pragma unroll
      for (int c = 0; c < 16; c++) acc[c] += xv * Ws[kk][c0 + c];
    }
    __syncthreads();
  }
  #pragma unroll
  for (int c = 0; c < 16; c++) {
    float x = acc[c];
    float u = 0.7978845608028654f * (x + 0.044715f * x * x * x);
    inner[(size_t)(row0 + r)*INNER_D + c0 + c] = 0.5f * x * (1.0f + tanhf(u));
  }
}

// ---------------------------------------------------------------------------
// K6: per (f,b): h_cls row (gather + masked hd), qbase row (cache/bias + masked qd),
//     and compact Xq row (fresh LN row, else zero) for the batched Q GEMM.
__launch_bounds__(256)
__global__ void cls_gather_kernel(const float* __restrict__ hs, const float* __restrict__ hqkv,
                                  const __bf16* __restrict__ xbf, const float* __restrict__ bq,
                                  const float* __restrict__ w2, const float* __restrict__ inner,
                                  const int* __restrict__ gidx, const unsigned char* __restrict__ mask,
                                  float* __restrict__ h_cls, float* __restrict__ qbase,
                                  float* __restrict__ Xq)
{
  int fb = blockIdx.x, t = threadIdx.x;
  int g0 = fb * NPOS;
  int idx = gidx[g0];
  int m = mask[g0];
  const float* q_cache = hqkv + (size_t)NC * DIM;
  __shared__ float inn[INNER_D];
  if (t < INNER_D) inn[t] = inner[(size_t)g0 * INNER_D + t];
  __syncthreads();
  bool fresh = idx >= NC;
  for (int c = t; c < DIM; c += 256) {
    float xv = fresh ? (float)xbf[(size_t)(idx - NC)*DIM + c] : 0.f;
    Xq[(size_t)fb*DIM + c] = xv;
    float hv = fresh ? hs[(size_t)(idx - NC)*DIM + c] : hqkv[(size_t)idx*DIM + c];
    float qb = fresh ? bq[c] : q_cache[(size_t)idx*DIM + c];
    if (m) {
      float hd = 0.f, qd = 0.f;
      #pragma unroll 8
      for (int j = 0; j < INNER_D; j++) {
        float iv = inn[j];
        hd += iv * w2[(size_t)j*FF + c];
        qd += iv * w2[(size_t)j*FF + DIM + c];
      }
      hv += hd; qb += qd;
    }
    h_cls[(size_t)fb*DIM + c] = hv;
    qbase[(size_t)fb*DIM + c] = qb;
  }
}

// ---------------------------------------------------------------------------
// K7: partial GEMM, M=64 fixed. grid (N/64, K/kChunk), 256 thr.
__launch_bounds__(256)
__global__ void pgemm_kernel(const float* __restrict__ X, const float* __restrict__ W,
                             float* __restrict__ part, int N, int K, int kChunk)
{
  int t = threadIdx.x;
  int c = t & 63;
  int rq = t >> 6;
  int col0 = blockIdx.x * 64;
  int k0base = blockIdx.y * kChunk;
  __shared__ __align__(16) float Xs[64][68];
  float acc[16];
  #pragma unroll
  for (int i = 0; i < 16; i++) acc[i] = 0.f;
  for (int k0 = k0base; k0 < k0base + kChunk; k0 += 64) {
    #pragma unroll
    for (int j = 0; j < 4; j++) {
      int v = t + 256*j;
      int rr = v >> 4, cc = (v & 15) << 2;
      *(float4*)&Xs[rr][cc] = *(const float4*)&X[(size_t)rr*K + k0 + cc];
    }
    __syncthreads();
    const float* Wp = W + (size_t)k0*N + col0 + c;
    #pragma unroll 4
    for (int kk = 0; kk < 64; kk += 4) {
      float w0 = Wp[(size_t)(kk+0)*N];
      float w1 = Wp[(size_t)(kk+1)*N];
      float w2 = Wp[(size_t)(kk+2)*N];
      float w3 = Wp[(size_t)(kk+3)*N];
      #pragma unroll
      for (int r = 0; r < 16; r++) {
        float4 xv = *(const float4*)&Xs[rq*16 + r][kk];
        acc[r] += xv.x*w0 + xv.y*w1 + xv.z*w2 + xv.w*w3;
      }
    }
    __syncthreads();
  }
  #pragma unroll
  for (int r = 0; r < 16; r++)
    part[((size_t)blockIdx.y*64 + rq*16 + r)*N + col0 + c] = acc[r];
}

// K7b: q0s = (qbase + sum_s partQ) * SCALE     (12 slabs)
__global__ void reduce_q_kernel(const float* __restrict__ qbase, const float* __restrict__ partQ,
                                float* __restrict__ q0s)
{
  int i = blockIdx.x * 256 + threadIdx.x;   // < 49152
  float v = qbase[i];
  #pragma unroll
  for (int s = 0; s < 12; s++) v += partQ[(size_t)s*FB_N*DIM + i];
  q0s[i] = v * 0.125f;
}

// ---------------------------------------------------------------------------
// K8: CLS-row attention with low-rank diff folded in algebraically.
__launch_bounds__(256)
__global__ void attn_cls_kernel(const float* __restrict__ hqkv, const __bf16* __restrict__ k_new,
                                const __bf16* __restrict__ v_new, const float* __restrict__ w2,
                                const float* __restrict__ inner, const int* __restrict__ gidx,
                                const unsigned char* __restrict__ mask,
                                const float* __restrict__ q0s, float* __restrict__ pre_cls)
{
  int bid = blockIdx.x;
  int fb = bid / NH, h = bid % NH;
  int t = threadIdx.x;
  int lane = t & 63, wv = t >> 6;
  const float* k_cache = hqkv + (size_t)2 * NC * DIM;
  const float* v_cache = hqkv + (size_t)3 * NC * DIM;
  __shared__ float q0[HD], w2q[INNER_D], tj[INNER_D];
  __shared__ float p[200];
  __shared__ int sidx[200];
  __shared__ unsigned char smk[200];
  __shared__ float red[16];
  __shared__ float pacc[4][64];
  if (t < HD) q0[t] = q0s[(size_t)fb*DIM + h*HD + t];
  __syncthreads();
  if (t < INNER_D) {
    const float* wr = w2 + (size_t)t*FF + 2*DIM + h*HD;  // kd columns
    float s = 0.f;
    for (int d = 0; d < HD; d++) s += q0[d] * wr[d];
    w2q[t] = s;
  }
  __syncthreads();
  if (t < NPOS) {
    int g = fb * NPOS + t;
    int idx = gidx[g];
    unsigned char m = mask[g];
    sidx[t] = idx; smk[t] = m;
    float s = 0.f;
    if (idx >= NC) {
      const __bf16* kr = k_new + (size_t)(idx - NC)*DIM + h*HD;
      #pragma unroll
      for (int d0 = 0; d0 < HD; d0 += 8) {
        bf16x8 kv = *(const bf16x8*)(kr + d0);
        #pragma unroll
        for (int j = 0; j < 8; j++) s += q0[d0 + j] * (float)kv[j];
      }
    } else {
      const float* kr = k_cache + (size_t)idx*DIM + h*HD;
      #pragma unroll
      for (int d0 = 0; d0 < HD; d0 += 4) {
        float4 kv = *(const float4*)(kr + d0);
        s += q0[d0]*kv.x + q0[d0+1]*kv.y + q0[d0+2]*kv.z + q0[d0+3]*kv.w;
      }
    }
    if (m) {
      const float4* ir4 = (const float4*)(inner + (size_t)g * INNER_D);
      float s2 = 0.f;
      #pragma unroll
      for (int j0 = 0; j0 < 16; j0++) {
        float4 iv = ir4[j0];
        s2 += iv.x*w2q[j0*4] + iv.y*w2q[j0*4+1] + iv.z*w2q[j0*4+2] + iv.w*w2q[j0*4+3];
      }
      s += s2;
    }
    p[t] = s;
  }
  __syncthreads();
  float lm = (t < NPOS) ? p[t] : -1e30f;
  lm = wred_max(lm);
  if (lane == 0) red[wv] = lm;
  __syncthreads();
  float mx = fmaxf(fmaxf(red[0], red[1]), fmaxf(red[2], red[3]));
  float lp = 0.f;
  if (t < NPOS) { lp = __expf(p[t] - mx); p[t] = lp; }
  float ls = wred_sum(lp);
  if (lane == 0) red[8 + wv] = ls;
  __syncthreads();
  float inv = 1.0f / (red[8] + red[9] + red[10] + red[11]);
  float tp = 0.f;
  for (int n = wv; n < NPOS; n += 4) {
    if (smk[n]) tp += p[n] * inner[(size_t)(fb*NPOS + n)*INNER_D + lane];
  }
  pacc[wv][lane] = tp;
  __syncthreads();
  if (t < INNER_D) tj[t] = pacc[0][t] + pacc[1][t] + pacc[2][t] + pacc[3][t];
  __syncthreads();
  float va = 0.f;
  for (int n = wv; n < NPOS; n += 4) {
    float pn = p[n];
    int idx = sidx[n];
    float vvv;
    if (idx >= NC) vvv = (float)v_new[(size_t)(idx - NC)*DIM + h*HD + lane];
    else           vvv = v_cache[(size_t)idx*DIM + h*HD + lane];
    va += pn * vvv;
  }
  __syncthreads();
  pacc[wv][lane] = va;
  __syncthreads();
  if (t < HD) {
    float o = pacc[0][t] + pacc[1][t] + pacc[2][t] + pacc[3][t];
    const float* wv2 = w2 + 3*DIM + h*HD + t;   // vd columns
    float dd = 0.f;
    for (int j = 0; j < INNER_D; j++) dd += tj[j] * wv2[(size_t)j*FF];
    pre_cls[(size_t)fb*DIM + h*HD + t] = (o + dd) * inv;
  }
}

// ---------------------------------------------------------------------------
// K9: out0 = h_cls + (sum_s partW) + bo;  yln = LN2(out0).  One block per row. (12 slabs)
__launch_bounds__(256)
__global__ void reduce_wo_ln_kernel(const float* __restrict__ partW, const float* __restrict__ bo,
                                    const float* __restrict__ h_cls, const float* __restrict__ g,
                                    const float* __restrict__ b, float* __restrict__ out0,
                                    float* __restrict__ yln)
{
  int row = blockIdx.x, t = threadIdx.x;
  float v[3];
  #pragma unroll
  for (int j = 0; j < 3; j++) {
    int c = t + j*256;
    float s = h_cls[(size_t)row*DIM + c] + bo[c];
    #pragma unroll
    for (int ks = 0; ks < 12; ks++) s += partW[((size_t)ks*FB_N + row)*DIM + c];
    v[j] = s;
    out0[(size_t)row*DIM + c] = s;
  }
  float sm = wred_sum(v[0] + v[1] + v[2]);
  float sq = wred_sum(v[0]*v[0] + v[1]*v[1] + v[2]*v[2]);
  __shared__ float red[8];
  int wv = t >> 6, ln = t & 63;
  if (ln == 0) { red[wv] = sm; red[4 + wv] = sq; }
  __syncthreads();
  float mean = (red[0]+red[1]+red[2]+red[3]) * (1.f/DIM);
  float var  = (red[4]+red[5]+red[6]+red[7]) * (1.f/DIM) - mean*mean;
  float rr = rsqrtf(var + 1e-5f);
  #pragma unroll
  for (int j = 0; j < 3; j++) {
    int c = t + j*256;
    yln[(size_t)row*DIM + c] = (v[j] - mean) * rr * g[c] + b[c];
  }
}

// K10: t1 = quick_gelu(sum_s partF1 + fc1b)    (6 slabs)
__global__ void reduce_gelu_kernel(const float* __restrict__ partF1, const float* __restrict__ b1,
                                   float* __restrict__ t1)
{
  int i = blockIdx.x * 256 + threadIdx.x;   // < 196608
  int c = i % FF;
  float v = b1[c];
  #pragma unroll
  for (int s = 0; s < 6; s++) v += partF1[(size_t)s*FB_N*FF + i];
  t1[i] = v / (1.0f + __expf(-1.702f * v));
}

// K11: d_out = out0 + fc2_b + sum_s partF2     (24 slabs)
__global__ void final_reduce_kernel(const float* __restrict__ out0, const float* __restrict__ b2,
                                    const float* __restrict__ partF2, float* __restrict__ dout)
{
  int i = blockIdx.x * 256 + threadIdx.x;   // < 49152
  int c = i % DIM;
  float v = out0[i] + b2[c];
  #pragma unroll
  for (int s = 0; s < 24; s++) v += partF2[(size_t)s*FB_N*DIM + i];
  dout[i] = v;
}

// ---------------------------------------------------------------------------
extern "C" void kernel_launch(void* const* d_in, const int* in_sizes, int n_in,
                              void* d_out, int out_size, void* d_ws, size_t ws_size,
                              hipStream_t stream)
{
  const float* hs   = (const float*)d_in[0];
  const float* dpp  = (const float*)d_in[1];
  const float* hqkv = (const float*)d_in[2];
  const float* ln1g = (const float*)d_in[3];
  const float* ln1b = (const float*)d_in[4];
  const float* wq   = (const float*)d_in[5];
  const float* bq   = (const float*)d_in[6];
  const float* wk   = (const float*)d_in[7];
  const float* bk   = (const float*)d_in[8];
  const float* wvw  = (const float*)d_in[9];
  const float* bv   = (const float*)d_in[10];
  const float* w1   = (const float*)d_in[11];
  const float* w2   = (const float*)d_in[12];
  const float* wo   = (const float*)d_in[13];
  const float* bo   = (const float*)d_in[14];
  const float* ln2g = (const float*)d_in[15];
  const float* ln2b = (const float*)d_in[16];
  const float* fc1w = (const float*)d_in[17];
  const float* fc1b = (const float*)d_in[18];
  const float* fc2w = (const float*)d_in[19];
  const float* fc2b = (const float*)d_in[20];
  const int*   gidx = (const int*)d_in[21];
  const unsigned char* rmap = (const unsigned char*)d_in[22];
  float* outp = (float*)d_out;

  char* ws = (char*)d_ws;
  size_t off = 0;
  auto alloc = [&](size_t bytes) { void* p = ws + off; off += (bytes + 255) & ~(size_t)255; return p; };
  unsigned char* mask = (unsigned char*)alloc(TT);
  __bf16* xbf   = (__bf16*)alloc((size_t)TT * DIM * 2);
  __bf16* wcatT = (__bf16*)alloc((size_t)NCOLS * DIM * 2);
  __bf16* k_new = (__bf16*)alloc((size_t)TT * DIM * 2);
  __bf16* v_new = (__bf16*)alloc((size_t)TT * DIM * 2);
  float* inner  = (float*)alloc((size_t)TT * INNER_D * 4);
  float* h_cls  = (float*)alloc((size_t)FB_N * DIM * 4);
  float* qbase  = (float*)alloc((size_t)FB_N * DIM * 4);
  float* Xq     = (float*)alloc((size_t)FB_N * DIM * 4);
  float* q0s    = (float*)alloc((size_t)FB_N * DIM * 4);
  float* precls = (float*)alloc((size_t)FB_N * DIM * 4);
  float* out0   = (float*)alloc((size_t)FB_N * DIM * 4);
  float* yln    = (float*)alloc((size_t)FB_N * DIM * 4);
  float* t1     = (float*)alloc((size_t)FB_N * FF * 4);
  float* partQ  = (float*)alloc((size_t)12 * FB_N * DIM * 4);
  float* partW  = (float*)alloc((size_t)12 * FB_N * DIM * 4);
  float* partF1 = (float*)alloc((size_t)6  * FB_N * FF  * 4);
  float* partF2 = (float*)alloc((size_t)24 * FB_N * DIM * 4);
  (void)ws_size; (void)in_sizes; (void)n_in; (void)out_size;

  mask_norm_kernel<<<1, 256, 0, stream>>>(rmap, mask);
  ln_kernel<<<TT, 256, 0, stream>>>(hs, ln1g, ln1b, xbf);
  transpose_w_kernel<<<dim3(24, 24, 2), dim3(32, 8), 0, stream>>>(wk, wvw, wcatT);
  kv_gemm_kernel<<<624, 512, 0, stream>>>(xbf, wcatT, bk, bv, k_new, v_new);
  inner_kernel<<<TT/64, 256, 0, stream>>>(dpp, w1, inner);
  cls_gather_kernel<<<FB_N, 256, 0, stream>>>(hs, hqkv, xbf, bq, w2, inner, gidx, mask,
                                              h_cls, qbase, Xq);
  // q0s = (qbase + Xq @ wq) * SCALE   (zero Xq rows for cached fb's)
  pgemm_kernel<<<dim3(12, 12), 256, 0, stream>>>(Xq, wq, partQ, DIM, DIM, 64);
  reduce_q_kernel<<<192, 256, 0, stream>>>(qbase, partQ, q0s);
  attn_cls_kernel<<<FB_N * NH, 256, 0, stream>>>(hqkv, k_new, v_new, w2, inner, gidx, mask, q0s, precls);
  // out0 = h_cls + precls@wo + bo ; yln = LN2(out0)
  pgemm_kernel<<<dim3(12, 12), 256, 0, stream>>>(precls, wo, partW, DIM, DIM, 64);
  reduce_wo_ln_kernel<<<FB_N, 256, 0, stream>>>(partW, bo, h_cls, ln2g, ln2b, out0, yln);
  // t1 = qgelu(yln@fc1w + fc1b)
  pgemm_kernel<<<dim3(48, 6), 256, 0, stream>>>(yln, fc1w, partF1, FF, DIM, 128);
  reduce_gelu_kernel<<<768, 256, 0, stream>>>(partF1, fc1b, t1);
  // d_out = out0 + t1@fc2w + fc2b
  pgemm_kernel<<<dim3(12, 24), 256, 0, stream>>>(t1, fc2w, partF2, DIM, FF, 128);
  final_reduce_kernel<<<192, 256, 0, stream>>>(out0, fc2b, partF2, outp);
}

// Round 5
// 274.934 us; speedup vs baseline: 3.0869x; 1.0743x over previous
//
#include <hip/hip_runtime.h>
#include <hip/hip_bf16.h>

// Problem constants
#define TT 12608          // 4*B*N rows of hs
#define NC 3152           // B*N cache rows (= 16*197)
#define DIM 768
#define NPOS 197
#define NH 12
#define HD 64
#define FB_N 64           // 4*B
#define FF 3072
#define INNER_D 64
#define NCOLS 1536        // K cols + V cols combined

typedef __bf16 bf16x8 __attribute__((ext_vector_type(8)));
typedef float f32x4 __attribute__((ext_vector_type(4)));

__device__ inline float wred_sum(float v){
  #pragma unroll
  for (int o = 32; o > 0; o >>= 1) v += __shfl_down(v, o, 64);
  return v;
}
__device__ inline float wred_max(float v){
  #pragma unroll
  for (int o = 32; o > 0; o >>= 1) v = fmaxf(v, __shfl_down(v, o, 64));
  return v;
}

// async global->LDS, 16B per lane; LDS dest = wave-uniform base + lane*16
__device__ __forceinline__ void gl_lds16(const __bf16* g, __bf16* l) {
  __builtin_amdgcn_global_load_lds(
      (const __attribute__((address_space(1))) void*)g,
      (__attribute__((address_space(3))) void*)l, 16, 0, 0);
}

// ---------------------------------------------------------------------------
// K1: normalize reuse_map to uint8 regardless of harness dtype (int32/int8/f32).
__global__ void mask_norm_kernel(const unsigned char* __restrict__ rm,
                                 unsigned char* __restrict__ mask)
{
  __shared__ int flagA, flagB;
  if (threadIdx.x == 0) { flagA = 0; flagB = 0; }
  __syncthreads();
  int la = 0, lb = 0;
  for (int i = threadIdx.x; i < TT; i += blockDim.x) {
    unsigned char v = rm[i];
    if (v) { if (i & 3) la = 1; else lb = 1; }
  }
  if (la) atomicOr(&flagA, 1);
  if (lb) atomicOr(&flagB, 1);
  __syncthreads();
  int mode = (!flagA) ? 0 : (flagB ? 1 : 2); // 0=int32, 1=byte, 2=f32
  for (int i = threadIdx.x; i < TT; i += blockDim.x) {
    unsigned char m;
    if (mode == 0)      m = ((const int*)rm)[i] != 0;
    else if (mode == 1) m = rm[i] != 0;
    else                m = ((const float*)rm)[i] != 0.0f;
    mask[i] = m;
  }
}

// ---------------------------------------------------------------------------
// K1b: flag referenced fresh rows.
__global__ void flag_kernel(const int* __restrict__ gidx, int* __restrict__ flag)
{
  int g = blockIdx.x * 256 + threadIdx.x;
  if (g < TT) { int idx = gidx[g]; if (idx >= NC) flag[idx - NC] = 1; }
}

// K1c: single-block exclusive scan -> rowlist (compact->orig), remap (orig->compact), mc.
__launch_bounds__(1024)
__global__ void scan_kernel(const int* __restrict__ flag, int* __restrict__ rowlist,
                            int* __restrict__ remap, int* __restrict__ mc)
{
  __shared__ int wsum[16];
  __shared__ int base;
  int t = threadIdx.x, lane = t & 63, wv = t >> 6;
  if (t == 0) base = 0;
  __syncthreads();
  for (int start = 0; start < TT; start += 1024) {
    int i = start + t;
    int f = (i < TT) ? flag[i] : 0;
    unsigned long long mb = __ballot(f != 0);
    int rank = __popcll(mb & ((1ULL << lane) - 1ULL));
    if (lane == 0) wsum[wv] = __popcll(mb);
    __syncthreads();
    int woff = 0;
    for (int w2 = 0; w2 < wv; w2++) woff += wsum[w2];
    int pos = base + woff + rank;
    if (f) { rowlist[pos] = i; remap[i] = pos; }
    __syncthreads();
    if (t == 0) { int tot = 0; for (int w2 = 0; w2 < 16; w2++) tot += wsum[w2]; base += tot; }
    __syncthreads();
  }
  if (t == 0) mc[0] = base;
}

// ---------------------------------------------------------------------------
// K2: row LayerNorm over 768 cols -> bf16, COMPACT rows only (xbf[c] = LN(hs[rowlist[c]])).
__launch_bounds__(256)
__global__ void ln_kernel(const float* __restrict__ in, const float* __restrict__ g,
                          const float* __restrict__ b, __bf16* __restrict__ outp,
                          const int* __restrict__ rowlist, const int* __restrict__ mc)
{
  if ((int)blockIdx.x >= mc[0]) return;
  int row = rowlist[blockIdx.x];
  int t = threadIdx.x;
  const float* x = in + (size_t)row * DIM;
  float v0 = x[t], v1 = x[t + 256], v2 = x[t + 512];
  float s = wred_sum(v0 + v1 + v2);
  float q = wred_sum(v0*v0 + v1*v1 + v2*v2);
  __shared__ float red[8];
  int wv = t >> 6, ln = t & 63;
  if (ln == 0) { red[wv] = s; red[4 + wv] = q; }
  __syncthreads();
  float mean = (red[0]+red[1]+red[2]+red[3]) * (1.f/DIM);
  float var  = (red[4]+red[5]+red[6]+red[7]) * (1.f/DIM) - mean*mean;
  float rr = rsqrtf(var + 1e-5f);
  #pragma unroll
  for (int j = 0; j < 3; j++) {
    int c = t + j*256;
    float v = (j==0) ? v0 : (j==1) ? v1 : v2;
    outp[(size_t)blockIdx.x*DIM + c] = (__bf16)((v - mean) * rr * g[c] + b[c]);
  }
}

// ---------------------------------------------------------------------------
// K3: transpose wk/wv (768x768 f32) -> combined bf16 B^T buffer wcatT[1536][768].
__global__ void transpose_w_kernel(const float* __restrict__ wk, const float* __restrict__ wv,
                                   __bf16* __restrict__ wcatT)
{
  const float* src = blockIdx.z ? wv : wk;
  __bf16* dst = wcatT + (blockIdx.z ? (size_t)768 * DIM : 0);
  __shared__ float tile[32][33];
  int bx = blockIdx.x, by = blockIdx.y;
  int tx = threadIdx.x, ty = threadIdx.y;
  #pragma unroll
  for (int i = 0; i < 32; i += 8)
    tile[ty + i][tx] = src[(size_t)(by*32 + ty + i) * DIM + bx*32 + tx];
  __syncthreads();
  #pragma unroll
  for (int i = 0; i < 32; i += 8)
    dst[(size_t)(bx*32 + ty + i) * DIM + by*32 + tx] = (__bf16)tile[tx][ty + i];
}

// ---------------------------------------------------------------------------
// K4: [k_newc | v_newc] = xbf(compact) @ wcatT^T (+bias), m97 structure:
// 128x128 tile, 4 waves (2x2, each 64x64 = 4x4 frags), BK=32,
// global_load_lds(16B) staging, linear LDS, 2 barriers/K-step.
// XCD swizzle: panel p on XCD p%8; 12 col-tiles of a panel consecutive on that XCD.
__launch_bounds__(256)
__global__ void kv_gemm_kernel(const __bf16* __restrict__ xbf, const __bf16* __restrict__ wcatT,
                               const float* __restrict__ bk, const float* __restrict__ bv,
                               __bf16* __restrict__ k_newc, __bf16* __restrict__ v_newc,
                               const int* __restrict__ mc)
{
  int Mc = mc[0];
  int npanels = (Mc + 127) >> 7;
  int bid = blockIdx.x;                 // 8 * 13 * 12 = 1248
  int xcd = bid & 7, s = bid >> 3;
  int panel = (s / 12) * 8 + xcd;
  if (panel >= npanels) return;
  int col0 = (s % 12) * 128;
  int row0 = panel * 128;

  __shared__ __align__(16) __bf16 As[128][32];
  __shared__ __align__(16) __bf16 Bs[128][32];
  int t = threadIdx.x;
  int lane = t & 63, wid = t >> 6;
  int wr = wid >> 1, wc = wid & 1;
  int fr = lane & 15, fg = lane >> 4;

  int lr = t >> 2, lc = (t & 3) << 3;   // staging: row 0..63, col {0,8,16,24}
  int ar0 = min(row0 + lr, Mc - 1);
  int ar1 = min(row0 + 64 + lr, Mc - 1);
  const __bf16* aG0 = xbf + (size_t)ar0 * DIM + lc;
  const __bf16* aG1 = xbf + (size_t)ar1 * DIM + lc;
  const __bf16* bG0 = wcatT + (size_t)(col0 + lr) * DIM + lc;
  const __bf16* bG1 = wcatT + (size_t)(col0 + 64 + lr) * DIM + lc;
  __bf16* lA0 = &As[lr][lc];
  __bf16* lA1 = &As[64 + lr][lc];
  __bf16* lB0 = &Bs[lr][lc];
  __bf16* lB1 = &Bs[64 + lr][lc];

  f32x4 acc[4][4];
  #pragma unroll
  for (int m = 0; m < 4; m++)
    #pragma unroll
    for (int n = 0; n < 4; n++) acc[m][n] = (f32x4){0.f, 0.f, 0.f, 0.f};

  for (int k0 = 0; k0 < DIM; k0 += 32) {
    gl_lds16(aG0 + k0, lA0);
    gl_lds16(aG1 + k0, lA1);
    gl_lds16(bG0 + k0, lB0);
    gl_lds16(bG1 + k0, lB1);
    __syncthreads();                    // compiler drains vmcnt before s_barrier
    bf16x8 af[4], bb[4];
    #pragma unroll
    for (int m = 0; m < 4; m++) af[m] = *(const bf16x8*)&As[wr*64 + m*16 + fr][fg << 3];
    #pragma unroll
    for (int n = 0; n < 4; n++) bb[n] = *(const bf16x8*)&Bs[wc*64 + n*16 + fr][fg << 3];
    #pragma unroll
    for (int m = 0; m < 4; m++)
      #pragma unroll
      for (int n = 0; n < 4; n++)
        acc[m][n] = __builtin_amdgcn_mfma_f32_16x16x32_bf16(af[m], bb[n], acc[m][n], 0, 0, 0);
    __syncthreads();                    // all waves done reading before restage
  }

  // C/D layout: col = lane&15, row = (lane>>4)*4 + reg  [verified m89/m91]
  bool isK = (col0 < 768);
  const float* bias = isK ? bk : bv;
  __bf16* dst = isK ? k_newc : v_newc;
  int cbase = isK ? col0 : col0 - 768;
  #pragma unroll
  for (int n = 0; n < 4; n++) {
    int dcol = cbase + wc*64 + n*16 + fr;
    float bc = bias[dcol];
    #pragma unroll
    for (int m = 0; m < 4; m++) {
      int orow = row0 + wr*64 + m*16 + fg*4;
      #pragma unroll
      for (int r = 0; r < 4; r++) {
        int rr = orow + r;
        if (rr < Mc) dst[(size_t)rr * DIM + dcol] = (__bf16)(acc[m][n][r] + bc);
      }
    }
  }
}

// ---------------------------------------------------------------------------
// K5: inner = gelu_tanh(diff_pre_proj @ rest_w1)   (12608 x 64)
__launch_bounds__(256)
__global__ void inner_kernel(const float* __restrict__ dpp, const float* __restrict__ w1,
                             float* __restrict__ inner)
{
  __shared__ __align__(16) float Xs[64][68];
  __shared__ __align__(16) float Ws[64][64];
  int t = threadIdx.x;
  int r = t >> 2, c0 = (t & 3) << 4;
  int row0 = blockIdx.x * 64;
  float acc[16];
  #pragma unroll
  for (int i = 0; i < 16; i++) acc[i] = 0.f;
  for (int k0 = 0; k0 < DIM; k0 += 64) {
    #pragma unroll
    for (int j = 0; j < 4; j++) {
      int v = t + 256*j;
      int rr = v >> 4, c4 = (v & 15) << 2;
      *(float4*)&Xs[rr][c4] = *(const float4*)&dpp[(size_t)(row0 + rr)*DIM + k0 + c4];
      *(float4*)&Ws[rr][c4] = *(const float4*)&w1[(size_t)(k0 + rr)*INNER_D + c4];
    }
    __syncthreads();
    for (int kk = 0; kk < 64; kk++) {
      float xv = Xs[r][kk];
      #pragma unroll
      for (int c = 0; c < 16; c++) acc[c] += xv * Ws[kk][c0 + c];
    }
    __syncthreads();
  }
  #pragma unroll
  for (int c = 0; c < 16; c++) {
    float x = acc[c];
    float u = 0.7978845608028654f * (x + 0.044715f * x * x * x);
    inner[(size_t)(row0 + r)*INNER_D + c0 + c] = 0.5f * x * (1.0f + tanhf(u));
  }
}

// ---------------------------------------------------------------------------
// K6: per (f,b): h_cls row (gather + masked hd), qbase row (cache/bias + masked qd),
//     and compact Xq row (fresh LN row via remap, else zero).
__launch_bounds__(256)
__global__ void cls_gather_kernel(const float* __restrict__ hs, const float* __restrict__ hqkv,
                                  const __bf16* __restrict__ xbf, const float* __restrict__ bq,
                                  const float* __restrict__ w2, const float* __restrict__ inner,
                                  const int* __restrict__ gidx, const unsigned char* __restrict__ mask,
                                  const int* __restrict__ remap,
                                  float* __restrict__ h_cls, float* __restrict__ qbase,
                                  float* __restrict__ Xq)
{
  int fb = blockIdx.x, t = threadIdx.x;
  int g0 = fb * NPOS;
  int idx = gidx[g0];
  int m = mask[g0];
  const float* q_cache = hqkv + (size_t)NC * DIM;
  __shared__ float inn[INNER_D];
  if (t < INNER_D) inn[t] = inner[(size_t)g0 * INNER_D + t];
  __syncthreads();
  bool fresh = idx >= NC;
  int crow = fresh ? remap[idx - NC] : 0;
  for (int c = t; c < DIM; c += 256) {
    float xv = fresh ? (float)xbf[(size_t)crow*DIM + c] : 0.f;
    Xq[(size_t)fb*DIM + c] = xv;
    float hv = fresh ? hs[(size_t)(idx - NC)*DIM + c] : hqkv[(size_t)idx*DIM + c];
    float qb = fresh ? bq[c] : q_cache[(size_t)idx*DIM + c];
    if (m) {
      float hd = 0.f, qd = 0.f;
      #pragma unroll 8
      for (int j = 0; j < INNER_D; j++) {
        float iv = inn[j];
        hd += iv * w2[(size_t)j*FF + c];
        qd += iv * w2[(size_t)j*FF + DIM + c];
      }
      hv += hd; qb += qd;
    }
    h_cls[(size_t)fb*DIM + c] = hv;
    qbase[(size_t)fb*DIM + c] = qb;
  }
}

// ---------------------------------------------------------------------------
// K7: partial GEMM, M=64 fixed. grid (N/64, K/kChunk), 256 thr.
__launch_bounds__(256)
__global__ void pgemm_kernel(const float* __restrict__ X, const float* __restrict__ W,
                             float* __restrict__ part, int N, int K, int kChunk)
{
  int t = threadIdx.x;
  int c = t & 63;
  int rq = t >> 6;
  int col0 = blockIdx.x * 64;
  int k0base = blockIdx.y * kChunk;
  __shared__ __align__(16) float Xs[64][68];
  float acc[16];
  #pragma unroll
  for (int i = 0; i < 16; i++) acc[i] = 0.f;
  for (int k0 = k0base; k0 < k0base + kChunk; k0 += 64) {
    #pragma unroll
    for (int j = 0; j < 4; j++) {
      int v = t + 256*j;
      int rr = v >> 4, cc = (v & 15) << 2;
      *(float4*)&Xs[rr][cc] = *(const float4*)&X[(size_t)rr*K + k0 + cc];
    }
    __syncthreads();
    const float* Wp = W + (size_t)k0*N + col0 + c;
    #pragma unroll 4
    for (int kk = 0; kk < 64; kk += 4) {
      float w0 = Wp[(size_t)(kk+0)*N];
      float w1 = Wp[(size_t)(kk+1)*N];
      float w2 = Wp[(size_t)(kk+2)*N];
      float w3 = Wp[(size_t)(kk+3)*N];
      #pragma unroll
      for (int r = 0; r < 16; r++) {
        float4 xv = *(const float4*)&Xs[rq*16 + r][kk];
        acc[r] += xv.x*w0 + xv.y*w1 + xv.z*w2 + xv.w*w3;
      }
    }
    __syncthreads();
  }
  #pragma unroll
  for (int r = 0; r < 16; r++)
    part[((size_t)blockIdx.y*64 + rq*16 + r)*N + col0 + c] = acc[r];
}

// K7b: q0s = (qbase + sum_s partQ) * SCALE     (12 slabs)
__global__ void reduce_q_kernel(const float* __restrict__ qbase, const float* __restrict__ partQ,
                                float* __restrict__ q0s)
{
  int i = blockIdx.x * 256 + threadIdx.x;   // < 49152
  float v = qbase[i];
  #pragma unroll
  for (int s = 0; s < 12; s++) v += partQ[(size_t)s*FB_N*DIM + i];
  q0s[i] = v * 0.125f;
}

// ---------------------------------------------------------------------------
// K8: CLS-row attention with low-rank diff folded in algebraically.
__launch_bounds__(256)
__global__ void attn_cls_kernel(const float* __restrict__ hqkv, const __bf16* __restrict__ k_newc,
                                const __bf16* __restrict__ v_newc, const float* __restrict__ w2,
                                const float* __restrict__ inner, const int* __restrict__ gidx,
                                const unsigned char* __restrict__ mask, const int* __restrict__ remap,
                                const float* __restrict__ q0s, float* __restrict__ pre_cls)
{
  int bid = blockIdx.x;
  int fb = bid / NH, h = bid % NH;
  int t = threadIdx.x;
  int lane = t & 63, wv = t >> 6;
  const float* k_cache = hqkv + (size_t)2 * NC * DIM;
  const float* v_cache = hqkv + (size_t)3 * NC * DIM;
  __shared__ float q0[HD], w2q[INNER_D], tj[INNER_D];
  __shared__ float p[200];
  __shared__ int sidx[200];
  __shared__ unsigned char smk[200];
  __shared__ float red[16];
  __shared__ float pacc[4][64];
  if (t < HD) q0[t] = q0s[(size_t)fb*DIM + h*HD + t];
  __syncthreads();
  if (t < INNER_D) {
    const float* wr = w2 + (size_t)t*FF + 2*DIM + h*HD;  // kd columns
    float s = 0.f;
    for (int d = 0; d < HD; d++) s += q0[d] * wr[d];
    w2q[t] = s;
  }
  __syncthreads();
  if (t < NPOS) {
    int g = fb * NPOS + t;
    int idx = gidx[g];
    if (idx >= NC) idx = NC + remap[idx - NC];   // translate to compact index
    unsigned char m = mask[g];
    sidx[t] = idx; smk[t] = m;
    float s = 0.f;
    if (idx >= NC) {
      const __bf16* kr = k_newc + (size_t)(idx - NC)*DIM + h*HD;
      #pragma unroll
      for (int d0 = 0; d0 < HD; d0 += 8) {
        bf16x8 kv = *(const bf16x8*)(kr + d0);
        #pragma unroll
        for (int j = 0; j < 8; j++) s += q0[d0 + j] * (float)kv[j];
      }
    } else {
      const float* kr = k_cache + (size_t)idx*DIM + h*HD;
      #pragma unroll
      for (int d0 = 0; d0 < HD; d0 += 4) {
        float4 kv = *(const float4*)(kr + d0);
        s += q0[d0]*kv.x + q0[d0+1]*kv.y + q0[d0+2]*kv.z + q0[d0+3]*kv.w;
      }
    }
    if (m) {
      const float4* ir4 = (const float4*)(inner + (size_t)g * INNER_D);
      float s2 = 0.f;
      #pragma unroll
      for (int j0 = 0; j0 < 16; j0++) {
        float4 iv = ir4[j0];
        s2 += iv.x*w2q[j0*4] + iv.y*w2q[j0*4+1] + iv.z*w2q[j0*4+2] + iv.w*w2q[j0*4+3];
      }
      s += s2;
    }
    p[t] = s;
  }
  __syncthreads();
  float lm = (t < NPOS) ? p[t] : -1e30f;
  lm = wred_max(lm);
  if (lane == 0) red[wv] = lm;
  __syncthreads();
  float mx = fmaxf(fmaxf(red[0], red[1]), fmaxf(red[2], red[3]));
  float lp = 0.f;
  if (t < NPOS) { lp = __expf(p[t] - mx); p[t] = lp; }
  float ls = wred_sum(lp);
  if (lane == 0) red[8 + wv] = ls;
  __syncthreads();
  float inv = 1.0f / (red[8] + red[9] + red[10] + red[11]);
  float tp = 0.f;
  for (int n = wv; n < NPOS; n += 4) {
    if (smk[n]) tp += p[n] * inner[(size_t)(fb*NPOS + n)*INNER_D + lane];
  }
  pacc[wv][lane] = tp;
  __syncthreads();
  if (t < INNER_D) tj[t] = pacc[0][t] + pacc[1][t] + pacc[2][t] + pacc[3][t];
  __syncthreads();
  float va = 0.f;
  for (int n = wv; n < NPOS; n += 4) {
    float pn = p[n];
    int idx = sidx[n];
    float vvv;
    if (idx >= NC) vvv = (float)v_newc[(size_t)(idx - NC)*DIM + h*HD + lane];
    else           vvv = v_cache[(size_t)idx*DIM + h*HD + lane];
    va += pn * vvv;
  }
  __syncthreads();
  pacc[wv][lane] = va;
  __syncthreads();
  if (t < HD) {
    float o = pacc[0][t] + pacc[1][t] + pacc[2][t] + pacc[3][t];
    const float* wv2 = w2 + 3*DIM + h*HD + t;   // vd columns
    float dd = 0.f;
    for (int j = 0; j < INNER_D; j++) dd += tj[j] * wv2[(size_t)j*FF];
    pre_cls[(size_t)fb*DIM + h*HD + t] = (o + dd) * inv;
  }
}

// ---------------------------------------------------------------------------
// K9: out0 = h_cls + (sum_s partW) + bo;  yln = LN2(out0).  One block per row. (12 slabs)
__launch_bounds__(256)
__global__ void reduce_wo_ln_kernel(const float* __restrict__ partW, const float* __restrict__ bo,
                                    const float* __restrict__ h_cls, const float* __restrict__ g,
                                    const float* __restrict__ b, float* __restrict__ out0,
                                    float* __restrict__ yln)
{
  int row = blockIdx.x, t = threadIdx.x;
  float v[3];
  #pragma unroll
  for (int j = 0; j < 3; j++) {
    int c = t + j*256;
    float s = h_cls[(size_t)row*DIM + c] + bo[c];
    #pragma unroll
    for (int ks = 0; ks < 12; ks++) s += partW[((size_t)ks*FB_N + row)*DIM + c];
    v[j] = s;
    out0[(size_t)row*DIM + c] = s;
  }
  float sm = wred_sum(v[0] + v[1] + v[2]);
  float sq = wred_sum(v[0]*v[0] + v[1]*v[1] + v[2]*v[2]);
  __shared__ float red[8];
  int wv = t >> 6, ln = t & 63;
  if (ln == 0) { red[wv] = sm; red[4 + wv] = sq; }
  __syncthreads();
  float mean = (red[0]+red[1]+red[2]+red[3]) * (1.f/DIM);
  float var  = (red[4]+red[5]+red[6]+red[7]) * (1.f/DIM) - mean*mean;
  float rr = rsqrtf(var + 1e-5f);
  #pragma unroll
  for (int j = 0; j < 3; j++) {
    int c = t + j*256;
    yln[(size_t)row*DIM + c] = (v[j] - mean) * rr * g[c] + b[c];
  }
}

// K10: t1 = quick_gelu(sum_s partF1 + fc1b)    (6 slabs)
__global__ void reduce_gelu_kernel(const float* __restrict__ partF1, const float* __restrict__ b1,
                                   float* __restrict__ t1)
{
  int i = blockIdx.x * 256 + threadIdx.x;   // < 196608
  int c = i % FF;
  float v = b1[c];
  #pragma unroll
  for (int s = 0; s < 6; s++) v += partF1[(size_t)s*FB_N*FF + i];
  t1[i] = v / (1.0f + __expf(-1.702f * v));
}

// K11: d_out = out0 + fc2_b + sum_s partF2     (24 slabs)
__global__ void final_reduce_kernel(const float* __restrict__ out0, const float* __restrict__ b2,
                                    const float* __restrict__ partF2, float* __restrict__ dout)
{
  int i = blockIdx.x * 256 + threadIdx.x;   // < 49152
  int c = i % DIM;
  float v = out0[i] + b2[c];
  #pragma unroll
  for (int s = 0; s < 24; s++) v += partF2[(size_t)s*FB_N*DIM + i];
  dout[i] = v;
}

// ---------------------------------------------------------------------------
extern "C" void kernel_launch(void* const* d_in, const int* in_sizes, int n_in,
                              void* d_out, int out_size, void* d_ws, size_t ws_size,
                              hipStream_t stream)
{
  const float* hs   = (const float*)d_in[0];
  const float* dpp  = (const float*)d_in[1];
  const float* hqkv = (const float*)d_in[2];
  const float* ln1g = (const float*)d_in[3];
  const float* ln1b = (const float*)d_in[4];
  const float* wq   = (const float*)d_in[5];
  const float* bq   = (const float*)d_in[6];
  const float* wk   = (const float*)d_in[7];
  const float* bk   = (const float*)d_in[8];
  const float* wvw  = (const float*)d_in[9];
  const float* bv   = (const float*)d_in[10];
  const float* w1   = (const float*)d_in[11];
  const float* w2   = (const float*)d_in[12];
  const float* wo   = (const float*)d_in[13];
  const float* bo   = (const float*)d_in[14];
  const float* ln2g = (const float*)d_in[15];
  const float* ln2b = (const float*)d_in[16];
  const float* fc1w = (const float*)d_in[17];
  const float* fc1b = (const float*)d_in[18];
  const float* fc2w = (const float*)d_in[19];
  const float* fc2b = (const float*)d_in[20];
  const int*   gidx = (const int*)d_in[21];
  const unsigned char* rmap = (const unsigned char*)d_in[22];
  float* outp = (float*)d_out;

  char* ws = (char*)d_ws;
  size_t off = 0;
  auto alloc = [&](size_t bytes) { void* p = ws + off; off += (bytes + 255) & ~(size_t)255; return p; };
  unsigned char* mask = (unsigned char*)alloc(TT);
  int* flag    = (int*)alloc((size_t)TT * 4);
  int* rowlist = (int*)alloc((size_t)TT * 4);
  int* remap   = (int*)alloc((size_t)TT * 4);
  int* mc      = (int*)alloc(256);
  __bf16* xbf   = (__bf16*)alloc((size_t)TT * DIM * 2);
  __bf16* wcatT = (__bf16*)alloc((size_t)NCOLS * DIM * 2);
  __bf16* k_newc = (__bf16*)alloc((size_t)TT * DIM * 2);
  __bf16* v_newc = (__bf16*)alloc((size_t)TT * DIM * 2);
  float* inner  = (float*)alloc((size_t)TT * INNER_D * 4);
  float* h_cls  = (float*)alloc((size_t)FB_N * DIM * 4);
  float* qbase  = (float*)alloc((size_t)FB_N * DIM * 4);
  float* Xq     = (float*)alloc((size_t)FB_N * DIM * 4);
  float* q0s    = (float*)alloc((size_t)FB_N * DIM * 4);
  float* precls = (float*)alloc((size_t)FB_N * DIM * 4);
  float* out0   = (float*)alloc((size_t)FB_N * DIM * 4);
  float* yln    = (float*)alloc((size_t)FB_N * DIM * 4);
  float* t1     = (float*)alloc((size_t)FB_N * FF * 4);
  float* partQ  = (float*)alloc((size_t)12 * FB_N * DIM * 4);
  float* partW  = (float*)alloc((size_t)12 * FB_N * DIM * 4);
  float* partF1 = (float*)alloc((size_t)6  * FB_N * FF  * 4);
  float* partF2 = (float*)alloc((size_t)24 * FB_N * DIM * 4);
  (void)ws_size; (void)in_sizes; (void)n_in; (void)out_size;

  mask_norm_kernel<<<1, 256, 0, stream>>>(rmap, mask);
  hipMemsetAsync(flag, 0, (size_t)TT * 4, stream);
  flag_kernel<<<(TT + 255) / 256, 256, 0, stream>>>(gidx, flag);
  scan_kernel<<<1, 1024, 0, stream>>>(flag, rowlist, remap, mc);
  ln_kernel<<<TT, 256, 0, stream>>>(hs, ln1g, ln1b, xbf, rowlist, mc);
  transpose_w_kernel<<<dim3(24, 24, 2), dim3(32, 8), 0, stream>>>(wk, wvw, wcatT);
  kv_gemm_kernel<<<1248, 256, 0, stream>>>(xbf, wcatT, bk, bv, k_newc, v_newc, mc);
  inner_kernel<<<TT/64, 256, 0, stream>>>(dpp, w1, inner);
  cls_gather_kernel<<<FB_N, 256, 0, stream>>>(hs, hqkv, xbf, bq, w2, inner, gidx, mask, remap,
                                              h_cls, qbase, Xq);
  // q0s = (qbase + Xq @ wq) * SCALE   (zero Xq rows for cached fb's)
  pgemm_kernel<<<dim3(12, 12), 256, 0, stream>>>(Xq, wq, partQ, DIM, DIM, 64);
  reduce_q_kernel<<<192, 256, 0, stream>>>(qbase, partQ, q0s);
  attn_cls_kernel<<<FB_N * NH, 256, 0, stream>>>(hqkv, k_newc, v_newc, w2, inner, gidx, mask, remap,
                                                 q0s, precls);
  // out0 = h_cls + precls@wo + bo ; yln = LN2(out0)
  pgemm_kernel<<<dim3(12, 12), 256, 0, stream>>>(precls, wo, partW, DIM, DIM, 64);
  reduce_wo_ln_kernel<<<FB_N, 256, 0, stream>>>(partW, bo, h_cls, ln2g, ln2b, out0, yln);
  // t1 = qgelu(yln@fc1w + fc1b)
  pgemm_kernel<<<dim3(48, 6), 256, 0, stream>>>(yln, fc1w, partF1, FF, DIM, 128);
  reduce_gelu_kernel<<<768, 256, 0, stream>>>(partF1, fc1b, t1);
  // d_out = out0 + t1@fc2w + fc2b
  pgemm_kernel<<<dim3(12, 24), 256, 0, stream>>>(t1, fc2w, partF2, DIM, FF, 128);
  final_reduce_kernel<<<192, 256, 0, stream>>>(out0, fc2b, partF2, outp);
}

// Round 6
// 267.069 us; speedup vs baseline: 3.1778x; 1.0294x over previous
//
#include <hip/hip_runtime.h>
#include <hip/hip_bf16.h>

// Problem constants
#define TT 12608          // 4*B*N rows of hs
#define NC 3152           // B*N cache rows (= 16*197)
#define DIM 768
#define NPOS 197
#define NH 12
#define HD 64
#define FB_N 64           // 4*B
#define FF 3072
#define INNER_D 64
#define NCOLS 1536        // K cols + V cols combined

typedef __bf16 bf16x8 __attribute__((ext_vector_type(8)));
typedef float f32x4 __attribute__((ext_vector_type(4)));

__device__ inline float wred_sum(float v){
  #pragma unroll
  for (int o = 32; o > 0; o >>= 1) v += __shfl_down(v, o, 64);
  return v;
}
__device__ inline float wred_max(float v){
  #pragma unroll
  for (int o = 32; o > 0; o >>= 1) v = fmaxf(v, __shfl_down(v, o, 64));
  return v;
}

// async global->LDS, 16B per lane; LDS dest = wave-uniform base + lane*16
__device__ __forceinline__ void gl_lds16(const __bf16* g, __bf16* l) {
  __builtin_amdgcn_global_load_lds(
      (const __attribute__((address_space(1))) void*)g,
      (__attribute__((address_space(3))) void*)l, 16, 0, 0);
}

// ---------------------------------------------------------------------------
// K1: normalize reuse_map to uint8 regardless of harness dtype (int32/int8/f32).
__global__ void mask_norm_kernel(const unsigned char* __restrict__ rm,
                                 unsigned char* __restrict__ mask)
{
  __shared__ int flagA, flagB;
  if (threadIdx.x == 0) { flagA = 0; flagB = 0; }
  __syncthreads();
  int la = 0, lb = 0;
  for (int i = threadIdx.x; i < TT; i += blockDim.x) {
    unsigned char v = rm[i];
    if (v) { if (i & 3) la = 1; else lb = 1; }
  }
  if (la) atomicOr(&flagA, 1);
  if (lb) atomicOr(&flagB, 1);
  __syncthreads();
  int mode = (!flagA) ? 0 : (flagB ? 1 : 2); // 0=int32, 1=byte, 2=f32
  for (int i = threadIdx.x; i < TT; i += blockDim.x) {
    unsigned char m;
    if (mode == 0)      m = ((const int*)rm)[i] != 0;
    else if (mode == 1) m = rm[i] != 0;
    else                m = ((const float*)rm)[i] != 0.0f;
    mask[i] = m;
  }
}

// ---------------------------------------------------------------------------
// K1b: flag referenced fresh rows.
__global__ void flag_kernel(const int* __restrict__ gidx, int* __restrict__ flag)
{
  int g = blockIdx.x * 256 + threadIdx.x;
  if (g < TT) { int idx = gidx[g]; if (idx >= NC) flag[idx - NC] = 1; }
}

// K1c: single-block dual exclusive scan:
//   A: fresh-row compaction (flag)  -> rowlist / remap / mc[0]
//   B: masked-row compaction (mask) -> mrowlist / mremap / mc[1]
__launch_bounds__(1024)
__global__ void scan_kernel(const int* __restrict__ flag, const unsigned char* __restrict__ mask,
                            int* __restrict__ rowlist, int* __restrict__ remap,
                            int* __restrict__ mrowlist, int* __restrict__ mremap,
                            int* __restrict__ mc)
{
  __shared__ int wsumA[16], wsumB[16];
  __shared__ int baseA, baseB;
  int t = threadIdx.x, lane = t & 63, wv = t >> 6;
  if (t == 0) { baseA = 0; baseB = 0; }
  __syncthreads();
  for (int start = 0; start < TT; start += 1024) {
    int i = start + t;
    int fA = (i < TT) ? flag[i] : 0;
    int fB = (i < TT) ? (int)mask[i] : 0;
    unsigned long long mbA = __ballot(fA != 0);
    unsigned long long mbB = __ballot(fB != 0);
    int rankA = __popcll(mbA & ((1ULL << lane) - 1ULL));
    int rankB = __popcll(mbB & ((1ULL << lane) - 1ULL));
    if (lane == 0) { wsumA[wv] = __popcll(mbA); wsumB[wv] = __popcll(mbB); }
    __syncthreads();
    int woffA = 0, woffB = 0;
    for (int w2 = 0; w2 < wv; w2++) { woffA += wsumA[w2]; woffB += wsumB[w2]; }
    if (fA) { int pos = baseA + woffA + rankA; rowlist[pos] = i; remap[i] = pos; }
    if (fB) { int pos = baseB + woffB + rankB; mrowlist[pos] = i; mremap[i] = pos; }
    __syncthreads();
    if (t == 0) {
      int ta = 0, tb = 0;
      for (int w2 = 0; w2 < 16; w2++) { ta += wsumA[w2]; tb += wsumB[w2]; }
      baseA += ta; baseB += tb;
    }
    __syncthreads();
  }
  if (t == 0) { mc[0] = baseA; mc[1] = baseB; }
}

// ---------------------------------------------------------------------------
// K2: row LayerNorm over 768 cols -> bf16, COMPACT rows only (xbf[c] = LN(hs[rowlist[c]])).
__launch_bounds__(256)
__global__ void ln_kernel(const float* __restrict__ in, const float* __restrict__ g,
                          const float* __restrict__ b, __bf16* __restrict__ outp,
                          const int* __restrict__ rowlist, const int* __restrict__ mc)
{
  if ((int)blockIdx.x >= mc[0]) return;
  int row = rowlist[blockIdx.x];
  int t = threadIdx.x;
  const float* x = in + (size_t)row * DIM;
  float v0 = x[t], v1 = x[t + 256], v2 = x[t + 512];
  float s = wred_sum(v0 + v1 + v2);
  float q = wred_sum(v0*v0 + v1*v1 + v2*v2);
  __shared__ float red[8];
  int wv = t >> 6, ln = t & 63;
  if (ln == 0) { red[wv] = s; red[4 + wv] = q; }
  __syncthreads();
  float mean = (red[0]+red[1]+red[2]+red[3]) * (1.f/DIM);
  float var  = (red[4]+red[5]+red[6]+red[7]) * (1.f/DIM) - mean*mean;
  float rr = rsqrtf(var + 1e-5f);
  #pragma unroll
  for (int j = 0; j < 3; j++) {
    int c = t + j*256;
    float v = (j==0) ? v0 : (j==1) ? v1 : v2;
    outp[(size_t)blockIdx.x*DIM + c] = (__bf16)((v - mean) * rr * g[c] + b[c]);
  }
}

// ---------------------------------------------------------------------------
// K3: transpose wk/wv (768x768 f32) -> combined bf16 B^T buffer wcatT[1536][768].
__global__ void transpose_w_kernel(const float* __restrict__ wk, const float* __restrict__ wv,
                                   __bf16* __restrict__ wcatT)
{
  const float* src = blockIdx.z ? wv : wk;
  __bf16* dst = wcatT + (blockIdx.z ? (size_t)768 * DIM : 0);
  __shared__ float tile[32][33];
  int bx = blockIdx.x, by = blockIdx.y;
  int tx = threadIdx.x, ty = threadIdx.y;
  #pragma unroll
  for (int i = 0; i < 32; i += 8)
    tile[ty + i][tx] = src[(size_t)(by*32 + ty + i) * DIM + bx*32 + tx];
  __syncthreads();
  #pragma unroll
  for (int i = 0; i < 32; i += 8)
    dst[(size_t)(bx*32 + ty + i) * DIM + by*32 + tx] = (__bf16)tile[tx][ty + i];
}

// ---------------------------------------------------------------------------
// K4: [k_newc | v_newc] = xbf(compact) @ wcatT^T (+bias), m97 structure.
__launch_bounds__(256)
__global__ void kv_gemm_kernel(const __bf16* __restrict__ xbf, const __bf16* __restrict__ wcatT,
                               const float* __restrict__ bk, const float* __restrict__ bv,
                               __bf16* __restrict__ k_newc, __bf16* __restrict__ v_newc,
                               const int* __restrict__ mc)
{
  int Mc = mc[0];
  int npanels = (Mc + 127) >> 7;
  int bid = blockIdx.x;                 // 8 * 13 * 12 = 1248
  int xcd = bid & 7, s = bid >> 3;
  int panel = (s / 12) * 8 + xcd;
  if (panel >= npanels) return;
  int col0 = (s % 12) * 128;
  int row0 = panel * 128;

  __shared__ __align__(16) __bf16 As[128][32];
  __shared__ __align__(16) __bf16 Bs[128][32];
  int t = threadIdx.x;
  int lane = t & 63, wid = t >> 6;
  int wr = wid >> 1, wc = wid & 1;
  int fr = lane & 15, fg = lane >> 4;

  int lr = t >> 2, lc = (t & 3) << 3;
  int ar0 = min(row0 + lr, Mc - 1);
  int ar1 = min(row0 + 64 + lr, Mc - 1);
  const __bf16* aG0 = xbf + (size_t)ar0 * DIM + lc;
  const __bf16* aG1 = xbf + (size_t)ar1 * DIM + lc;
  const __bf16* bG0 = wcatT + (size_t)(col0 + lr) * DIM + lc;
  const __bf16* bG1 = wcatT + (size_t)(col0 + 64 + lr) * DIM + lc;
  __bf16* lA0 = &As[lr][lc];
  __bf16* lA1 = &As[64 + lr][lc];
  __bf16* lB0 = &Bs[lr][lc];
  __bf16* lB1 = &Bs[64 + lr][lc];

  f32x4 acc[4][4];
  #pragma unroll
  for (int m = 0; m < 4; m++)
    #pragma unroll
    for (int n = 0; n < 4; n++) acc[m][n] = (f32x4){0.f, 0.f, 0.f, 0.f};

  for (int k0 = 0; k0 < DIM; k0 += 32) {
    gl_lds16(aG0 + k0, lA0);
    gl_lds16(aG1 + k0, lA1);
    gl_lds16(bG0 + k0, lB0);
    gl_lds16(bG1 + k0, lB1);
    __syncthreads();
    bf16x8 af[4], bb[4];
    #pragma unroll
    for (int m = 0; m < 4; m++) af[m] = *(const bf16x8*)&As[wr*64 + m*16 + fr][fg << 3];
    #pragma unroll
    for (int n = 0; n < 4; n++) bb[n] = *(const bf16x8*)&Bs[wc*64 + n*16 + fr][fg << 3];
    #pragma unroll
    for (int m = 0; m < 4; m++)
      #pragma unroll
      for (int n = 0; n < 4; n++)
        acc[m][n] = __builtin_amdgcn_mfma_f32_16x16x32_bf16(af[m], bb[n], acc[m][n], 0, 0, 0);
    __syncthreads();
  }

  bool isK = (col0 < 768);
  const float* bias = isK ? bk : bv;
  __bf16* dst = isK ? k_newc : v_newc;
  int cbase = isK ? col0 : col0 - 768;
  #pragma unroll
  for (int n = 0; n < 4; n++) {
    int dcol = cbase + wc*64 + n*16 + fr;
    float bc = bias[dcol];
    #pragma unroll
    for (int m = 0; m < 4; m++) {
      int orow = row0 + wr*64 + m*16 + fg*4;
      #pragma unroll
      for (int r = 0; r < 4; r++) {
        int rr = orow + r;
        if (rr < Mc) dst[(size_t)rr * DIM + dcol] = (__bf16)(acc[m][n][r] + bc);
      }
    }
  }
}

// ---------------------------------------------------------------------------
// K5: partial inner GEMM over MASKED rows only:
// partI[ks][crow][64] = dpp[mrowlist[crow]] (K-chunk ks) @ w1.
// grid (ceil(TT/32), 4), 256 thr; early-exit on mc[1].
__launch_bounds__(256)
__global__ void inner_gemm_kernel(const float* __restrict__ dpp, const float* __restrict__ w1,
                                  const int* __restrict__ mrowlist, const int* __restrict__ mc,
                                  float* __restrict__ partI)
{
  int mcnt = mc[1];
  int row0 = blockIdx.x * 32;
  if (row0 >= mcnt) return;
  int t = threadIdx.x;
  int c = t & 63;
  int rq = t >> 6;                    // 4 waves, each 8 rows
  int k0base = blockIdx.y * 192;
  __shared__ __align__(16) float Xs[32][68];
  __shared__ int rlist[32];
  if (t < 32) rlist[t] = mrowlist[min(row0 + t, mcnt - 1)];
  __syncthreads();
  float acc[8];
  #pragma unroll
  for (int i = 0; i < 8; i++) acc[i] = 0.f;
  for (int k0 = k0base; k0 < k0base + 192; k0 += 64) {
    {
      int rr = t >> 3, c8 = (t & 7) << 3;
      const float* src = &dpp[(size_t)rlist[rr]*DIM + k0 + c8];
      *(float4*)&Xs[rr][c8]     = *(const float4*)(src);
      *(float4*)&Xs[rr][c8 + 4] = *(const float4*)(src + 4);
    }
    __syncthreads();
    const float* Wp = w1 + (size_t)k0*INNER_D + c;
    #pragma unroll 4
    for (int kk = 0; kk < 64; kk += 4) {
      float w0 = Wp[(size_t)(kk+0)*INNER_D];
      float w1v = Wp[(size_t)(kk+1)*INNER_D];
      float w2v = Wp[(size_t)(kk+2)*INNER_D];
      float w3v = Wp[(size_t)(kk+3)*INNER_D];
      #pragma unroll
      for (int r = 0; r < 8; r++) {
        float4 xv = *(const float4*)&Xs[rq*8 + r][kk];
        acc[r] += xv.x*w0 + xv.y*w1v + xv.z*w2v + xv.w*w3v;
      }
    }
    __syncthreads();
  }
  #pragma unroll
  for (int r = 0; r < 8; r++) {
    int crow = row0 + rq*8 + r;
    if (crow < mcnt) partI[((size_t)blockIdx.y*TT + crow)*INNER_D + c] = acc[r];
  }
}

// K5b: inner_c = gelu_tanh(sum_ks partI)
__global__ void reduce_inner_kernel(const float* __restrict__ partI, const int* __restrict__ mc,
                                    float* __restrict__ inner_c)
{
  int i = blockIdx.x * 256 + threadIdx.x;
  if (i >= mc[1] * INNER_D) return;
  float x = partI[i] + partI[(size_t)TT*INNER_D + i] + partI[(size_t)2*TT*INNER_D + i]
          + partI[(size_t)3*TT*INNER_D + i];
  float u = 0.7978845608028654f * (x + 0.044715f * x * x * x);
  inner_c[i] = 0.5f * x * (1.0f + tanhf(u));
}

// ---------------------------------------------------------------------------
// K6: per (f,b): h_cls row, qbase row, compact Xq row.
__launch_bounds__(256)
__global__ void cls_gather_kernel(const float* __restrict__ hs, const float* __restrict__ hqkv,
                                  const __bf16* __restrict__ xbf, const float* __restrict__ bq,
                                  const float* __restrict__ w2, const float* __restrict__ inner_c,
                                  const int* __restrict__ gidx, const unsigned char* __restrict__ mask,
                                  const int* __restrict__ remap, const int* __restrict__ mremap,
                                  float* __restrict__ h_cls, float* __restrict__ qbase,
                                  float* __restrict__ Xq)
{
  int fb = blockIdx.x, t = threadIdx.x;
  int g0 = fb * NPOS;
  int idx = gidx[g0];
  int m = mask[g0];
  const float* q_cache = hqkv + (size_t)NC * DIM;
  __shared__ float inn[INNER_D];
  if (t < INNER_D) inn[t] = m ? inner_c[(size_t)mremap[g0]*INNER_D + t] : 0.f;
  __syncthreads();
  bool fresh = idx >= NC;
  int crow = fresh ? remap[idx - NC] : 0;
  for (int c = t; c < DIM; c += 256) {
    float xv = fresh ? (float)xbf[(size_t)crow*DIM + c] : 0.f;
    Xq[(size_t)fb*DIM + c] = xv;
    float hv = fresh ? hs[(size_t)(idx - NC)*DIM + c] : hqkv[(size_t)idx*DIM + c];
    float qb = fresh ? bq[c] : q_cache[(size_t)idx*DIM + c];
    if (m) {
      float hd = 0.f, qd = 0.f;
      #pragma unroll 8
      for (int j = 0; j < INNER_D; j++) {
        float iv = inn[j];
        hd += iv * w2[(size_t)j*FF + c];
        qd += iv * w2[(size_t)j*FF + DIM + c];
      }
      hv += hd; qb += qd;
    }
    h_cls[(size_t)fb*DIM + c] = hv;
    qbase[(size_t)fb*DIM + c] = qb;
  }
}

// ---------------------------------------------------------------------------
// K7: partial GEMM, M=64 fixed. grid (N/64, K/kChunk), 256 thr.
__launch_bounds__(256)
__global__ void pgemm_kernel(const float* __restrict__ X, const float* __restrict__ W,
                             float* __restrict__ part, int N, int K, int kChunk)
{
  int t = threadIdx.x;
  int c = t & 63;
  int rq = t >> 6;
  int col0 = blockIdx.x * 64;
  int k0base = blockIdx.y * kChunk;
  __shared__ __align__(16) float Xs[64][68];
  float acc[16];
  #pragma unroll
  for (int i = 0; i < 16; i++) acc[i] = 0.f;
  for (int k0 = k0base; k0 < k0base + kChunk; k0 += 64) {
    #pragma unroll
    for (int j = 0; j < 4; j++) {
      int v = t + 256*j;
      int rr = v >> 4, cc = (v & 15) << 2;
      *(float4*)&Xs[rr][cc] = *(const float4*)&X[(size_t)rr*K + k0 + cc];
    }
    __syncthreads();
    const float* Wp = W + (size_t)k0*N + col0 + c;
    #pragma unroll 4
    for (int kk = 0; kk < 64; kk += 4) {
      float w0 = Wp[(size_t)(kk+0)*N];
      float w1 = Wp[(size_t)(kk+1)*N];
      float w2 = Wp[(size_t)(kk+2)*N];
      float w3 = Wp[(size_t)(kk+3)*N];
      #pragma unroll
      for (int r = 0; r < 16; r++) {
        float4 xv = *(const float4*)&Xs[rq*16 + r][kk];
        acc[r] += xv.x*w0 + xv.y*w1 + xv.z*w2 + xv.w*w3;
      }
    }
    __syncthreads();
  }
  #pragma unroll
  for (int r = 0; r < 16; r++)
    part[((size_t)blockIdx.y*64 + rq*16 + r)*N + col0 + c] = acc[r];
}

// K7b: q0s = (qbase + sum_s partQ) * SCALE     (12 slabs)
__global__ void reduce_q_kernel(const float* __restrict__ qbase, const float* __restrict__ partQ,
                                float* __restrict__ q0s)
{
  int i = blockIdx.x * 256 + threadIdx.x;   // < 49152
  float v = qbase[i];
  #pragma unroll
  for (int s = 0; s < 12; s++) v += partQ[(size_t)s*FB_N*DIM + i];
  q0s[i] = v * 0.125f;
}

// ---------------------------------------------------------------------------
// K8: CLS-row attention with low-rank diff folded in algebraically.
__launch_bounds__(256)
__global__ void attn_cls_kernel(const float* __restrict__ hqkv, const __bf16* __restrict__ k_newc,
                                const __bf16* __restrict__ v_newc, const float* __restrict__ w2,
                                const float* __restrict__ inner_c, const int* __restrict__ gidx,
                                const unsigned char* __restrict__ mask, const int* __restrict__ remap,
                                const int* __restrict__ mremap,
                                const float* __restrict__ q0s, float* __restrict__ pre_cls)
{
  int bid = blockIdx.x;
  int fb = bid / NH, h = bid % NH;
  int t = threadIdx.x;
  int lane = t & 63, wv = t >> 6;
  const float* k_cache = hqkv + (size_t)2 * NC * DIM;
  const float* v_cache = hqkv + (size_t)3 * NC * DIM;
  __shared__ float q0[HD], w2q[INNER_D], tj[INNER_D];
  __shared__ float p[200];
  __shared__ int sidx[200];
  __shared__ int smg[200];        // compact inner row (-1 if unmasked)
  __shared__ float red[16];
  __shared__ float pacc[4][64];
  if (t < HD) q0[t] = q0s[(size_t)fb*DIM + h*HD + t];
  __syncthreads();
  if (t < INNER_D) {
    const float* wr = w2 + (size_t)t*FF + 2*DIM + h*HD;  // kd columns
    float s = 0.f;
    for (int d = 0; d < HD; d++) s += q0[d] * wr[d];
    w2q[t] = s;
  }
  __syncthreads();
  if (t < NPOS) {
    int g = fb * NPOS + t;
    int idx = gidx[g];
    if (idx >= NC) idx = NC + remap[idx - NC];   // translate to compact index
    int m = mask[g];
    int mg = m ? mremap[g] : -1;
    sidx[t] = idx; smg[t] = mg;
    float s = 0.f;
    if (idx >= NC) {
      const __bf16* kr = k_newc + (size_t)(idx - NC)*DIM + h*HD;
      #pragma unroll
      for (int d0 = 0; d0 < HD; d0 += 8) {
        bf16x8 kv = *(const bf16x8*)(kr + d0);
        #pragma unroll
        for (int j = 0; j < 8; j++) s += q0[d0 + j] * (float)kv[j];
      }
    } else {
      const float* kr = k_cache + (size_t)idx*DIM + h*HD;
      #pragma unroll
      for (int d0 = 0; d0 < HD; d0 += 4) {
        float4 kv = *(const float4*)(kr + d0);
        s += q0[d0]*kv.x + q0[d0+1]*kv.y + q0[d0+2]*kv.z + q0[d0+3]*kv.w;
      }
    }
    if (mg >= 0) {
      const float4* ir4 = (const float4*)(inner_c + (size_t)mg * INNER_D);
      float s2 = 0.f;
      #pragma unroll
      for (int j0 = 0; j0 < 16; j0++) {
        float4 iv = ir4[j0];
        s2 += iv.x*w2q[j0*4] + iv.y*w2q[j0*4+1] + iv.z*w2q[j0*4+2] + iv.w*w2q[j0*4+3];
      }
      s += s2;
    }
    p[t] = s;
  }
  __syncthreads();
  float lm = (t < NPOS) ? p[t] : -1e30f;
  lm = wred_max(lm);
  if (lane == 0) red[wv] = lm;
  __syncthreads();
  float mx = fmaxf(fmaxf(red[0], red[1]), fmaxf(red[2], red[3]));
  float lp = 0.f;
  if (t < NPOS) { lp = __expf(p[t] - mx); p[t] = lp; }
  float ls = wred_sum(lp);
  if (lane == 0) red[8 + wv] = ls;
  __syncthreads();
  float inv = 1.0f / (red[8] + red[9] + red[10] + red[11]);
  float tp = 0.f;
  for (int n = wv; n < NPOS; n += 4) {
    int mg = smg[n];
    if (mg >= 0) tp += p[n] * inner_c[(size_t)mg*INNER_D + lane];
  }
  pacc[wv][lane] = tp;
  __syncthreads();
  if (t < INNER_D) tj[t] = pacc[0][t] + pacc[1][t] + pacc[2][t] + pacc[3][t];
  __syncthreads();
  float va = 0.f;
  for (int n = wv; n < NPOS; n += 4) {
    float pn = p[n];
    int idx = sidx[n];
    float vvv;
    if (idx >= NC) vvv = (float)v_newc[(size_t)(idx - NC)*DIM + h*HD + lane];
    else           vvv = v_cache[(size_t)idx*DIM + h*HD + lane];
    va += pn * vvv;
  }
  __syncthreads();
  pacc[wv][lane] = va;
  __syncthreads();
  if (t < HD) {
    float o = pacc[0][t] + pacc[1][t] + pacc[2][t] + pacc[3][t];
    const float* wv2 = w2 + 3*DIM + h*HD + t;   // vd columns
    float dd = 0.f;
    for (int j = 0; j < INNER_D; j++) dd += tj[j] * wv2[(size_t)j*FF];
    pre_cls[(size_t)fb*DIM + h*HD + t] = (o + dd) * inv;
  }
}

// ---------------------------------------------------------------------------
// K9: out0 = h_cls + (sum_s partW) + bo;  yln = LN2(out0).  One block per row. (12 slabs)
__launch_bounds__(256)
__global__ void reduce_wo_ln_kernel(const float* __restrict__ partW, const float* __restrict__ bo,
                                    const float* __restrict__ h_cls, const float* __restrict__ g,
                                    const float* __restrict__ b, float* __restrict__ out0,
                                    float* __restrict__ yln)
{
  int row = blockIdx.x, t = threadIdx.x;
  float v[3];
  #pragma unroll
  for (int j = 0; j < 3; j++) {
    int c = t + j*256;
    float s = h_cls[(size_t)row*DIM + c] + bo[c];
    #pragma unroll
    for (int ks = 0; ks < 12; ks++) s += partW[((size_t)ks*FB_N + row)*DIM + c];
    v[j] = s;
    out0[(size_t)row*DIM + c] = s;
  }
  float sm = wred_sum(v[0] + v[1] + v[2]);
  float sq = wred_sum(v[0]*v[0] + v[1]*v[1] + v[2]*v[2]);
  __shared__ float red[8];
  int wv = t >> 6, ln = t & 63;
  if (ln == 0) { red[wv] = sm; red[4 + wv] = sq; }
  __syncthreads();
  float mean = (red[0]+red[1]+red[2]+red[3]) * (1.f/DIM);
  float var  = (red[4]+red[5]+red[6]+red[7]) * (1.f/DIM) - mean*mean;
  float rr = rsqrtf(var + 1e-5f);
  #pragma unroll
  for (int j = 0; j < 3; j++) {
    int c = t + j*256;
    yln[(size_t)row*DIM + c] = (v[j] - mean) * rr * g[c] + b[c];
  }
}

// K10: t1 = quick_gelu(sum_s partF1 + fc1b)    (6 slabs)
__global__ void reduce_gelu_kernel(const float* __restrict__ partF1, const float* __restrict__ b1,
                                   float* __restrict__ t1)
{
  int i = blockIdx.x * 256 + threadIdx.x;   // < 196608
  int c = i % FF;
  float v = b1[c];
  #pragma unroll
  for (int s = 0; s < 6; s++) v += partF1[(size_t)s*FB_N*FF + i];
  t1[i] = v / (1.0f + __expf(-1.702f * v));
}

// K11: d_out = out0 + fc2_b + sum_s partF2     (24 slabs)
__global__ void final_reduce_kernel(const float* __restrict__ out0, const float* __restrict__ b2,
                                    const float* __restrict__ partF2, float* __restrict__ dout)
{
  int i = blockIdx.x * 256 + threadIdx.x;   // < 49152
  int c = i % DIM;
  float v = out0[i] + b2[c];
  #pragma unroll
  for (int s = 0; s < 24; s++) v += partF2[(size_t)s*FB_N*DIM + i];
  dout[i] = v;
}

// ---------------------------------------------------------------------------
extern "C" void kernel_launch(void* const* d_in, const int* in_sizes, int n_in,
                              void* d_out, int out_size, void* d_ws, size_t ws_size,
                              hipStream_t stream)
{
  const float* hs   = (const float*)d_in[0];
  const float* dpp  = (const float*)d_in[1];
  const float* hqkv = (const float*)d_in[2];
  const float* ln1g = (const float*)d_in[3];
  const float* ln1b = (const float*)d_in[4];
  const float* wq   = (const float*)d_in[5];
  const float* bq   = (const float*)d_in[6];
  const float* wk   = (const float*)d_in[7];
  const float* bk   = (const float*)d_in[8];
  const float* wvw  = (const float*)d_in[9];
  const float* bv   = (const float*)d_in[10];
  const float* w1   = (const float*)d_in[11];
  const float* w2   = (const float*)d_in[12];
  const float* wo   = (const float*)d_in[13];
  const float* bo   = (const float*)d_in[14];
  const float* ln2g = (const float*)d_in[15];
  const float* ln2b = (const float*)d_in[16];
  const float* fc1w = (const float*)d_in[17];
  const float* fc1b = (const float*)d_in[18];
  const float* fc2w = (const float*)d_in[19];
  const float* fc2b = (const float*)d_in[20];
  const int*   gidx = (const int*)d_in[21];
  const unsigned char* rmap = (const unsigned char*)d_in[22];
  float* outp = (float*)d_out;

  char* ws = (char*)d_ws;
  size_t off = 0;
  auto alloc = [&](size_t bytes) { void* p = ws + off; off += (bytes + 255) & ~(size_t)255; return p; };
  unsigned char* mask = (unsigned char*)alloc(TT);
  int* flag     = (int*)alloc((size_t)TT * 4);
  int* rowlist  = (int*)alloc((size_t)TT * 4);
  int* remap    = (int*)alloc((size_t)TT * 4);
  int* mrowlist = (int*)alloc((size_t)TT * 4);
  int* mremap   = (int*)alloc((size_t)TT * 4);
  int* mc       = (int*)alloc(256);
  __bf16* xbf    = (__bf16*)alloc((size_t)TT * DIM * 2);
  __bf16* wcatT  = (__bf16*)alloc((size_t)NCOLS * DIM * 2);
  __bf16* k_newc = (__bf16*)alloc((size_t)TT * DIM * 2);
  __bf16* v_newc = (__bf16*)alloc((size_t)TT * DIM * 2);
  float* partI   = (float*)alloc((size_t)4 * TT * INNER_D * 4);
  float* inner_c = (float*)alloc((size_t)TT * INNER_D * 4);
  float* h_cls  = (float*)alloc((size_t)FB_N * DIM * 4);
  float* qbase  = (float*)alloc((size_t)FB_N * DIM * 4);
  float* Xq     = (float*)alloc((size_t)FB_N * DIM * 4);
  float* q0s    = (float*)alloc((size_t)FB_N * DIM * 4);
  float* precls = (float*)alloc((size_t)FB_N * DIM * 4);
  float* out0   = (float*)alloc((size_t)FB_N * DIM * 4);
  float* yln    = (float*)alloc((size_t)FB_N * DIM * 4);
  float* t1     = (float*)alloc((size_t)FB_N * FF * 4);
  float* partQ  = (float*)alloc((size_t)12 * FB_N * DIM * 4);
  float* partW  = (float*)alloc((size_t)12 * FB_N * DIM * 4);
  float* partF1 = (float*)alloc((size_t)6  * FB_N * FF  * 4);
  float* partF2 = (float*)alloc((size_t)24 * FB_N * DIM * 4);
  (void)ws_size; (void)in_sizes; (void)n_in; (void)out_size;

  mask_norm_kernel<<<1, 256, 0, stream>>>(rmap, mask);
  hipMemsetAsync(flag, 0, (size_t)TT * 4, stream);
  flag_kernel<<<(TT + 255) / 256, 256, 0, stream>>>(gidx, flag);
  scan_kernel<<<1, 1024, 0, stream>>>(flag, mask, rowlist, remap, mrowlist, mremap, mc);
  ln_kernel<<<TT, 256, 0, stream>>>(hs, ln1g, ln1b, xbf, rowlist, mc);
  transpose_w_kernel<<<dim3(24, 24, 2), dim3(32, 8), 0, stream>>>(wk, wvw, wcatT);
  kv_gemm_kernel<<<1248, 256, 0, stream>>>(xbf, wcatT, bk, bv, k_newc, v_newc, mc);
  inner_gemm_kernel<<<dim3((TT + 31) / 32, 4), 256, 0, stream>>>(dpp, w1, mrowlist, mc, partI);
  reduce_inner_kernel<<<(TT * INNER_D + 255) / 256, 256, 0, stream>>>(partI, mc, inner_c);
  cls_gather_kernel<<<FB_N, 256, 0, stream>>>(hs, hqkv, xbf, bq, w2, inner_c, gidx, mask,
                                              remap, mremap, h_cls, qbase, Xq);
  // q0s = (qbase + Xq @ wq) * SCALE   (zero Xq rows for cached fb's)
  pgemm_kernel<<<dim3(12, 12), 256, 0, stream>>>(Xq, wq, partQ, DIM, DIM, 64);
  reduce_q_kernel<<<192, 256, 0, stream>>>(qbase, partQ, q0s);
  attn_cls_kernel<<<FB_N * NH, 256, 0, stream>>>(hqkv, k_newc, v_newc, w2, inner_c, gidx, mask,
                                                 remap, mremap, q0s, precls);
  // out0 = h_cls + precls@wo + bo ; yln = LN2(out0)
  pgemm_kernel<<<dim3(12, 12), 256, 0, stream>>>(precls, wo, partW, DIM, DIM, 64);
  reduce_wo_ln_kernel<<<FB_N, 256, 0, stream>>>(partW, bo, h_cls, ln2g, ln2b, out0, yln);
  // t1 = qgelu(yln@fc1w + fc1b)
  pgemm_kernel<<<dim3(48, 6), 256, 0, stream>>>(yln, fc1w, partF1, FF, DIM, 128);
  reduce_gelu_kernel<<<768, 256, 0, stream>>>(partF1, fc1b, t1);
  // d_out = out0 + t1@fc2w + fc2b
  pgemm_kernel<<<dim3(12, 24), 256, 0, stream>>>(t1, fc2w, partF2, DIM, FF, 128);
  final_reduce_kernel<<<192, 256, 0, stream>>>(out0, fc2b, partF2, outp);
}

// Round 7
// 254.546 us; speedup vs baseline: 3.3342x; 1.0492x over previous
//
#include <hip/hip_runtime.h>
#include <hip/hip_bf16.h>

// Problem constants
#define TT 12608          // 4*B*N rows of hs
#define NC 3152           // B*N cache rows (= 16*197)
#define DIM 768
#define NPOS 197
#define NH 12
#define HD 64
#define FB_N 64           // 4*B
#define FF 3072
#define INNER_D 64
#define NCOLS 1536        // K cols + V cols combined

typedef __bf16 bf16x8 __attribute__((ext_vector_type(8)));
typedef float f32x4 __attribute__((ext_vector_type(4)));

__device__ inline float wred_sum(float v){
  #pragma unroll
  for (int o = 32; o > 0; o >>= 1) v += __shfl_down(v, o, 64);
  return v;
}
__device__ inline float wred_max(float v){
  #pragma unroll
  for (int o = 32; o > 0; o >>= 1) v = fmaxf(v, __shfl_down(v, o, 64));
  return v;
}

// async global->LDS, 16B per lane; LDS dest = wave-uniform base + lane*16
__device__ __forceinline__ void gl_lds16(const __bf16* g, __bf16* l) {
  __builtin_amdgcn_global_load_lds(
      (const __attribute__((address_space(1))) void*)g,
      (__attribute__((address_space(3))) void*)l, 16, 0, 0);
}

// ---------------------------------------------------------------------------
// K1: normalize reuse_map to uint8 regardless of harness dtype (int32/int8/f32).
__global__ void mask_norm_kernel(const unsigned char* __restrict__ rm,
                                 unsigned char* __restrict__ mask)
{
  __shared__ int flagA, flagB;
  if (threadIdx.x == 0) { flagA = 0; flagB = 0; }
  __syncthreads();
  int la = 0, lb = 0;
  for (int i = threadIdx.x; i < TT; i += blockDim.x) {
    unsigned char v = rm[i];
    if (v) { if (i & 3) la = 1; else lb = 1; }
  }
  if (la) atomicOr(&flagA, 1);
  if (lb) atomicOr(&flagB, 1);
  __syncthreads();
  int mode = (!flagA) ? 0 : (flagB ? 1 : 2); // 0=int32, 1=byte, 2=f32
  for (int i = threadIdx.x; i < TT; i += blockDim.x) {
    unsigned char m;
    if (mode == 0)      m = ((const int*)rm)[i] != 0;
    else if (mode == 1) m = rm[i] != 0;
    else                m = ((const float*)rm)[i] != 0.0f;
    mask[i] = m;
  }
}

// ---------------------------------------------------------------------------
// K1b: flag referenced fresh rows.
__global__ void flag_kernel(const int* __restrict__ gidx, int* __restrict__ flag)
{
  int g = blockIdx.x * 256 + threadIdx.x;
  if (g < TT) { int idx = gidx[g]; if (idx >= NC) flag[idx - NC] = 1; }
}

// K1c: single-block dual exclusive scan:
//   A: fresh-row compaction (flag)  -> rowlist / remap / mc[0]
//   B: masked-row compaction (mask) -> mrowlist / mremap / mc[1]
__launch_bounds__(1024)
__global__ void scan_kernel(const int* __restrict__ flag, const unsigned char* __restrict__ mask,
                            int* __restrict__ rowlist, int* __restrict__ remap,
                            int* __restrict__ mrowlist, int* __restrict__ mremap,
                            int* __restrict__ mc)
{
  __shared__ int wsumA[16], wsumB[16];
  __shared__ int baseA, baseB;
  int t = threadIdx.x, lane = t & 63, wv = t >> 6;
  if (t == 0) { baseA = 0; baseB = 0; }
  __syncthreads();
  for (int start = 0; start < TT; start += 1024) {
    int i = start + t;
    int fA = (i < TT) ? flag[i] : 0;
    int fB = (i < TT) ? (int)mask[i] : 0;
    unsigned long long mbA = __ballot(fA != 0);
    unsigned long long mbB = __ballot(fB != 0);
    int rankA = __popcll(mbA & ((1ULL << lane) - 1ULL));
    int rankB = __popcll(mbB & ((1ULL << lane) - 1ULL));
    if (lane == 0) { wsumA[wv] = __popcll(mbA); wsumB[wv] = __popcll(mbB); }
    __syncthreads();
    int woffA = 0, woffB = 0;
    for (int w2 = 0; w2 < wv; w2++) { woffA += wsumA[w2]; woffB += wsumB[w2]; }
    if (fA) { int pos = baseA + woffA + rankA; rowlist[pos] = i; remap[i] = pos; }
    if (fB) { int pos = baseB + woffB + rankB; mrowlist[pos] = i; mremap[i] = pos; }
    __syncthreads();
    if (t == 0) {
      int ta = 0, tb = 0;
      for (int w2 = 0; w2 < 16; w2++) { ta += wsumA[w2]; tb += wsumB[w2]; }
      baseA += ta; baseB += tb;
    }
    __syncthreads();
  }
  if (t == 0) { mc[0] = baseA; mc[1] = baseB; }
}

// ---------------------------------------------------------------------------
// K2: row LayerNorm over 768 cols -> bf16, COMPACT rows only (xbf[c] = LN(hs[rowlist[c]])).
__launch_bounds__(256)
__global__ void ln_kernel(const float* __restrict__ in, const float* __restrict__ g,
                          const float* __restrict__ b, __bf16* __restrict__ outp,
                          const int* __restrict__ rowlist, const int* __restrict__ mc)
{
  if ((int)blockIdx.x >= mc[0]) return;
  int row = rowlist[blockIdx.x];
  int t = threadIdx.x;
  const float* x = in + (size_t)row * DIM;
  float v0 = x[t], v1 = x[t + 256], v2 = x[t + 512];
  float s = wred_sum(v0 + v1 + v2);
  float q = wred_sum(v0*v0 + v1*v1 + v2*v2);
  __shared__ float red[8];
  int wv = t >> 6, ln = t & 63;
  if (ln == 0) { red[wv] = s; red[4 + wv] = q; }
  __syncthreads();
  float mean = (red[0]+red[1]+red[2]+red[3]) * (1.f/DIM);
  float var  = (red[4]+red[5]+red[6]+red[7]) * (1.f/DIM) - mean*mean;
  float rr = rsqrtf(var + 1e-5f);
  #pragma unroll
  for (int j = 0; j < 3; j++) {
    int c = t + j*256;
    float v = (j==0) ? v0 : (j==1) ? v1 : v2;
    outp[(size_t)blockIdx.x*DIM + c] = (__bf16)((v - mean) * rr * g[c] + b[c]);
  }
}

// ---------------------------------------------------------------------------
// K3: transpose wk/wv (768x768 f32) -> combined bf16 B^T buffer wcatT[1536][768].
__global__ void transpose_w_kernel(const float* __restrict__ wk, const float* __restrict__ wv,
                                   __bf16* __restrict__ wcatT)
{
  const float* src = blockIdx.z ? wv : wk;
  __bf16* dst = wcatT + (blockIdx.z ? (size_t)768 * DIM : 0);
  __shared__ float tile[32][33];
  int bx = blockIdx.x, by = blockIdx.y;
  int tx = threadIdx.x, ty = threadIdx.y;
  #pragma unroll
  for (int i = 0; i < 32; i += 8)
    tile[ty + i][tx] = src[(size_t)(by*32 + ty + i) * DIM + bx*32 + tx];
  __syncthreads();
  #pragma unroll
  for (int i = 0; i < 32; i += 8)
    dst[(size_t)(bx*32 + ty + i) * DIM + by*32 + tx] = (__bf16)tile[tx][ty + i];
}

// ---------------------------------------------------------------------------
// K4: [k_newc | v_newc] = xbf(compact) @ wcatT^T (+bias), m97 structure.
__launch_bounds__(256)
__global__ void kv_gemm_kernel(const __bf16* __restrict__ xbf, const __bf16* __restrict__ wcatT,
                               const float* __restrict__ bk, const float* __restrict__ bv,
                               __bf16* __restrict__ k_newc, __bf16* __restrict__ v_newc,
                               const int* __restrict__ mc)
{
  int Mc = mc[0];
  int npanels = (Mc + 127) >> 7;
  int bid = blockIdx.x;                 // 8 * 13 * 12 = 1248
  int xcd = bid & 7, s = bid >> 3;
  int panel = (s / 12) * 8 + xcd;
  if (panel >= npanels) return;
  int col0 = (s % 12) * 128;
  int row0 = panel * 128;

  __shared__ __align__(16) __bf16 As[128][32];
  __shared__ __align__(16) __bf16 Bs[128][32];
  int t = threadIdx.x;
  int lane = t & 63, wid = t >> 6;
  int wr = wid >> 1, wc = wid & 1;
  int fr = lane & 15, fg = lane >> 4;

  int lr = t >> 2, lc = (t & 3) << 3;
  int ar0 = min(row0 + lr, Mc - 1);
  int ar1 = min(row0 + 64 + lr, Mc - 1);
  const __bf16* aG0 = xbf + (size_t)ar0 * DIM + lc;
  const __bf16* aG1 = xbf + (size_t)ar1 * DIM + lc;
  const __bf16* bG0 = wcatT + (size_t)(col0 + lr) * DIM + lc;
  const __bf16* bG1 = wcatT + (size_t)(col0 + 64 + lr) * DIM + lc;
  __bf16* lA0 = &As[lr][lc];
  __bf16* lA1 = &As[64 + lr][lc];
  __bf16* lB0 = &Bs[lr][lc];
  __bf16* lB1 = &Bs[64 + lr][lc];

  f32x4 acc[4][4];
  #pragma unroll
  for (int m = 0; m < 4; m++)
    #pragma unroll
    for (int n = 0; n < 4; n++) acc[m][n] = (f32x4){0.f, 0.f, 0.f, 0.f};

  for (int k0 = 0; k0 < DIM; k0 += 32) {
    gl_lds16(aG0 + k0, lA0);
    gl_lds16(aG1 + k0, lA1);
    gl_lds16(bG0 + k0, lB0);
    gl_lds16(bG1 + k0, lB1);
    __syncthreads();
    bf16x8 af[4], bb[4];
    #pragma unroll
    for (int m = 0; m < 4; m++) af[m] = *(const bf16x8*)&As[wr*64 + m*16 + fr][fg << 3];
    #pragma unroll
    for (int n = 0; n < 4; n++) bb[n] = *(const bf16x8*)&Bs[wc*64 + n*16 + fr][fg << 3];
    #pragma unroll
    for (int m = 0; m < 4; m++)
      #pragma unroll
      for (int n = 0; n < 4; n++)
        acc[m][n] = __builtin_amdgcn_mfma_f32_16x16x32_bf16(af[m], bb[n], acc[m][n], 0, 0, 0);
    __syncthreads();
  }

  bool isK = (col0 < 768);
  const float* bias = isK ? bk : bv;
  __bf16* dst = isK ? k_newc : v_newc;
  int cbase = isK ? col0 : col0 - 768;
  #pragma unroll
  for (int n = 0; n < 4; n++) {
    int dcol = cbase + wc*64 + n*16 + fr;
    float bc = bias[dcol];
    #pragma unroll
    for (int m = 0; m < 4; m++) {
      int orow = row0 + wr*64 + m*16 + fg*4;
      #pragma unroll
      for (int r = 0; r < 4; r++) {
        int rr = orow + r;
        if (rr < Mc) dst[(size_t)rr * DIM + dcol] = (__bf16)(acc[m][n][r] + bc);
      }
    }
  }
}

// ---------------------------------------------------------------------------
// K5: partial inner GEMM over MASKED rows only.
__launch_bounds__(256)
__global__ void inner_gemm_kernel(const float* __restrict__ dpp, const float* __restrict__ w1,
                                  const int* __restrict__ mrowlist, const int* __restrict__ mc,
                                  float* __restrict__ partI)
{
  int mcnt = mc[1];
  int row0 = blockIdx.x * 32;
  if (row0 >= mcnt) return;
  int t = threadIdx.x;
  int c = t & 63;
  int rq = t >> 6;                    // 4 waves, each 8 rows
  int k0base = blockIdx.y * 192;
  __shared__ __align__(16) float Xs[32][68];
  __shared__ int rlist[32];
  if (t < 32) rlist[t] = mrowlist[min(row0 + t, mcnt - 1)];
  __syncthreads();
  float acc[8];
  #pragma unroll
  for (int i = 0; i < 8; i++) acc[i] = 0.f;
  for (int k0 = k0base; k0 < k0base + 192; k0 += 64) {
    {
      int rr = t >> 3, c8 = (t & 7) << 3;
      const float* src = &dpp[(size_t)rlist[rr]*DIM + k0 + c8];
      *(float4*)&Xs[rr][c8]     = *(const float4*)(src);
      *(float4*)&Xs[rr][c8 + 4] = *(const float4*)(src + 4);
    }
    __syncthreads();
    const float* Wp = w1 + (size_t)k0*INNER_D + c;
    #pragma unroll 4
    for (int kk = 0; kk < 64; kk += 4) {
      float w0 = Wp[(size_t)(kk+0)*INNER_D];
      float w1v = Wp[(size_t)(kk+1)*INNER_D];
      float w2v = Wp[(size_t)(kk+2)*INNER_D];
      float w3v = Wp[(size_t)(kk+3)*INNER_D];
      #pragma unroll
      for (int r = 0; r < 8; r++) {
        float4 xv = *(const float4*)&Xs[rq*8 + r][kk];
        acc[r] += xv.x*w0 + xv.y*w1v + xv.z*w2v + xv.w*w3v;
      }
    }
    __syncthreads();
  }
  #pragma unroll
  for (int r = 0; r < 8; r++) {
    int crow = row0 + rq*8 + r;
    if (crow < mcnt) partI[((size_t)blockIdx.y*TT + crow)*INNER_D + c] = acc[r];
  }
}

// K5b: inner_c = gelu_tanh(sum_ks partI)
__global__ void reduce_inner_kernel(const float* __restrict__ partI, const int* __restrict__ mc,
                                    float* __restrict__ inner_c)
{
  int i = blockIdx.x * 256 + threadIdx.x;
  if (i >= mc[1] * INNER_D) return;
  float x = partI[i] + partI[(size_t)TT*INNER_D + i] + partI[(size_t)2*TT*INNER_D + i]
          + partI[(size_t)3*TT*INNER_D + i];
  float u = 0.7978845608028654f * (x + 0.044715f * x * x * x);
  inner_c[i] = 0.5f * x * (1.0f + tanhf(u));
}

// ---------------------------------------------------------------------------
// K6: per (f,b): h_cls row, qbase row, compact Xq row.
__launch_bounds__(256)
__global__ void cls_gather_kernel(const float* __restrict__ hs, const float* __restrict__ hqkv,
                                  const __bf16* __restrict__ xbf, const float* __restrict__ bq,
                                  const float* __restrict__ w2, const float* __restrict__ inner_c,
                                  const int* __restrict__ gidx, const unsigned char* __restrict__ mask,
                                  const int* __restrict__ remap, const int* __restrict__ mremap,
                                  float* __restrict__ h_cls, float* __restrict__ qbase,
                                  float* __restrict__ Xq)
{
  int fb = blockIdx.x, t = threadIdx.x;
  int g0 = fb * NPOS;
  int idx = gidx[g0];
  int m = mask[g0];
  const float* q_cache = hqkv + (size_t)NC * DIM;
  __shared__ float inn[INNER_D];
  if (t < INNER_D) inn[t] = m ? inner_c[(size_t)mremap[g0]*INNER_D + t] : 0.f;
  __syncthreads();
  bool fresh = idx >= NC;
  int crow = fresh ? remap[idx - NC] : 0;
  for (int c = t; c < DIM; c += 256) {
    float xv = fresh ? (float)xbf[(size_t)crow*DIM + c] : 0.f;
    Xq[(size_t)fb*DIM + c] = xv;
    float hv = fresh ? hs[(size_t)(idx - NC)*DIM + c] : hqkv[(size_t)idx*DIM + c];
    float qb = fresh ? bq[c] : q_cache[(size_t)idx*DIM + c];
    if (m) {
      float hd = 0.f, qd = 0.f;
      #pragma unroll 8
      for (int j = 0; j < INNER_D; j++) {
        float iv = inn[j];
        hd += iv * w2[(size_t)j*FF + c];
        qd += iv * w2[(size_t)j*FF + DIM + c];
      }
      hv += hd; qb += qd;
    }
    h_cls[(size_t)fb*DIM + c] = hv;
    qbase[(size_t)fb*DIM + c] = qb;
  }
}

// ---------------------------------------------------------------------------
// K7: partial GEMM, M=64 fixed. grid (N/64, K/kChunk), 256 thr.
__launch_bounds__(256)
__global__ void pgemm_kernel(const float* __restrict__ X, const float* __restrict__ W,
                             float* __restrict__ part, int N, int K, int kChunk)
{
  int t = threadIdx.x;
  int c = t & 63;
  int rq = t >> 6;
  int col0 = blockIdx.x * 64;
  int k0base = blockIdx.y * kChunk;
  __shared__ __align__(16) float Xs[64][68];
  float acc[16];
  #pragma unroll
  for (int i = 0; i < 16; i++) acc[i] = 0.f;
  for (int k0 = k0base; k0 < k0base + kChunk; k0 += 64) {
    #pragma unroll
    for (int j = 0; j < 4; j++) {
      int v = t + 256*j;
      int rr = v >> 4, cc = (v & 15) << 2;
      *(float4*)&Xs[rr][cc] = *(const float4*)&X[(size_t)rr*K + k0 + cc];
    }
    __syncthreads();
    const float* Wp = W + (size_t)k0*N + col0 + c;
    #pragma unroll 4
    for (int kk = 0; kk < 64; kk += 4) {
      float w0 = Wp[(size_t)(kk+0)*N];
      float w1 = Wp[(size_t)(kk+1)*N];
      float w2 = Wp[(size_t)(kk+2)*N];
      float w3 = Wp[(size_t)(kk+3)*N];
      #pragma unroll
      for (int r = 0; r < 16; r++) {
        float4 xv = *(const float4*)&Xs[rq*16 + r][kk];
        acc[r] += xv.x*w0 + xv.y*w1 + xv.z*w2 + xv.w*w3;
      }
    }
    __syncthreads();
  }
  #pragma unroll
  for (int r = 0; r < 16; r++)
    part[((size_t)blockIdx.y*64 + rq*16 + r)*N + col0 + c] = acc[r];
}

// K7b: q0s = (qbase + sum_s partQ) * SCALE     (12 slabs)
__global__ void reduce_q_kernel(const float* __restrict__ qbase, const float* __restrict__ partQ,
                                float* __restrict__ q0s)
{
  int i = blockIdx.x * 256 + threadIdx.x;   // < 49152
  float v = qbase[i];
  #pragma unroll
  for (int s = 0; s < 12; s++) v += partQ[(size_t)s*FB_N*DIM + i];
  q0s[i] = v * 0.125f;
}

// ---------------------------------------------------------------------------
// K8: CLS-row attention, 512 threads (8 waves). Quad-dot pattern: 8 lanes per
// key row (lane dg owns 8 contiguous elems) -> coalesced gathers + shfl reduce.
__launch_bounds__(512)
__global__ void attn_cls_kernel(const float* __restrict__ hqkv, const __bf16* __restrict__ k_newc,
                                const __bf16* __restrict__ v_newc, const float* __restrict__ w2,
                                const float* __restrict__ inner_c, const int* __restrict__ gidx,
                                const unsigned char* __restrict__ mask, const int* __restrict__ remap,
                                const int* __restrict__ mremap,
                                const float* __restrict__ q0s, float* __restrict__ pre_cls)
{
  int bid = blockIdx.x;
  int fb = bid / NH, h = bid % NH;
  int t = threadIdx.x;
  int lane = t & 63, wv = t >> 6;        // 8 waves
  const float* k_cache = hqkv + (size_t)2 * NC * DIM;
  const float* v_cache = hqkv + (size_t)3 * NC * DIM;
  __shared__ float q0[HD], w2q[INNER_D], tj[INNER_D];
  __shared__ float p[200];
  __shared__ int sidx[200];
  __shared__ int smg[200];        // compact inner row (-1 if unmasked)
  __shared__ float red[16];
  __shared__ float pacc[8][64];
  // phase 0: q0 + index translation (parallel)
  if (t < HD) q0[t] = q0s[(size_t)fb*DIM + h*HD + t];
  int tt = t - 64;
  if (tt >= 0 && tt < NPOS) {
    int g = fb * NPOS + tt;
    int idx = gidx[g];
    if (idx >= NC) idx = NC + remap[idx - NC];
    sidx[tt] = idx;
    smg[tt] = mask[g] ? mremap[g] : -1;
  }
  __syncthreads();
  // phase 1: w2q[j] = dot(q0, w2 kd column block) — 8 lanes per j
  {
    int j = t >> 3, dg = t & 7;
    const float* wr = w2 + (size_t)j*FF + 2*DIM + h*HD + dg*8;
    float4 a = *(const float4*)wr, b = *(const float4*)(wr + 4);
    const float* q = &q0[dg*8];
    float s = a.x*q[0] + a.y*q[1] + a.z*q[2] + a.w*q[3]
            + b.x*q[4] + b.y*q[5] + b.z*q[6] + b.w*q[7];
    s += __shfl_xor(s, 1); s += __shfl_xor(s, 2); s += __shfl_xor(s, 4);
    if (dg == 0) w2q[j] = s;
  }
  __syncthreads();
  // phase 2: scores — 8 lanes per key row, 64 rows per pass
  #pragma unroll
  for (int it = 0; it < 4; it++) {
    int n = it*64 + wv*8 + (lane >> 3);
    int dg = lane & 7;
    if (n < NPOS) {
      int idx = sidx[n], mg = smg[n];
      const float* q = &q0[dg*8];
      float s = 0.f;
      if (idx >= NC) {
        bf16x8 kv = *(const bf16x8*)(k_newc + (size_t)(idx - NC)*DIM + h*HD + dg*8);
        #pragma unroll
        for (int j = 0; j < 8; j++) s += q[j] * (float)kv[j];
      } else {
        const float* kr = k_cache + (size_t)idx*DIM + h*HD + dg*8;
        float4 a = *(const float4*)kr, b = *(const float4*)(kr + 4);
        s = a.x*q[0] + a.y*q[1] + a.z*q[2] + a.w*q[3]
          + b.x*q[4] + b.y*q[5] + b.z*q[6] + b.w*q[7];
      }
      if (mg >= 0) {
        const float* ir = inner_c + (size_t)mg*INNER_D + dg*8;
        float4 a = *(const float4*)ir, b = *(const float4*)(ir + 4);
        const float* wq8 = &w2q[dg*8];
        s += a.x*wq8[0] + a.y*wq8[1] + a.z*wq8[2] + a.w*wq8[3]
           + b.x*wq8[4] + b.y*wq8[5] + b.z*wq8[6] + b.w*wq8[7];
      }
      s += __shfl_xor(s, 1); s += __shfl_xor(s, 2); s += __shfl_xor(s, 4);
      if (dg == 0) p[n] = s;
    }
  }
  __syncthreads();
  // softmax
  float lm = (t < NPOS) ? p[t] : -1e30f;
  lm = wred_max(lm);
  if (lane == 0) red[wv] = lm;
  __syncthreads();
  float mx = red[0];
  #pragma unroll
  for (int w = 1; w < 8; w++) mx = fmaxf(mx, red[w]);
  float lp = 0.f;
  if (t < NPOS) { lp = __expf(p[t] - mx); p[t] = lp; }
  float ls = wred_sum(lp);
  if (lane == 0) red[8 + wv] = ls;
  __syncthreads();
  float inv = red[8];
  #pragma unroll
  for (int w = 1; w < 8; w++) inv += red[8 + w];
  inv = 1.0f / inv;
  // tp: masked inner accumulation (lane = j, coalesced)
  float tp = 0.f;
  for (int n = wv; n < NPOS; n += 8) {
    int mg = smg[n];
    if (mg >= 0) tp += p[n] * inner_c[(size_t)mg*INNER_D + lane];
  }
  pacc[wv][lane] = tp;
  __syncthreads();
  if (t < INNER_D) tj[t] = pacc[0][t] + pacc[1][t] + pacc[2][t] + pacc[3][t]
                         + pacc[4][t] + pacc[5][t] + pacc[6][t] + pacc[7][t];
  __syncthreads();
  // PV: gathered V accumulation (lane = d, coalesced)
  float va = 0.f;
  for (int n = wv; n < NPOS; n += 8) {
    float pn = p[n];
    int idx = sidx[n];
    float vvv;
    if (idx >= NC) vvv = (float)v_newc[(size_t)(idx - NC)*DIM + h*HD + lane];
    else           vvv = v_cache[(size_t)idx*DIM + h*HD + lane];
    va += pn * vvv;
  }
  __syncthreads();
  pacc[wv][lane] = va;
  __syncthreads();
  if (t < HD) {
    float o = pacc[0][t] + pacc[1][t] + pacc[2][t] + pacc[3][t]
            + pacc[4][t] + pacc[5][t] + pacc[6][t] + pacc[7][t];
    const float* wv2 = w2 + 3*DIM + h*HD + t;   // vd columns (coalesced per j)
    float dd = 0.f;
    for (int j = 0; j < INNER_D; j++) dd += tj[j] * wv2[(size_t)j*FF];
    pre_cls[(size_t)fb*DIM + h*HD + t] = (o + dd) * inv;
  }
}

// ---------------------------------------------------------------------------
// K9: out0 = h_cls + (sum_s partW) + bo;  yln = LN2(out0).  One block per row. (12 slabs)
__launch_bounds__(256)
__global__ void reduce_wo_ln_kernel(const float* __restrict__ partW, const float* __restrict__ bo,
                                    const float* __restrict__ h_cls, const float* __restrict__ g,
                                    const float* __restrict__ b, float* __restrict__ out0,
                                    float* __restrict__ yln)
{
  int row = blockIdx.x, t = threadIdx.x;
  float v[3];
  #pragma unroll
  for (int j = 0; j < 3; j++) {
    int c = t + j*256;
    float s = h_cls[(size_t)row*DIM + c] + bo[c];
    #pragma unroll
    for (int ks = 0; ks < 12; ks++) s += partW[((size_t)ks*FB_N + row)*DIM + c];
    v[j] = s;
    out0[(size_t)row*DIM + c] = s;
  }
  float sm = wred_sum(v[0] + v[1] + v[2]);
  float sq = wred_sum(v[0]*v[0] + v[1]*v[1] + v[2]*v[2]);
  __shared__ float red[8];
  int wv = t >> 6, ln = t & 63;
  if (ln == 0) { red[wv] = sm; red[4 + wv] = sq; }
  __syncthreads();
  float mean = (red[0]+red[1]+red[2]+red[3]) * (1.f/DIM);
  float var  = (red[4]+red[5]+red[6]+red[7]) * (1.f/DIM) - mean*mean;
  float rr = rsqrtf(var + 1e-5f);
  #pragma unroll
  for (int j = 0; j < 3; j++) {
    int c = t + j*256;
    yln[(size_t)row*DIM + c] = (v[j] - mean) * rr * g[c] + b[c];
  }
}

// K10: t1 = quick_gelu(sum_s partF1 + fc1b)    (6 slabs)
__global__ void reduce_gelu_kernel(const float* __restrict__ partF1, const float* __restrict__ b1,
                                   float* __restrict__ t1)
{
  int i = blockIdx.x * 256 + threadIdx.x;   // < 196608
  int c = i % FF;
  float v = b1[c];
  #pragma unroll
  for (int s = 0; s < 6; s++) v += partF1[(size_t)s*FB_N*FF + i];
  t1[i] = v / (1.0f + __expf(-1.702f * v));
}

// K11: d_out = out0 + fc2_b + sum_s partF2     (24 slabs)
__global__ void final_reduce_kernel(const float* __restrict__ out0, const float* __restrict__ b2,
                                    const float* __restrict__ partF2, float* __restrict__ dout)
{
  int i = blockIdx.x * 256 + threadIdx.x;   // < 49152
  int c = i % DIM;
  float v = out0[i] + b2[c];
  #pragma unroll
  for (int s = 0; s < 24; s++) v += partF2[(size_t)s*FB_N*DIM + i];
  dout[i] = v;
}

// ---------------------------------------------------------------------------
extern "C" void kernel_launch(void* const* d_in, const int* in_sizes, int n_in,
                              void* d_out, int out_size, void* d_ws, size_t ws_size,
                              hipStream_t stream)
{
  const float* hs   = (const float*)d_in[0];
  const float* dpp  = (const float*)d_in[1];
  const float* hqkv = (const float*)d_in[2];
  const float* ln1g = (const float*)d_in[3];
  const float* ln1b = (const float*)d_in[4];
  const float* wq   = (const float*)d_in[5];
  const float* bq   = (const float*)d_in[6];
  const float* wk   = (const float*)d_in[7];
  const float* bk   = (const float*)d_in[8];
  const float* wvw  = (const float*)d_in[9];
  const float* bv   = (const float*)d_in[10];
  const float* w1   = (const float*)d_in[11];
  const float* w2   = (const float*)d_in[12];
  const float* wo   = (const float*)d_in[13];
  const float* bo   = (const float*)d_in[14];
  const float* ln2g = (const float*)d_in[15];
  const float* ln2b = (const float*)d_in[16];
  const float* fc1w = (const float*)d_in[17];
  const float* fc1b = (const float*)d_in[18];
  const float* fc2w = (const float*)d_in[19];
  const float* fc2b = (const float*)d_in[20];
  const int*   gidx = (const int*)d_in[21];
  const unsigned char* rmap = (const unsigned char*)d_in[22];
  float* outp = (float*)d_out;

  char* ws = (char*)d_ws;
  size_t off = 0;
  auto alloc = [&](size_t bytes) { void* p = ws + off; off += (bytes + 255) & ~(size_t)255; return p; };
  unsigned char* mask = (unsigned char*)alloc(TT);
  int* flag     = (int*)alloc((size_t)TT * 4);
  int* rowlist  = (int*)alloc((size_t)TT * 4);
  int* remap    = (int*)alloc((size_t)TT * 4);
  int* mrowlist = (int*)alloc((size_t)TT * 4);
  int* mremap   = (int*)alloc((size_t)TT * 4);
  int* mc       = (int*)alloc(256);
  __bf16* xbf    = (__bf16*)alloc((size_t)TT * DIM * 2);
  __bf16* wcatT  = (__bf16*)alloc((size_t)NCOLS * DIM * 2);
  __bf16* k_newc = (__bf16*)alloc((size_t)TT * DIM * 2);
  __bf16* v_newc = (__bf16*)alloc((size_t)TT * DIM * 2);
  float* partI   = (float*)alloc((size_t)4 * TT * INNER_D * 4);
  float* inner_c = (float*)alloc((size_t)TT * INNER_D * 4);
  float* h_cls  = (float*)alloc((size_t)FB_N * DIM * 4);
  float* qbase  = (float*)alloc((size_t)FB_N * DIM * 4);
  float* Xq     = (float*)alloc((size_t)FB_N * DIM * 4);
  float* q0s    = (float*)alloc((size_t)FB_N * DIM * 4);
  float* precls = (float*)alloc((size_t)FB_N * DIM * 4);
  float* out0   = (float*)alloc((size_t)FB_N * DIM * 4);
  float* yln    = (float*)alloc((size_t)FB_N * DIM * 4);
  float* t1     = (float*)alloc((size_t)FB_N * FF * 4);
  float* partQ  = (float*)alloc((size_t)12 * FB_N * DIM * 4);
  float* partW  = (float*)alloc((size_t)12 * FB_N * DIM * 4);
  float* partF1 = (float*)alloc((size_t)6  * FB_N * FF  * 4);
  float* partF2 = (float*)alloc((size_t)24 * FB_N * DIM * 4);
  (void)ws_size; (void)in_sizes; (void)n_in; (void)out_size;

  mask_norm_kernel<<<1, 256, 0, stream>>>(rmap, mask);
  hipMemsetAsync(flag, 0, (size_t)TT * 4, stream);
  flag_kernel<<<(TT + 255) / 256, 256, 0, stream>>>(gidx, flag);
  scan_kernel<<<1, 1024, 0, stream>>>(flag, mask, rowlist, remap, mrowlist, mremap, mc);
  ln_kernel<<<TT, 256, 0, stream>>>(hs, ln1g, ln1b, xbf, rowlist, mc);
  transpose_w_kernel<<<dim3(24, 24, 2), dim3(32, 8), 0, stream>>>(wk, wvw, wcatT);
  kv_gemm_kernel<<<1248, 256, 0, stream>>>(xbf, wcatT, bk, bv, k_newc, v_newc, mc);
  inner_gemm_kernel<<<dim3((TT + 31) / 32, 4), 256, 0, stream>>>(dpp, w1, mrowlist, mc, partI);
  reduce_inner_kernel<<<(TT * INNER_D + 255) / 256, 256, 0, stream>>>(partI, mc, inner_c);
  cls_gather_kernel<<<FB_N, 256, 0, stream>>>(hs, hqkv, xbf, bq, w2, inner_c, gidx, mask,
                                              remap, mremap, h_cls, qbase, Xq);
  // q0s = (qbase + Xq @ wq) * SCALE   (zero Xq rows for cached fb's)
  pgemm_kernel<<<dim3(12, 12), 256, 0, stream>>>(Xq, wq, partQ, DIM, DIM, 64);
  reduce_q_kernel<<<192, 256, 0, stream>>>(qbase, partQ, q0s);
  attn_cls_kernel<<<FB_N * NH, 512, 0, stream>>>(hqkv, k_newc, v_newc, w2, inner_c, gidx, mask,
                                                 remap, mremap, q0s, precls);
  // out0 = h_cls + precls@wo + bo ; yln = LN2(out0)
  pgemm_kernel<<<dim3(12, 12), 256, 0, stream>>>(precls, wo, partW, DIM, DIM, 64);
  reduce_wo_ln_kernel<<<FB_N, 256, 0, stream>>>(partW, bo, h_cls, ln2g, ln2b, out0, yln);
  // t1 = qgelu(yln@fc1w + fc1b)
  pgemm_kernel<<<dim3(48, 6), 256, 0, stream>>>(yln, fc1w, partF1, FF, DIM, 128);
  reduce_gelu_kernel<<<768, 256, 0, stream>>>(partF1, fc1b, t1);
  // d_out = out0 + t1@fc2w + fc2b
  pgemm_kernel<<<dim3(12, 24), 256, 0, stream>>>(t1, fc2w, partF2, DIM, FF, 128);
  final_reduce_kernel<<<192, 256, 0, stream>>>(out0, fc2b, partF2, outp);
}

// Round 8
// 231.879 us; speedup vs baseline: 3.6601x; 1.0978x over previous
//
#include <hip/hip_runtime.h>
#include <hip/hip_bf16.h>

// Problem constants
#define TT 12608          // 4*B*N rows of hs
#define NC 3152           // B*N cache rows (= 16*197)
#define DIM 768
#define NPOS 197
#define NH 12
#define HD 64
#define FB_N 64           // 4*B
#define FF 3072
#define INNER_D 64
#define NCOLS 1536        // K cols + V cols combined

typedef __bf16 bf16x8 __attribute__((ext_vector_type(8)));
typedef float f32x4 __attribute__((ext_vector_type(4)));

__device__ inline float wred_sum(float v){
  #pragma unroll
  for (int o = 32; o > 0; o >>= 1) v += __shfl_down(v, o, 64);
  return v;
}
__device__ inline float wred_max(float v){
  #pragma unroll
  for (int o = 32; o > 0; o >>= 1) v = fmaxf(v, __shfl_down(v, o, 64));
  return v;
}

// async global->LDS, 16B per lane; LDS dest = wave-uniform base + lane*16
__device__ __forceinline__ void gl_lds16(const __bf16* g, __bf16* l) {
  __builtin_amdgcn_global_load_lds(
      (const __attribute__((address_space(1))) void*)g,
      (__attribute__((address_space(3))) void*)l, 16, 0, 0);
}

// ---------------------------------------------------------------------------
// K1: normalize reuse_map to uint8 regardless of harness dtype (int32/int8/f32).
__global__ void mask_norm_kernel(const unsigned char* __restrict__ rm,
                                 unsigned char* __restrict__ mask)
{
  __shared__ int flagA, flagB;
  if (threadIdx.x == 0) { flagA = 0; flagB = 0; }
  __syncthreads();
  int la = 0, lb = 0;
  for (int i = threadIdx.x; i < TT; i += blockDim.x) {
    unsigned char v = rm[i];
    if (v) { if (i & 3) la = 1; else lb = 1; }
  }
  if (la) atomicOr(&flagA, 1);
  if (lb) atomicOr(&flagB, 1);
  __syncthreads();
  int mode = (!flagA) ? 0 : (flagB ? 1 : 2); // 0=int32, 1=byte, 2=f32
  for (int i = threadIdx.x; i < TT; i += blockDim.x) {
    unsigned char m;
    if (mode == 0)      m = ((const int*)rm)[i] != 0;
    else if (mode == 1) m = rm[i] != 0;
    else                m = ((const float*)rm)[i] != 0.0f;
    mask[i] = m;
  }
}

// ---------------------------------------------------------------------------
// K1b: flag referenced fresh rows.
__global__ void flag_kernel(const int* __restrict__ gidx, int* __restrict__ flag)
{
  int g = blockIdx.x * 256 + threadIdx.x;
  if (g < TT) { int idx = gidx[g]; if (idx >= NC) flag[idx - NC] = 1; }
}

// K1c: single-block dual exclusive scan:
//   A: fresh-row compaction (flag)  -> rowlist / remap / mc[0]
//   B: masked-row compaction (mask) -> mrowlist / mremap / mc[1]
__launch_bounds__(1024)
__global__ void scan_kernel(const int* __restrict__ flag, const unsigned char* __restrict__ mask,
                            int* __restrict__ rowlist, int* __restrict__ remap,
                            int* __restrict__ mrowlist, int* __restrict__ mremap,
                            int* __restrict__ mc)
{
  __shared__ int wsumA[16], wsumB[16];
  __shared__ int baseA, baseB;
  int t = threadIdx.x, lane = t & 63, wv = t >> 6;
  if (t == 0) { baseA = 0; baseB = 0; }
  __syncthreads();
  for (int start = 0; start < TT; start += 1024) {
    int i = start + t;
    int fA = (i < TT) ? flag[i] : 0;
    int fB = (i < TT) ? (int)mask[i] : 0;
    unsigned long long mbA = __ballot(fA != 0);
    unsigned long long mbB = __ballot(fB != 0);
    int rankA = __popcll(mbA & ((1ULL << lane) - 1ULL));
    int rankB = __popcll(mbB & ((1ULL << lane) - 1ULL));
    if (lane == 0) { wsumA[wv] = __popcll(mbA); wsumB[wv] = __popcll(mbB); }
    __syncthreads();
    int woffA = 0, woffB = 0;
    for (int w2 = 0; w2 < wv; w2++) { woffA += wsumA[w2]; woffB += wsumB[w2]; }
    if (fA) { int pos = baseA + woffA + rankA; rowlist[pos] = i; remap[i] = pos; }
    if (fB) { int pos = baseB + woffB + rankB; mrowlist[pos] = i; mremap[i] = pos; }
    __syncthreads();
    if (t == 0) {
      int ta = 0, tb = 0;
      for (int w2 = 0; w2 < 16; w2++) { ta += wsumA[w2]; tb += wsumB[w2]; }
      baseA += ta; baseB += tb;
    }
    __syncthreads();
  }
  if (t == 0) { mc[0] = baseA; mc[1] = baseB; }
}

// ---------------------------------------------------------------------------
// K2: row LayerNorm over 768 cols -> bf16, COMPACT rows only.
__launch_bounds__(256)
__global__ void ln_kernel(const float* __restrict__ in, const float* __restrict__ g,
                          const float* __restrict__ b, __bf16* __restrict__ outp,
                          const int* __restrict__ rowlist, const int* __restrict__ mc)
{
  if ((int)blockIdx.x >= mc[0]) return;
  int row = rowlist[blockIdx.x];
  int t = threadIdx.x;
  const float* x = in + (size_t)row * DIM;
  float v0 = x[t], v1 = x[t + 256], v2 = x[t + 512];
  float s = wred_sum(v0 + v1 + v2);
  float q = wred_sum(v0*v0 + v1*v1 + v2*v2);
  __shared__ float red[8];
  int wv = t >> 6, ln = t & 63;
  if (ln == 0) { red[wv] = s; red[4 + wv] = q; }
  __syncthreads();
  float mean = (red[0]+red[1]+red[2]+red[3]) * (1.f/DIM);
  float var  = (red[4]+red[5]+red[6]+red[7]) * (1.f/DIM) - mean*mean;
  float rr = rsqrtf(var + 1e-5f);
  #pragma unroll
  for (int j = 0; j < 3; j++) {
    int c = t + j*256;
    float v = (j==0) ? v0 : (j==1) ? v1 : v2;
    outp[(size_t)blockIdx.x*DIM + c] = (__bf16)((v - mean) * rr * g[c] + b[c]);
  }
}

// ---------------------------------------------------------------------------
// K3: transpose wk/wv (768x768 f32) -> combined bf16 B^T buffer wcatT[1536][768].
__global__ void transpose_w_kernel(const float* __restrict__ wk, const float* __restrict__ wv,
                                   __bf16* __restrict__ wcatT)
{
  const float* src = blockIdx.z ? wv : wk;
  __bf16* dst = wcatT + (blockIdx.z ? (size_t)768 * DIM : 0);
  __shared__ float tile[32][33];
  int bx = blockIdx.x, by = blockIdx.y;
  int tx = threadIdx.x, ty = threadIdx.y;
  #pragma unroll
  for (int i = 0; i < 32; i += 8)
    tile[ty + i][tx] = src[(size_t)(by*32 + ty + i) * DIM + bx*32 + tx];
  __syncthreads();
  #pragma unroll
  for (int i = 0; i < 32; i += 8)
    dst[(size_t)(bx*32 + ty + i) * DIM + by*32 + tx] = (__bf16)tile[tx][ty + i];
}

// K3b: transpose w1 (768x64 f32) -> bf16 w1T[64][768].
__global__ void transpose_w1_kernel(const float* __restrict__ w1, __bf16* __restrict__ w1T)
{
  __shared__ float tile[32][33];
  int bx = blockIdx.x, by = blockIdx.y;   // bx: k-tile (24), by: n-tile (2)
  int tx = threadIdx.x, ty = threadIdx.y;
  #pragma unroll
  for (int i = 0; i < 32; i += 8)
    tile[ty + i][tx] = w1[(size_t)(bx*32 + ty + i) * INNER_D + by*32 + tx];
  __syncthreads();
  #pragma unroll
  for (int i = 0; i < 32; i += 8)
    w1T[(size_t)(by*32 + ty + i) * DIM + bx*32 + tx] = (__bf16)tile[tx][ty + i];
}

// ---------------------------------------------------------------------------
// K4: [k_newc | v_newc] = xbf(compact) @ wcatT^T (+bias), m97 structure.
__launch_bounds__(256)
__global__ void kv_gemm_kernel(const __bf16* __restrict__ xbf, const __bf16* __restrict__ wcatT,
                               const float* __restrict__ bk, const float* __restrict__ bv,
                               __bf16* __restrict__ k_newc, __bf16* __restrict__ v_newc,
                               const int* __restrict__ mc)
{
  int Mc = mc[0];
  int npanels = (Mc + 127) >> 7;
  int bid = blockIdx.x;                 // 8 * 13 * 12 = 1248
  int xcd = bid & 7, s = bid >> 3;
  int panel = (s / 12) * 8 + xcd;
  if (panel >= npanels) return;
  int col0 = (s % 12) * 128;
  int row0 = panel * 128;

  __shared__ __align__(16) __bf16 As[128][32];
  __shared__ __align__(16) __bf16 Bs[128][32];
  int t = threadIdx.x;
  int lane = t & 63, wid = t >> 6;
  int wr = wid >> 1, wc = wid & 1;
  int fr = lane & 15, fg = lane >> 4;

  int lr = t >> 2, lc = (t & 3) << 3;
  int ar0 = min(row0 + lr, Mc - 1);
  int ar1 = min(row0 + 64 + lr, Mc - 1);
  const __bf16* aG0 = xbf + (size_t)ar0 * DIM + lc;
  const __bf16* aG1 = xbf + (size_t)ar1 * DIM + lc;
  const __bf16* bG0 = wcatT + (size_t)(col0 + lr) * DIM + lc;
  const __bf16* bG1 = wcatT + (size_t)(col0 + 64 + lr) * DIM + lc;
  __bf16* lA0 = &As[lr][lc];
  __bf16* lA1 = &As[64 + lr][lc];
  __bf16* lB0 = &Bs[lr][lc];
  __bf16* lB1 = &Bs[64 + lr][lc];

  f32x4 acc[4][4];
  #pragma unroll
  for (int m = 0; m < 4; m++)
    #pragma unroll
    for (int n = 0; n < 4; n++) acc[m][n] = (f32x4){0.f, 0.f, 0.f, 0.f};

  for (int k0 = 0; k0 < DIM; k0 += 32) {
    gl_lds16(aG0 + k0, lA0);
    gl_lds16(aG1 + k0, lA1);
    gl_lds16(bG0 + k0, lB0);
    gl_lds16(bG1 + k0, lB1);
    __syncthreads();
    bf16x8 af[4], bb[4];
    #pragma unroll
    for (int m = 0; m < 4; m++) af[m] = *(const bf16x8*)&As[wr*64 + m*16 + fr][fg << 3];
    #pragma unroll
    for (int n = 0; n < 4; n++) bb[n] = *(const bf16x8*)&Bs[wc*64 + n*16 + fr][fg << 3];
    #pragma unroll
    for (int m = 0; m < 4; m++)
      #pragma unroll
      for (int n = 0; n < 4; n++)
        acc[m][n] = __builtin_amdgcn_mfma_f32_16x16x32_bf16(af[m], bb[n], acc[m][n], 0, 0, 0);
    __syncthreads();
  }

  bool isK = (col0 < 768);
  const float* bias = isK ? bk : bv;
  __bf16* dst = isK ? k_newc : v_newc;
  int cbase = isK ? col0 : col0 - 768;
  #pragma unroll
  for (int n = 0; n < 4; n++) {
    int dcol = cbase + wc*64 + n*16 + fr;
    float bc = bias[dcol];
    #pragma unroll
    for (int m = 0; m < 4; m++) {
      int orow = row0 + wr*64 + m*16 + fg*4;
      #pragma unroll
      for (int r = 0; r < 4; r++) {
        int rr = orow + r;
        if (rr < Mc) dst[(size_t)rr * DIM + dcol] = (__bf16)(acc[m][n][r] + bc);
      }
    }
  }
}

// ---------------------------------------------------------------------------
// K5: MFMA partial inner GEMM over MASKED rows:
// partI[ks][crow][64] = dpp[mrowlist[crow]] (K-chunk ks, 128 wide) @ w1.
// Tile 64 rows x 64 cols, 4 waves (2x2, each 32x32 = 2x2 frags), K-step 32.
// A reg-staged with fused f32->bf16 convert; B from pre-transposed w1T.
// LDS padded [64][40] -> <=2-way bank conflicts.
__launch_bounds__(256)
__global__ void inner_gemm_kernel(const float* __restrict__ dpp, const __bf16* __restrict__ w1T,
                                  const int* __restrict__ mrowlist, const int* __restrict__ mc,
                                  float* __restrict__ partI)
{
  int mcnt = mc[1];
  int row0 = blockIdx.x * 64;
  if (row0 >= mcnt) return;
  int k0base = blockIdx.y * 128;
  int t = threadIdx.x;
  int lane = t & 63, wid = t >> 6;
  int wr = wid >> 1, wc = wid & 1;        // 2x2 wave grid
  int fr = lane & 15, fg = lane >> 4;

  __shared__ __align__(16) __bf16 As[64][40];
  __shared__ __align__(16) __bf16 Bs[64][40];
  __shared__ int rlist[64];
  if (t < 64) rlist[t] = mrowlist[min(row0 + t, mcnt - 1)];
  __syncthreads();

  int lr = t >> 2, lc = (t & 3) << 3;     // staging: row 0..63, col {0,8,16,24}
  const float* aG = dpp + (size_t)rlist[lr] * DIM + lc;
  const __bf16* bG = w1T + (size_t)lr * DIM + lc;

  f32x4 acc[2][2];
  #pragma unroll
  for (int m = 0; m < 2; m++)
    #pragma unroll
    for (int n = 0; n < 2; n++) acc[m][n] = (f32x4){0.f, 0.f, 0.f, 0.f};

  for (int k0 = k0base; k0 < k0base + 128; k0 += 32) {
    // A: load 8 f32, convert to bf16x8, store b128
    float4 a0 = *(const float4*)(aG + k0);
    float4 a1 = *(const float4*)(aG + k0 + 4);
    bf16x8 av;
    av[0] = (__bf16)a0.x; av[1] = (__bf16)a0.y; av[2] = (__bf16)a0.z; av[3] = (__bf16)a0.w;
    av[4] = (__bf16)a1.x; av[5] = (__bf16)a1.y; av[6] = (__bf16)a1.z; av[7] = (__bf16)a1.w;
    *(bf16x8*)&As[lr][lc] = av;
    // B: bf16x8 direct
    *(bf16x8*)&Bs[lr][lc] = *(const bf16x8*)(bG + k0);
    __syncthreads();
    bf16x8 af[2], bb[2];
    #pragma unroll
    for (int m = 0; m < 2; m++) af[m] = *(const bf16x8*)&As[wr*32 + m*16 + fr][fg << 3];
    #pragma unroll
    for (int n = 0; n < 2; n++) bb[n] = *(const bf16x8*)&Bs[wc*32 + n*16 + fr][fg << 3];
    #pragma unroll
    for (int m = 0; m < 2; m++)
      #pragma unroll
      for (int n = 0; n < 2; n++)
        acc[m][n] = __builtin_amdgcn_mfma_f32_16x16x32_bf16(af[m], bb[n], acc[m][n], 0, 0, 0);
    __syncthreads();
  }

  // C/D layout: col=lane&15, row=(lane>>4)*4+reg
  #pragma unroll
  for (int m = 0; m < 2; m++) {
    #pragma unroll
    for (int n = 0; n < 2; n++) {
      int col = wc*32 + n*16 + fr;
      int orow = row0 + wr*32 + m*16 + fg*4;
      #pragma unroll
      for (int r = 0; r < 4; r++) {
        int rr = orow + r;
        if (rr < mcnt)
          partI[((size_t)blockIdx.y*TT + rr)*INNER_D + col] = acc[m][n][r];
      }
    }
  }
}

// K5b: inner_c = gelu_tanh(sum_ks partI)     (6 slabs)
__global__ void reduce_inner_kernel(const float* __restrict__ partI, const int* __restrict__ mc,
                                    float* __restrict__ inner_c)
{
  int i = blockIdx.x * 256 + threadIdx.x;
  if (i >= mc[1] * INNER_D) return;
  float x = 0.f;
  #pragma unroll
  for (int s = 0; s < 6; s++) x += partI[(size_t)s*TT*INNER_D + i];
  float u = 0.7978845608028654f * (x + 0.044715f * x * x * x);
  inner_c[i] = 0.5f * x * (1.0f + tanhf(u));
}

// ---------------------------------------------------------------------------
// K6: per (f,b): h_cls row, qbase row, compact Xq row.
__launch_bounds__(256)
__global__ void cls_gather_kernel(const float* __restrict__ hs, const float* __restrict__ hqkv,
                                  const __bf16* __restrict__ xbf, const float* __restrict__ bq,
                                  const float* __restrict__ w2, const float* __restrict__ inner_c,
                                  const int* __restrict__ gidx, const unsigned char* __restrict__ mask,
                                  const int* __restrict__ remap, const int* __restrict__ mremap,
                                  float* __restrict__ h_cls, float* __restrict__ qbase,
                                  float* __restrict__ Xq)
{
  int fb = blockIdx.x, t = threadIdx.x;
  int g0 = fb * NPOS;
  int idx = gidx[g0];
  int m = mask[g0];
  const float* q_cache = hqkv + (size_t)NC * DIM;
  __shared__ float inn[INNER_D];
  if (t < INNER_D) inn[t] = m ? inner_c[(size_t)mremap[g0]*INNER_D + t] : 0.f;
  __syncthreads();
  bool fresh = idx >= NC;
  int crow = fresh ? remap[idx - NC] : 0;
  for (int c = t; c < DIM; c += 256) {
    float xv = fresh ? (float)xbf[(size_t)crow*DIM + c] : 0.f;
    Xq[(size_t)fb*DIM + c] = xv;
    float hv = fresh ? hs[(size_t)(idx - NC)*DIM + c] : hqkv[(size_t)idx*DIM + c];
    float qb = fresh ? bq[c] : q_cache[(size_t)idx*DIM + c];
    if (m) {
      float hd = 0.f, qd = 0.f;
      #pragma unroll 8
      for (int j = 0; j < INNER_D; j++) {
        float iv = inn[j];
        hd += iv * w2[(size_t)j*FF + c];
        qd += iv * w2[(size_t)j*FF + DIM + c];
      }
      hv += hd; qb += qd;
    }
    h_cls[(size_t)fb*DIM + c] = hv;
    qbase[(size_t)fb*DIM + c] = qb;
  }
}

// ---------------------------------------------------------------------------
// K7: partial GEMM, M=64 fixed. grid (N/64, K/kChunk), 256 thr.
__launch_bounds__(256)
__global__ void pgemm_kernel(const float* __restrict__ X, const float* __restrict__ W,
                             float* __restrict__ part, int N, int K, int kChunk)
{
  int t = threadIdx.x;
  int c = t & 63;
  int rq = t >> 6;
  int col0 = blockIdx.x * 64;
  int k0base = blockIdx.y * kChunk;
  __shared__ __align__(16) float Xs[64][68];
  float acc[16];
  #pragma unroll
  for (int i = 0; i < 16; i++) acc[i] = 0.f;
  for (int k0 = k0base; k0 < k0base + kChunk; k0 += 64) {
    #pragma unroll
    for (int j = 0; j < 4; j++) {
      int v = t + 256*j;
      int rr = v >> 4, cc = (v & 15) << 2;
      *(float4*)&Xs[rr][cc] = *(const float4*)&X[(size_t)rr*K + k0 + cc];
    }
    __syncthreads();
    const float* Wp = W + (size_t)k0*N + col0 + c;
    #pragma unroll 4
    for (int kk = 0; kk < 64; kk += 4) {
      float w0 = Wp[(size_t)(kk+0)*N];
      float w1 = Wp[(size_t)(kk+1)*N];
      float w2 = Wp[(size_t)(kk+2)*N];
      float w3 = Wp[(size_t)(kk+3)*N];
      #pragma unroll
      for (int r = 0; r < 16; r++) {
        float4 xv = *(const float4*)&Xs[rq*16 + r][kk];
        acc[r] += xv.x*w0 + xv.y*w1 + xv.z*w2 + xv.w*w3;
      }
    }
    __syncthreads();
  }
  #pragma unroll
  for (int r = 0; r < 16; r++)
    part[((size_t)blockIdx.y*64 + rq*16 + r)*N + col0 + c] = acc[r];
}

// K7b: q0s = (qbase + sum_s partQ) * SCALE     (12 slabs)
__global__ void reduce_q_kernel(const float* __restrict__ qbase, const float* __restrict__ partQ,
                                float* __restrict__ q0s)
{
  int i = blockIdx.x * 256 + threadIdx.x;   // < 49152
  float v = qbase[i];
  #pragma unroll
  for (int s = 0; s < 12; s++) v += partQ[(size_t)s*FB_N*DIM + i];
  q0s[i] = v * 0.125f;
}

// ---------------------------------------------------------------------------
// K8: CLS-row attention, 512 threads (8 waves), quad-dot gathers.
__launch_bounds__(512)
__global__ void attn_cls_kernel(const float* __restrict__ hqkv, const __bf16* __restrict__ k_newc,
                                const __bf16* __restrict__ v_newc, const float* __restrict__ w2,
                                const float* __restrict__ inner_c, const int* __restrict__ gidx,
                                const unsigned char* __restrict__ mask, const int* __restrict__ remap,
                                const int* __restrict__ mremap,
                                const float* __restrict__ q0s, float* __restrict__ pre_cls)
{
  int bid = blockIdx.x;
  int fb = bid / NH, h = bid % NH;
  int t = threadIdx.x;
  int lane = t & 63, wv = t >> 6;        // 8 waves
  const float* k_cache = hqkv + (size_t)2 * NC * DIM;
  const float* v_cache = hqkv + (size_t)3 * NC * DIM;
  __shared__ float q0[HD], w2q[INNER_D], tj[INNER_D];
  __shared__ float p[200];
  __shared__ int sidx[200];
  __shared__ int smg[200];
  __shared__ float red[16];
  __shared__ float pacc[8][64];
  if (t < HD) q0[t] = q0s[(size_t)fb*DIM + h*HD + t];
  int tt = t - 64;
  if (tt >= 0 && tt < NPOS) {
    int g = fb * NPOS + tt;
    int idx = gidx[g];
    if (idx >= NC) idx = NC + remap[idx - NC];
    sidx[tt] = idx;
    smg[tt] = mask[g] ? mremap[g] : -1;
  }
  __syncthreads();
  {
    int j = t >> 3, dg = t & 7;
    const float* wr = w2 + (size_t)j*FF + 2*DIM + h*HD + dg*8;
    float4 a = *(const float4*)wr, b = *(const float4*)(wr + 4);
    const float* q = &q0[dg*8];
    float s = a.x*q[0] + a.y*q[1] + a.z*q[2] + a.w*q[3]
            + b.x*q[4] + b.y*q[5] + b.z*q[6] + b.w*q[7];
    s += __shfl_xor(s, 1); s += __shfl_xor(s, 2); s += __shfl_xor(s, 4);
    if (dg == 0) w2q[j] = s;
  }
  __syncthreads();
  #pragma unroll
  for (int it = 0; it < 4; it++) {
    int n = it*64 + wv*8 + (lane >> 3);
    int dg = lane & 7;
    if (n < NPOS) {
      int idx = sidx[n], mg = smg[n];
      const float* q = &q0[dg*8];
      float s = 0.f;
      if (idx >= NC) {
        bf16x8 kv = *(const bf16x8*)(k_newc + (size_t)(idx - NC)*DIM + h*HD + dg*8);
        #pragma unroll
        for (int j = 0; j < 8; j++) s += q[j] * (float)kv[j];
      } else {
        const float* kr = k_cache + (size_t)idx*DIM + h*HD + dg*8;
        float4 a = *(const float4*)kr, b = *(const float4*)(kr + 4);
        s = a.x*q[0] + a.y*q[1] + a.z*q[2] + a.w*q[3]
          + b.x*q[4] + b.y*q[5] + b.z*q[6] + b.w*q[7];
      }
      if (mg >= 0) {
        const float* ir = inner_c + (size_t)mg*INNER_D + dg*8;
        float4 a = *(const float4*)ir, b = *(const float4*)(ir + 4);
        const float* wq8 = &w2q[dg*8];
        s += a.x*wq8[0] + a.y*wq8[1] + a.z*wq8[2] + a.w*wq8[3]
           + b.x*wq8[4] + b.y*wq8[5] + b.z*wq8[6] + b.w*wq8[7];
      }
      s += __shfl_xor(s, 1); s += __shfl_xor(s, 2); s += __shfl_xor(s, 4);
      if (dg == 0) p[n] = s;
    }
  }
  __syncthreads();
  float lm = (t < NPOS) ? p[t] : -1e30f;
  lm = wred_max(lm);
  if (lane == 0) red[wv] = lm;
  __syncthreads();
  float mx = red[0];
  #pragma unroll
  for (int w = 1; w < 8; w++) mx = fmaxf(mx, red[w]);
  float lp = 0.f;
  if (t < NPOS) { lp = __expf(p[t] - mx); p[t] = lp; }
  float ls = wred_sum(lp);
  if (lane == 0) red[8 + wv] = ls;
  __syncthreads();
  float inv = red[8];
  #pragma unroll
  for (int w = 1; w < 8; w++) inv += red[8 + w];
  inv = 1.0f / inv;
  float tp = 0.f;
  for (int n = wv; n < NPOS; n += 8) {
    int mg = smg[n];
    if (mg >= 0) tp += p[n] * inner_c[(size_t)mg*INNER_D + lane];
  }
  pacc[wv][lane] = tp;
  __syncthreads();
  if (t < INNER_D) tj[t] = pacc[0][t] + pacc[1][t] + pacc[2][t] + pacc[3][t]
                         + pacc[4][t] + pacc[5][t] + pacc[6][t] + pacc[7][t];
  __syncthreads();
  float va = 0.f;
  for (int n = wv; n < NPOS; n += 8) {
    float pn = p[n];
    int idx = sidx[n];
    float vvv;
    if (idx >= NC) vvv = (float)v_newc[(size_t)(idx - NC)*DIM + h*HD + lane];
    else           vvv = v_cache[(size_t)idx*DIM + h*HD + lane];
    va += pn * vvv;
  }
  __syncthreads();
  pacc[wv][lane] = va;
  __syncthreads();
  if (t < HD) {
    float o = pacc[0][t] + pacc[1][t] + pacc[2][t] + pacc[3][t]
            + pacc[4][t] + pacc[5][t] + pacc[6][t] + pacc[7][t];
    const float* wv2 = w2 + 3*DIM + h*HD + t;
    float dd = 0.f;
    for (int j = 0; j < INNER_D; j++) dd += tj[j] * wv2[(size_t)j*FF];
    pre_cls[(size_t)fb*DIM + h*HD + t] = (o + dd) * inv;
  }
}

// ---------------------------------------------------------------------------
// K9: out0 = h_cls + (sum_s partW) + bo;  yln = LN2(out0).  (12 slabs)
__launch_bounds__(256)
__global__ void reduce_wo_ln_kernel(const float* __restrict__ partW, const float* __restrict__ bo,
                                    const float* __restrict__ h_cls, const float* __restrict__ g,
                                    const float* __restrict__ b, float* __restrict__ out0,
                                    float* __restrict__ yln)
{
  int row = blockIdx.x, t = threadIdx.x;
  float v[3];
  #pragma unroll
  for (int j = 0; j < 3; j++) {
    int c = t + j*256;
    float s = h_cls[(size_t)row*DIM + c] + bo[c];
    #pragma unroll
    for (int ks = 0; ks < 12; ks++) s += partW[((size_t)ks*FB_N + row)*DIM + c];
    v[j] = s;
    out0[(size_t)row*DIM + c] = s;
  }
  float sm = wred_sum(v[0] + v[1] + v[2]);
  float sq = wred_sum(v[0]*v[0] + v[1]*v[1] + v[2]*v[2]);
  __shared__ float red[8];
  int wv = t >> 6, ln = t & 63;
  if (ln == 0) { red[wv] = sm; red[4 + wv] = sq; }
  __syncthreads();
  float mean = (red[0]+red[1]+red[2]+red[3]) * (1.f/DIM);
  float var  = (red[4]+red[5]+red[6]+red[7]) * (1.f/DIM) - mean*mean;
  float rr = rsqrtf(var + 1e-5f);
  #pragma unroll
  for (int j = 0; j < 3; j++) {
    int c = t + j*256;
    yln[(size_t)row*DIM + c] = (v[j] - mean) * rr * g[c] + b[c];
  }
}

// K10: t1 = quick_gelu(sum_s partF1 + fc1b)    (6 slabs)
__global__ void reduce_gelu_kernel(const float* __restrict__ partF1, const float* __restrict__ b1,
                                   float* __restrict__ t1)
{
  int i = blockIdx.x * 256 + threadIdx.x;   // < 196608
  int c = i % FF;
  float v = b1[c];
  #pragma unroll
  for (int s = 0; s < 6; s++) v += partF1[(size_t)s*FB_N*FF + i];
  t1[i] = v / (1.0f + __expf(-1.702f * v));
}

// K11: d_out = out0 + fc2_b + sum_s partF2     (24 slabs)
__global__ void final_reduce_kernel(const float* __restrict__ out0, const float* __restrict__ b2,
                                    const float* __restrict__ partF2, float* __restrict__ dout)
{
  int i = blockIdx.x * 256 + threadIdx.x;   // < 49152
  int c = i % DIM;
  float v = out0[i] + b2[c];
  #pragma unroll
  for (int s = 0; s < 24; s++) v += partF2[(size_t)s*FB_N*DIM + i];
  dout[i] = v;
}

// ---------------------------------------------------------------------------
extern "C" void kernel_launch(void* const* d_in, const int* in_sizes, int n_in,
                              void* d_out, int out_size, void* d_ws, size_t ws_size,
                              hipStream_t stream)
{
  const float* hs   = (const float*)d_in[0];
  const float* dpp  = (const float*)d_in[1];
  const float* hqkv = (const float*)d_in[2];
  const float* ln1g = (const float*)d_in[3];
  const float* ln1b = (const float*)d_in[4];
  const float* wq   = (const float*)d_in[5];
  const float* bq   = (const float*)d_in[6];
  const float* wk   = (const float*)d_in[7];
  const float* bk   = (const float*)d_in[8];
  const float* wvw  = (const float*)d_in[9];
  const float* bv   = (const float*)d_in[10];
  const float* w1   = (const float*)d_in[11];
  const float* w2   = (const float*)d_in[12];
  const float* wo   = (const float*)d_in[13];
  const float* bo   = (const float*)d_in[14];
  const float* ln2g = (const float*)d_in[15];
  const float* ln2b = (const float*)d_in[16];
  const float* fc1w = (const float*)d_in[17];
  const float* fc1b = (const float*)d_in[18];
  const float* fc2w = (const float*)d_in[19];
  const float* fc2b = (const float*)d_in[20];
  const int*   gidx = (const int*)d_in[21];
  const unsigned char* rmap = (const unsigned char*)d_in[22];
  float* outp = (float*)d_out;

  char* ws = (char*)d_ws;
  size_t off = 0;
  auto alloc = [&](size_t bytes) { void* p = ws + off; off += (bytes + 255) & ~(size_t)255; return p; };
  unsigned char* mask = (unsigned char*)alloc(TT);
  int* flag     = (int*)alloc((size_t)TT * 4);
  int* rowlist  = (int*)alloc((size_t)TT * 4);
  int* remap    = (int*)alloc((size_t)TT * 4);
  int* mrowlist = (int*)alloc((size_t)TT * 4);
  int* mremap   = (int*)alloc((size_t)TT * 4);
  int* mc       = (int*)alloc(256);
  __bf16* xbf    = (__bf16*)alloc((size_t)TT * DIM * 2);
  __bf16* wcatT  = (__bf16*)alloc((size_t)NCOLS * DIM * 2);
  __bf16* w1T    = (__bf16*)alloc((size_t)INNER_D * DIM * 2);
  __bf16* k_newc = (__bf16*)alloc((size_t)TT * DIM * 2);
  __bf16* v_newc = (__bf16*)alloc((size_t)TT * DIM * 2);
  float* partI   = (float*)alloc((size_t)6 * TT * INNER_D * 4);
  float* inner_c = (float*)alloc((size_t)TT * INNER_D * 4);
  float* h_cls  = (float*)alloc((size_t)FB_N * DIM * 4);
  float* qbase  = (float*)alloc((size_t)FB_N * DIM * 4);
  float* Xq     = (float*)alloc((size_t)FB_N * DIM * 4);
  float* q0s    = (float*)alloc((size_t)FB_N * DIM * 4);
  float* precls = (float*)alloc((size_t)FB_N * DIM * 4);
  float* out0   = (float*)alloc((size_t)FB_N * DIM * 4);
  float* yln    = (float*)alloc((size_t)FB_N * DIM * 4);
  float* t1     = (float*)alloc((size_t)FB_N * FF * 4);
  float* partQ  = (float*)alloc((size_t)12 * FB_N * DIM * 4);
  float* partW  = (float*)alloc((size_t)12 * FB_N * DIM * 4);
  float* partF1 = (float*)alloc((size_t)6  * FB_N * FF  * 4);
  float* partF2 = (float*)alloc((size_t)24 * FB_N * DIM * 4);
  (void)ws_size; (void)in_sizes; (void)n_in; (void)out_size;

  mask_norm_kernel<<<1, 256, 0, stream>>>(rmap, mask);
  hipMemsetAsync(flag, 0, (size_t)TT * 4, stream);
  flag_kernel<<<(TT + 255) / 256, 256, 0, stream>>>(gidx, flag);
  scan_kernel<<<1, 1024, 0, stream>>>(flag, mask, rowlist, remap, mrowlist, mremap, mc);
  ln_kernel<<<TT, 256, 0, stream>>>(hs, ln1g, ln1b, xbf, rowlist, mc);
  transpose_w_kernel<<<dim3(24, 24, 2), dim3(32, 8), 0, stream>>>(wk, wvw, wcatT);
  transpose_w1_kernel<<<dim3(24, 2), dim3(32, 8), 0, stream>>>(w1, w1T);
  kv_gemm_kernel<<<1248, 256, 0, stream>>>(xbf, wcatT, bk, bv, k_newc, v_newc, mc);
  inner_gemm_kernel<<<dim3((TT + 63) / 64, 6), 256, 0, stream>>>(dpp, w1T, mrowlist, mc, partI);
  reduce_inner_kernel<<<(TT * INNER_D + 255) / 256, 256, 0, stream>>>(partI, mc, inner_c);
  cls_gather_kernel<<<FB_N, 256, 0, stream>>>(hs, hqkv, xbf, bq, w2, inner_c, gidx, mask,
                                              remap, mremap, h_cls, qbase, Xq);
  // q0s = (qbase + Xq @ wq) * SCALE   (zero Xq rows for cached fb's)
  pgemm_kernel<<<dim3(12, 12), 256, 0, stream>>>(Xq, wq, partQ, DIM, DIM, 64);
  reduce_q_kernel<<<192, 256, 0, stream>>>(qbase, partQ, q0s);
  attn_cls_kernel<<<FB_N * NH, 512, 0, stream>>>(hqkv, k_newc, v_newc, w2, inner_c, gidx, mask,
                                                 remap, mremap, q0s, precls);
  // out0 = h_cls + precls@wo + bo ; yln = LN2(out0)
  pgemm_kernel<<<dim3(12, 12), 256, 0, stream>>>(precls, wo, partW, DIM, DIM, 64);
  reduce_wo_ln_kernel<<<FB_N, 256, 0, stream>>>(partW, bo, h_cls, ln2g, ln2b, out0, yln);
  // t1 = qgelu(yln@fc1w + fc1b)
  pgemm_kernel<<<dim3(48, 6), 256, 0, stream>>>(yln, fc1w, partF1, FF, DIM, 128);
  reduce_gelu_kernel<<<768, 256, 0, stream>>>(partF1, fc1b, t1);
  // d_out = out0 + t1@fc2w + fc2b
  pgemm_kernel<<<dim3(12, 24), 256, 0, stream>>>(t1, fc2w, partF2, DIM, FF, 128);
  final_reduce_kernel<<<192, 256, 0, stream>>>(out0, fc2b, partF2, outp);
}

// Round 9
// 207.733 us; speedup vs baseline: 4.0855x; 1.1162x over previous
//
#include <hip/hip_runtime.h>
#include <hip/hip_bf16.h>

// Problem constants
#define TT 12608          // 4*B*N rows of hs
#define NC 3152           // B*N cache rows (= 16*197)
#define DIM 768
#define NPOS 197
#define NH 12
#define HD 64
#define FB_N 64           // 4*B
#define FF 3072
#define INNER_D 64
#define NCOLS 1536        // K cols + V cols combined

typedef __bf16 bf16x8 __attribute__((ext_vector_type(8)));
typedef float f32x4 __attribute__((ext_vector_type(4)));

__device__ inline float wred_sum(float v){
  #pragma unroll
  for (int o = 32; o > 0; o >>= 1) v += __shfl_down(v, o, 64);
  return v;
}
__device__ inline float wred_max(float v){
  #pragma unroll
  for (int o = 32; o > 0; o >>= 1) v = fmaxf(v, __shfl_down(v, o, 64));
  return v;
}

// async global->LDS, 16B per lane; LDS dest = wave-uniform base + lane*16
__device__ __forceinline__ void gl_lds16(const __bf16* g, __bf16* l) {
  __builtin_amdgcn_global_load_lds(
      (const __attribute__((address_space(1))) void*)g,
      (__attribute__((address_space(3))) void*)l, 16, 0, 0);
}

// ---------------------------------------------------------------------------
// K1: fused (a) fresh-row flagging from gidx, (b) reuse_map dtype detection.
// det[0]: any nonzero byte at offset %4 != 0; det[1]: any nonzero at %4 == 0.
// mode = (!det0) ? int32 : (det1 ? byte : f32)   [same logic as before]
__global__ void detect_flag_kernel(const int* __restrict__ gidx, const unsigned char* __restrict__ rm,
                                   int* __restrict__ flag, int* __restrict__ det)
{
  int g = blockIdx.x * 256 + threadIdx.x;
  int la = 0, lb = 0;
  if (g < TT) {
    int idx = gidx[g];
    if (idx >= NC) flag[idx - NC] = 1;
    unsigned char v = rm[g];
    if (v) { if (g & 3) la = 1; else lb = 1; }
  }
  unsigned long long ba = __ballot(la != 0), bb = __ballot(lb != 0);
  if ((threadIdx.x & 63) == 0) {
    if (ba) atomicOr(&det[0], 1);
    if (bb) atomicOr(&det[1], 1);
  }
}

// K1c: single-block dual exclusive scan; normalizes reuse_map inline (mode from det)
// and writes mask[] bytes for downstream consumers.
//   A: fresh-row compaction (flag)  -> rowlist / remap / mc[0]
//   B: masked-row compaction        -> mrowlist / mremap / mc[1]
__launch_bounds__(1024)
__global__ void scan_kernel(const int* __restrict__ flag, const unsigned char* __restrict__ rm,
                            const int* __restrict__ det, unsigned char* __restrict__ mask,
                            int* __restrict__ rowlist, int* __restrict__ remap,
                            int* __restrict__ mrowlist, int* __restrict__ mremap,
                            int* __restrict__ mc)
{
  __shared__ int wsumA[16], wsumB[16];
  __shared__ int baseA, baseB;
  int t = threadIdx.x, lane = t & 63, wv = t >> 6;
  int mode = (!det[0]) ? 0 : (det[1] ? 1 : 2); // 0=int32, 1=byte, 2=f32
  if (t == 0) { baseA = 0; baseB = 0; }
  __syncthreads();
  for (int start = 0; start < TT; start += 1024) {
    int i = start + t;
    int fA = 0, fB = 0;
    if (i < TT) {
      fA = flag[i];
      unsigned char mb_;
      if (mode == 0)      mb_ = ((const int*)rm)[i] != 0;
      else if (mode == 1) mb_ = rm[i] != 0;
      else                mb_ = ((const float*)rm)[i] != 0.0f;
      mask[i] = mb_;
      fB = mb_;
    }
    unsigned long long mbA = __ballot(fA != 0);
    unsigned long long mbB = __ballot(fB != 0);
    int rankA = __popcll(mbA & ((1ULL << lane) - 1ULL));
    int rankB = __popcll(mbB & ((1ULL << lane) - 1ULL));
    if (lane == 0) { wsumA[wv] = __popcll(mbA); wsumB[wv] = __popcll(mbB); }
    __syncthreads();
    int woffA = 0, woffB = 0;
    for (int w2 = 0; w2 < wv; w2++) { woffA += wsumA[w2]; woffB += wsumB[w2]; }
    if (fA) { int pos = baseA + woffA + rankA; rowlist[pos] = i; remap[i] = pos; }
    if (fB) { int pos = baseB + woffB + rankB; mrowlist[pos] = i; mremap[i] = pos; }
    __syncthreads();
    if (t == 0) {
      int ta = 0, tb = 0;
      for (int w2 = 0; w2 < 16; w2++) { ta += wsumA[w2]; tb += wsumB[w2]; }
      baseA += ta; baseB += tb;
    }
    __syncthreads();
  }
  if (t == 0) { mc[0] = baseA; mc[1] = baseB; }
}

// ---------------------------------------------------------------------------
// K2: row LayerNorm over 768 cols -> bf16, COMPACT rows only.
__launch_bounds__(256)
__global__ void ln_kernel(const float* __restrict__ in, const float* __restrict__ g,
                          const float* __restrict__ b, __bf16* __restrict__ outp,
                          const int* __restrict__ rowlist, const int* __restrict__ mc)
{
  if ((int)blockIdx.x >= mc[0]) return;
  int row = rowlist[blockIdx.x];
  int t = threadIdx.x;
  const float* x = in + (size_t)row * DIM;
  float v0 = x[t], v1 = x[t + 256], v2 = x[t + 512];
  float s = wred_sum(v0 + v1 + v2);
  float q = wred_sum(v0*v0 + v1*v1 + v2*v2);
  __shared__ float red[8];
  int wv = t >> 6, ln = t & 63;
  if (ln == 0) { red[wv] = s; red[4 + wv] = q; }
  __syncthreads();
  float mean = (red[0]+red[1]+red[2]+red[3]) * (1.f/DIM);
  float var  = (red[4]+red[5]+red[6]+red[7]) * (1.f/DIM) - mean*mean;
  float rr = rsqrtf(var + 1e-5f);
  #pragma unroll
  for (int j = 0; j < 3; j++) {
    int c = t + j*256;
    float v = (j==0) ? v0 : (j==1) ? v1 : v2;
    outp[(size_t)blockIdx.x*DIM + c] = (__bf16)((v - mean) * rr * g[c] + b[c]);
  }
}

// ---------------------------------------------------------------------------
// K3: transpose wk/wv (768x768 f32) -> combined bf16 B^T buffer wcatT[1536][768].
__global__ void transpose_w_kernel(const float* __restrict__ wk, const float* __restrict__ wv,
                                   __bf16* __restrict__ wcatT)
{
  const float* src = blockIdx.z ? wv : wk;
  __bf16* dst = wcatT + (blockIdx.z ? (size_t)768 * DIM : 0);
  __shared__ float tile[32][33];
  int bx = blockIdx.x, by = blockIdx.y;
  int tx = threadIdx.x, ty = threadIdx.y;
  #pragma unroll
  for (int i = 0; i < 32; i += 8)
    tile[ty + i][tx] = src[(size_t)(by*32 + ty + i) * DIM + bx*32 + tx];
  __syncthreads();
  #pragma unroll
  for (int i = 0; i < 32; i += 8)
    dst[(size_t)(bx*32 + ty + i) * DIM + by*32 + tx] = (__bf16)tile[tx][ty + i];
}

// K3b: transpose w1 (768x64 f32) -> bf16 w1T[64][768].
__global__ void transpose_w1_kernel(const float* __restrict__ w1, __bf16* __restrict__ w1T)
{
  __shared__ float tile[32][33];
  int bx = blockIdx.x, by = blockIdx.y;   // bx: k-tile (24), by: n-tile (2)
  int tx = threadIdx.x, ty = threadIdx.y;
  #pragma unroll
  for (int i = 0; i < 32; i += 8)
    tile[ty + i][tx] = w1[(size_t)(bx*32 + ty + i) * INNER_D + by*32 + tx];
  __syncthreads();
  #pragma unroll
  for (int i = 0; i < 32; i += 8)
    w1T[(size_t)(by*32 + ty + i) * DIM + bx*32 + tx] = (__bf16)tile[tx][ty + i];
}

// ---------------------------------------------------------------------------
// K4: [k_newc | v_newc] = xbf(compact) @ wcatT^T (+bias), m97 structure.
__launch_bounds__(256)
__global__ void kv_gemm_kernel(const __bf16* __restrict__ xbf, const __bf16* __restrict__ wcatT,
                               const float* __restrict__ bk, const float* __restrict__ bv,
                               __bf16* __restrict__ k_newc, __bf16* __restrict__ v_newc,
                               const int* __restrict__ mc)
{
  int Mc = mc[0];
  int npanels = (Mc + 127) >> 7;
  int bid = blockIdx.x;                 // 8 * 13 * 12 = 1248
  int xcd = bid & 7, s = bid >> 3;
  int panel = (s / 12) * 8 + xcd;
  if (panel >= npanels) return;
  int col0 = (s % 12) * 128;
  int row0 = panel * 128;

  __shared__ __align__(16) __bf16 As[128][32];
  __shared__ __align__(16) __bf16 Bs[128][32];
  int t = threadIdx.x;
  int lane = t & 63, wid = t >> 6;
  int wr = wid >> 1, wc = wid & 1;
  int fr = lane & 15, fg = lane >> 4;

  int lr = t >> 2, lc = (t & 3) << 3;
  int ar0 = min(row0 + lr, Mc - 1);
  int ar1 = min(row0 + 64 + lr, Mc - 1);
  const __bf16* aG0 = xbf + (size_t)ar0 * DIM + lc;
  const __bf16* aG1 = xbf + (size_t)ar1 * DIM + lc;
  const __bf16* bG0 = wcatT + (size_t)(col0 + lr) * DIM + lc;
  const __bf16* bG1 = wcatT + (size_t)(col0 + 64 + lr) * DIM + lc;
  __bf16* lA0 = &As[lr][lc];
  __bf16* lA1 = &As[64 + lr][lc];
  __bf16* lB0 = &Bs[lr][lc];
  __bf16* lB1 = &Bs[64 + lr][lc];

  f32x4 acc[4][4];
  #pragma unroll
  for (int m = 0; m < 4; m++)
    #pragma unroll
    for (int n = 0; n < 4; n++) acc[m][n] = (f32x4){0.f, 0.f, 0.f, 0.f};

  for (int k0 = 0; k0 < DIM; k0 += 32) {
    gl_lds16(aG0 + k0, lA0);
    gl_lds16(aG1 + k0, lA1);
    gl_lds16(bG0 + k0, lB0);
    gl_lds16(bG1 + k0, lB1);
    __syncthreads();
    bf16x8 af[4], bb[4];
    #pragma unroll
    for (int m = 0; m < 4; m++) af[m] = *(const bf16x8*)&As[wr*64 + m*16 + fr][fg << 3];
    #pragma unroll
    for (int n = 0; n < 4; n++) bb[n] = *(const bf16x8*)&Bs[wc*64 + n*16 + fr][fg << 3];
    #pragma unroll
    for (int m = 0; m < 4; m++)
      #pragma unroll
      for (int n = 0; n < 4; n++)
        acc[m][n] = __builtin_amdgcn_mfma_f32_16x16x32_bf16(af[m], bb[n], acc[m][n], 0, 0, 0);
    __syncthreads();
  }

  bool isK = (col0 < 768);
  const float* bias = isK ? bk : bv;
  __bf16* dst = isK ? k_newc : v_newc;
  int cbase = isK ? col0 : col0 - 768;
  #pragma unroll
  for (int n = 0; n < 4; n++) {
    int dcol = cbase + wc*64 + n*16 + fr;
    float bc = bias[dcol];
    #pragma unroll
    for (int m = 0; m < 4; m++) {
      int orow = row0 + wr*64 + m*16 + fg*4;
      #pragma unroll
      for (int r = 0; r < 4; r++) {
        int rr = orow + r;
        if (rr < Mc) dst[(size_t)rr * DIM + dcol] = (__bf16)(acc[m][n][r] + bc);
      }
    }
  }
}

// ---------------------------------------------------------------------------
// K5: MFMA partial inner GEMM over MASKED rows.
__launch_bounds__(256)
__global__ void inner_gemm_kernel(const float* __restrict__ dpp, const __bf16* __restrict__ w1T,
                                  const int* __restrict__ mrowlist, const int* __restrict__ mc,
                                  float* __restrict__ partI)
{
  int mcnt = mc[1];
  int row0 = blockIdx.x * 64;
  if (row0 >= mcnt) return;
  int k0base = blockIdx.y * 128;
  int t = threadIdx.x;
  int lane = t & 63, wid = t >> 6;
  int wr = wid >> 1, wc = wid & 1;        // 2x2 wave grid
  int fr = lane & 15, fg = lane >> 4;

  __shared__ __align__(16) __bf16 As[64][40];
  __shared__ __align__(16) __bf16 Bs[64][40];
  __shared__ int rlist[64];
  if (t < 64) rlist[t] = mrowlist[min(row0 + t, mcnt - 1)];
  __syncthreads();

  int lr = t >> 2, lc = (t & 3) << 3;
  const float* aG = dpp + (size_t)rlist[lr] * DIM + lc;
  const __bf16* bG = w1T + (size_t)lr * DIM + lc;

  f32x4 acc[2][2];
  #pragma unroll
  for (int m = 0; m < 2; m++)
    #pragma unroll
    for (int n = 0; n < 2; n++) acc[m][n] = (f32x4){0.f, 0.f, 0.f, 0.f};

  for (int k0 = k0base; k0 < k0base + 128; k0 += 32) {
    float4 a0 = *(const float4*)(aG + k0);
    float4 a1 = *(const float4*)(aG + k0 + 4);
    bf16x8 av;
    av[0] = (__bf16)a0.x; av[1] = (__bf16)a0.y; av[2] = (__bf16)a0.z; av[3] = (__bf16)a0.w;
    av[4] = (__bf16)a1.x; av[5] = (__bf16)a1.y; av[6] = (__bf16)a1.z; av[7] = (__bf16)a1.w;
    *(bf16x8*)&As[lr][lc] = av;
    *(bf16x8*)&Bs[lr][lc] = *(const bf16x8*)(bG + k0);
    __syncthreads();
    bf16x8 af[2], bb[2];
    #pragma unroll
    for (int m = 0; m < 2; m++) af[m] = *(const bf16x8*)&As[wr*32 + m*16 + fr][fg << 3];
    #pragma unroll
    for (int n = 0; n < 2; n++) bb[n] = *(const bf16x8*)&Bs[wc*32 + n*16 + fr][fg << 3];
    #pragma unroll
    for (int m = 0; m < 2; m++)
      #pragma unroll
      for (int n = 0; n < 2; n++)
        acc[m][n] = __builtin_amdgcn_mfma_f32_16x16x32_bf16(af[m], bb[n], acc[m][n], 0, 0, 0);
    __syncthreads();
  }

  #pragma unroll
  for (int m = 0; m < 2; m++) {
    #pragma unroll
    for (int n = 0; n < 2; n++) {
      int col = wc*32 + n*16 + fr;
      int orow = row0 + wr*32 + m*16 + fg*4;
      #pragma unroll
      for (int r = 0; r < 4; r++) {
        int rr = orow + r;
        if (rr < mcnt)
          partI[((size_t)blockIdx.y*TT + rr)*INNER_D + col] = acc[m][n][r];
      }
    }
  }
}

// K5b: inner_c = gelu_tanh(sum_ks partI)     (6 slabs)
__global__ void reduce_inner_kernel(const float* __restrict__ partI, const int* __restrict__ mc,
                                    float* __restrict__ inner_c)
{
  int i = blockIdx.x * 256 + threadIdx.x;
  if (i >= mc[1] * INNER_D) return;
  float x = 0.f;
  #pragma unroll
  for (int s = 0; s < 6; s++) x += partI[(size_t)s*TT*INNER_D + i];
  float u = 0.7978845608028654f * (x + 0.044715f * x * x * x);
  inner_c[i] = 0.5f * x * (1.0f + tanhf(u));
}

// ---------------------------------------------------------------------------
// K6: per (f,b): h_cls row, qbase row, compact Xq row.
__launch_bounds__(256)
__global__ void cls_gather_kernel(const float* __restrict__ hs, const float* __restrict__ hqkv,
                                  const __bf16* __restrict__ xbf, const float* __restrict__ bq,
                                  const float* __restrict__ w2, const float* __restrict__ inner_c,
                                  const int* __restrict__ gidx, const unsigned char* __restrict__ mask,
                                  const int* __restrict__ remap, const int* __restrict__ mremap,
                                  float* __restrict__ h_cls, float* __restrict__ qbase,
                                  float* __restrict__ Xq)
{
  int fb = blockIdx.x, t = threadIdx.x;
  int g0 = fb * NPOS;
  int idx = gidx[g0];
  int m = mask[g0];
  const float* q_cache = hqkv + (size_t)NC * DIM;
  __shared__ float inn[INNER_D];
  if (t < INNER_D) inn[t] = m ? inner_c[(size_t)mremap[g0]*INNER_D + t] : 0.f;
  __syncthreads();
  bool fresh = idx >= NC;
  int crow = fresh ? remap[idx - NC] : 0;
  for (int c = t; c < DIM; c += 256) {
    float xv = fresh ? (float)xbf[(size_t)crow*DIM + c] : 0.f;
    Xq[(size_t)fb*DIM + c] = xv;
    float hv = fresh ? hs[(size_t)(idx - NC)*DIM + c] : hqkv[(size_t)idx*DIM + c];
    float qb = fresh ? bq[c] : q_cache[(size_t)idx*DIM + c];
    if (m) {
      float hd = 0.f, qd = 0.f;
      #pragma unroll 8
      for (int j = 0; j < INNER_D; j++) {
        float iv = inn[j];
        hd += iv * w2[(size_t)j*FF + c];
        qd += iv * w2[(size_t)j*FF + DIM + c];
      }
      hv += hd; qb += qd;
    }
    h_cls[(size_t)fb*DIM + c] = hv;
    qbase[(size_t)fb*DIM + c] = qb;
  }
}

// ---------------------------------------------------------------------------
// K7: partial GEMM, M=64 fixed. grid (N/64, K/kChunk), 256 thr.
__launch_bounds__(256)
__global__ void pgemm_kernel(const float* __restrict__ X, const float* __restrict__ W,
                             float* __restrict__ part, int N, int K, int kChunk)
{
  int t = threadIdx.x;
  int c = t & 63;
  int rq = t >> 6;
  int col0 = blockIdx.x * 64;
  int k0base = blockIdx.y * kChunk;
  __shared__ __align__(16) float Xs[64][68];
  float acc[16];
  #pragma unroll
  for (int i = 0; i < 16; i++) acc[i] = 0.f;
  for (int k0 = k0base; k0 < k0base + kChunk; k0 += 64) {
    #pragma unroll
    for (int j = 0; j < 4; j++) {
      int v = t + 256*j;
      int rr = v >> 4, cc = (v & 15) << 2;
      *(float4*)&Xs[rr][cc] = *(const float4*)&X[(size_t)rr*K + k0 + cc];
    }
    __syncthreads();
    const float* Wp = W + (size_t)k0*N + col0 + c;
    #pragma unroll 4
    for (int kk = 0; kk < 64; kk += 4) {
      float w0 = Wp[(size_t)(kk+0)*N];
      float w1 = Wp[(size_t)(kk+1)*N];
      float w2 = Wp[(size_t)(kk+2)*N];
      float w3 = Wp[(size_t)(kk+3)*N];
      #pragma unroll
      for (int r = 0; r < 16; r++) {
        float4 xv = *(const float4*)&Xs[rq*16 + r][kk];
        acc[r] += xv.x*w0 + xv.y*w1 + xv.z*w2 + xv.w*w3;
      }
    }
    __syncthreads();
  }
  #pragma unroll
  for (int r = 0; r < 16; r++)
    part[((size_t)blockIdx.y*64 + rq*16 + r)*N + col0 + c] = acc[r];
}

// K7b: q0s = (qbase + sum_s partQ) * SCALE     (12 slabs)
__global__ void reduce_q_kernel(const float* __restrict__ qbase, const float* __restrict__ partQ,
                                float* __restrict__ q0s)
{
  int i = blockIdx.x * 256 + threadIdx.x;   // < 49152
  float v = qbase[i];
  #pragma unroll
  for (int s = 0; s < 12; s++) v += partQ[(size_t)s*FB_N*DIM + i];
  q0s[i] = v * 0.125f;
}

// ---------------------------------------------------------------------------
// K8: CLS-row attention, 512 threads (8 waves), quad-dot gathers.
__launch_bounds__(512)
__global__ void attn_cls_kernel(const float* __restrict__ hqkv, const __bf16* __restrict__ k_newc,
                                const __bf16* __restrict__ v_newc, const float* __restrict__ w2,
                                const float* __restrict__ inner_c, const int* __restrict__ gidx,
                                const unsigned char* __restrict__ mask, const int* __restrict__ remap,
                                const int* __restrict__ mremap,
                                const float* __restrict__ q0s, float* __restrict__ pre_cls)
{
  int bid = blockIdx.x;
  int fb = bid / NH, h = bid % NH;
  int t = threadIdx.x;
  int lane = t & 63, wv = t >> 6;        // 8 waves
  const float* k_cache = hqkv + (size_t)2 * NC * DIM;
  const float* v_cache = hqkv + (size_t)3 * NC * DIM;
  __shared__ float q0[HD], w2q[INNER_D], tj[INNER_D];
  __shared__ float p[200];
  __shared__ int sidx[200];
  __shared__ int smg[200];
  __shared__ float red[16];
  __shared__ float pacc[8][64];
  if (t < HD) q0[t] = q0s[(size_t)fb*DIM + h*HD + t];
  int tt = t - 64;
  if (tt >= 0 && tt < NPOS) {
    int g = fb * NPOS + tt;
    int idx = gidx[g];
    if (idx >= NC) idx = NC + remap[idx - NC];
    sidx[tt] = idx;
    smg[tt] = mask[g] ? mremap[g] : -1;
  }
  __syncthreads();
  {
    int j = t >> 3, dg = t & 7;
    const float* wr = w2 + (size_t)j*FF + 2*DIM + h*HD + dg*8;
    float4 a = *(const float4*)wr, b = *(const float4*)(wr + 4);
    const float* q = &q0[dg*8];
    float s = a.x*q[0] + a.y*q[1] + a.z*q[2] + a.w*q[3]
            + b.x*q[4] + b.y*q[5] + b.z*q[6] + b.w*q[7];
    s += __shfl_xor(s, 1); s += __shfl_xor(s, 2); s += __shfl_xor(s, 4);
    if (dg == 0) w2q[j] = s;
  }
  __syncthreads();
  #pragma unroll
  for (int it = 0; it < 4; it++) {
    int n = it*64 + wv*8 + (lane >> 3);
    int dg = lane & 7;
    if (n < NPOS) {
      int idx = sidx[n], mg = smg[n];
      const float* q = &q0[dg*8];
      float s = 0.f;
      if (idx >= NC) {
        bf16x8 kv = *(const bf16x8*)(k_newc + (size_t)(idx - NC)*DIM + h*HD + dg*8);
        #pragma unroll
        for (int j = 0; j < 8; j++) s += q[j] * (float)kv[j];
      } else {
        const float* kr = k_cache + (size_t)idx*DIM + h*HD + dg*8;
        float4 a = *(const float4*)kr, b = *(const float4*)(kr + 4);
        s = a.x*q[0] + a.y*q[1] + a.z*q[2] + a.w*q[3]
          + b.x*q[4] + b.y*q[5] + b.z*q[6] + b.w*q[7];
      }
      if (mg >= 0) {
        const float* ir = inner_c + (size_t)mg*INNER_D + dg*8;
        float4 a = *(const float4*)ir, b = *(const float4*)(ir + 4);
        const float* wq8 = &w2q[dg*8];
        s += a.x*wq8[0] + a.y*wq8[1] + a.z*wq8[2] + a.w*wq8[3]
           + b.x*wq8[4] + b.y*wq8[5] + b.z*wq8[6] + b.w*wq8[7];
      }
      s += __shfl_xor(s, 1); s += __shfl_xor(s, 2); s += __shfl_xor(s, 4);
      if (dg == 0) p[n] = s;
    }
  }
  __syncthreads();
  float lm = (t < NPOS) ? p[t] : -1e30f;
  lm = wred_max(lm);
  if (lane == 0) red[wv] = lm;
  __syncthreads();
  float mx = red[0];
  #pragma unroll
  for (int w = 1; w < 8; w++) mx = fmaxf(mx, red[w]);
  float lp = 0.f;
  if (t < NPOS) { lp = __expf(p[t] - mx); p[t] = lp; }
  float ls = wred_sum(lp);
  if (lane == 0) red[8 + wv] = ls;
  __syncthreads();
  float inv = red[8];
  #pragma unroll
  for (int w = 1; w < 8; w++) inv += red[8 + w];
  inv = 1.0f / inv;
  float tp = 0.f;
  for (int n = wv; n < NPOS; n += 8) {
    int mg = smg[n];
    if (mg >= 0) tp += p[n] * inner_c[(size_t)mg*INNER_D + lane];
  }
  pacc[wv][lane] = tp;
  __syncthreads();
  if (t < INNER_D) tj[t] = pacc[0][t] + pacc[1][t] + pacc[2][t] + pacc[3][t]
                         + pacc[4][t] + pacc[5][t] + pacc[6][t] + pacc[7][t];
  __syncthreads();
  float va = 0.f;
  for (int n = wv; n < NPOS; n += 8) {
    float pn = p[n];
    int idx = sidx[n];
    float vvv;
    if (idx >= NC) vvv = (float)v_newc[(size_t)(idx - NC)*DIM + h*HD + lane];
    else           vvv = v_cache[(size_t)idx*DIM + h*HD + lane];
    va += pn * vvv;
  }
  __syncthreads();
  pacc[wv][lane] = va;
  __syncthreads();
  if (t < HD) {
    float o = pacc[0][t] + pacc[1][t] + pacc[2][t] + pacc[3][t]
            + pacc[4][t] + pacc[5][t] + pacc[6][t] + pacc[7][t];
    const float* wv2 = w2 + 3*DIM + h*HD + t;
    float dd = 0.f;
    for (int j = 0; j < INNER_D; j++) dd += tj[j] * wv2[(size_t)j*FF];
    pre_cls[(size_t)fb*DIM + h*HD + t] = (o + dd) * inv;
  }
}

// ---------------------------------------------------------------------------
// K9: out0 = h_cls + (sum_s partW) + bo;  yln = LN2(out0).  (12 slabs)
__launch_bounds__(256)
__global__ void reduce_wo_ln_kernel(const float* __restrict__ partW, const float* __restrict__ bo,
                                    const float* __restrict__ h_cls, const float* __restrict__ g,
                                    const float* __restrict__ b, float* __restrict__ out0,
                                    float* __restrict__ yln)
{
  int row = blockIdx.x, t = threadIdx.x;
  float v[3];
  #pragma unroll
  for (int j = 0; j < 3; j++) {
    int c = t + j*256;
    float s = h_cls[(size_t)row*DIM + c] + bo[c];
    #pragma unroll
    for (int ks = 0; ks < 12; ks++) s += partW[((size_t)ks*FB_N + row)*DIM + c];
    v[j] = s;
    out0[(size_t)row*DIM + c] = s;
  }
  float sm = wred_sum(v[0] + v[1] + v[2]);
  float sq = wred_sum(v[0]*v[0] + v[1]*v[1] + v[2]*v[2]);
  __shared__ float red[8];
  int wv = t >> 6, ln = t & 63;
  if (ln == 0) { red[wv] = sm; red[4 + wv] = sq; }
  __syncthreads();
  float mean = (red[0]+red[1]+red[2]+red[3]) * (1.f/DIM);
  float var  = (red[4]+red[5]+red[6]+red[7]) * (1.f/DIM) - mean*mean;
  float rr = rsqrtf(var + 1e-5f);
  #pragma unroll
  for (int j = 0; j < 3; j++) {
    int c = t + j*256;
    yln[(size_t)row*DIM + c] = (v[j] - mean) * rr * g[c] + b[c];
  }
}

// K10: t1 = quick_gelu(sum_s partF1 + fc1b)    (6 slabs)
__global__ void reduce_gelu_kernel(const float* __restrict__ partF1, const float* __restrict__ b1,
                                   float* __restrict__ t1)
{
  int i = blockIdx.x * 256 + threadIdx.x;   // < 196608
  int c = i % FF;
  float v = b1[c];
  #pragma unroll
  for (int s = 0; s < 6; s++) v += partF1[(size_t)s*FB_N*FF + i];
  t1[i] = v / (1.0f + __expf(-1.702f * v));
}

// K11: d_out = out0 + fc2_b + sum_s partF2     (24 slabs)
__global__ void final_reduce_kernel(const float* __restrict__ out0, const float* __restrict__ b2,
                                    const float* __restrict__ partF2, float* __restrict__ dout)
{
  int i = blockIdx.x * 256 + threadIdx.x;   // < 49152
  int c = i % DIM;
  float v = out0[i] + b2[c];
  #pragma unroll
  for (int s = 0; s < 24; s++) v += partF2[(size_t)s*FB_N*DIM + i];
  dout[i] = v;
}

// ---------------------------------------------------------------------------
extern "C" void kernel_launch(void* const* d_in, const int* in_sizes, int n_in,
                              void* d_out, int out_size, void* d_ws, size_t ws_size,
                              hipStream_t stream)
{
  const float* hs   = (const float*)d_in[0];
  const float* dpp  = (const float*)d_in[1];
  const float* hqkv = (const float*)d_in[2];
  const float* ln1g = (const float*)d_in[3];
  const float* ln1b = (const float*)d_in[4];
  const float* wq   = (const float*)d_in[5];
  const float* bq   = (const float*)d_in[6];
  const float* wk   = (const float*)d_in[7];
  const float* bk   = (const float*)d_in[8];
  const float* wvw  = (const float*)d_in[9];
  const float* bv   = (const float*)d_in[10];
  const float* w1   = (const float*)d_in[11];
  const float* w2   = (const float*)d_in[12];
  const float* wo   = (const float*)d_in[13];
  const float* bo   = (const float*)d_in[14];
  const float* ln2g = (const float*)d_in[15];
  const float* ln2b = (const float*)d_in[16];
  const float* fc1w = (const float*)d_in[17];
  const float* fc1b = (const float*)d_in[18];
  const float* fc2w = (const float*)d_in[19];
  const float* fc2b = (const float*)d_in[20];
  const int*   gidx = (const int*)d_in[21];
  const unsigned char* rmap = (const unsigned char*)d_in[22];
  float* outp = (float*)d_out;

  char* ws = (char*)d_ws;
  size_t off = 0;
  auto alloc = [&](size_t bytes) { void* p = ws + off; off += (bytes + 255) & ~(size_t)255; return p; };
  unsigned char* mask = (unsigned char*)alloc(TT);
  int* flag     = (int*)alloc((size_t)TT * 4);   // contiguous with mc: one memset
  int* mc       = (int*)alloc(256);              // mc[0]=fresh cnt, mc[1]=mask cnt, mc[2..3]=detect
  int* rowlist  = (int*)alloc((size_t)TT * 4);
  int* remap    = (int*)alloc((size_t)TT * 4);
  int* mrowlist = (int*)alloc((size_t)TT * 4);
  int* mremap   = (int*)alloc((size_t)TT * 4);
  __bf16* xbf    = (__bf16*)alloc((size_t)TT * DIM * 2);
  __bf16* wcatT  = (__bf16*)alloc((size_t)NCOLS * DIM * 2);
  __bf16* w1T    = (__bf16*)alloc((size_t)INNER_D * DIM * 2);
  __bf16* k_newc = (__bf16*)alloc((size_t)TT * DIM * 2);
  __bf16* v_newc = (__bf16*)alloc((size_t)TT * DIM * 2);
  float* partI   = (float*)alloc((size_t)6 * TT * INNER_D * 4);
  float* inner_c = (float*)alloc((size_t)TT * INNER_D * 4);
  float* h_cls  = (float*)alloc((size_t)FB_N * DIM * 4);
  float* qbase  = (float*)alloc((size_t)FB_N * DIM * 4);
  float* Xq     = (float*)alloc((size_t)FB_N * DIM * 4);
  float* q0s    = (float*)alloc((size_t)FB_N * DIM * 4);
  float* precls = (float*)alloc((size_t)FB_N * DIM * 4);
  float* out0   = (float*)alloc((size_t)FB_N * DIM * 4);
  float* yln    = (float*)alloc((size_t)FB_N * DIM * 4);
  float* t1     = (float*)alloc((size_t)FB_N * FF * 4);
  float* partQ  = (float*)alloc((size_t)12 * FB_N * DIM * 4);
  float* partW  = (float*)alloc((size_t)12 * FB_N * DIM * 4);
  float* partF1 = (float*)alloc((size_t)6  * FB_N * FF  * 4);
  float* partF2 = (float*)alloc((size_t)24 * FB_N * DIM * 4);
  (void)ws_size; (void)in_sizes; (void)n_in; (void)out_size;

  // zero flag + mc in one shot (contiguous allocations)
  hipMemsetAsync(flag, 0, (size_t)TT * 4 + 256, stream);
  detect_flag_kernel<<<(TT + 255) / 256, 256, 0, stream>>>(gidx, rmap, flag, mc + 2);
  scan_kernel<<<1, 1024, 0, stream>>>(flag, rmap, mc + 2, mask, rowlist, remap,
                                      mrowlist, mremap, mc);
  ln_kernel<<<TT, 256, 0, stream>>>(hs, ln1g, ln1b, xbf, rowlist, mc);
  transpose_w_kernel<<<dim3(24, 24, 2), dim3(32, 8), 0, stream>>>(wk, wvw, wcatT);
  transpose_w1_kernel<<<dim3(24, 2), dim3(32, 8), 0, stream>>>(w1, w1T);
  kv_gemm_kernel<<<1248, 256, 0, stream>>>(xbf, wcatT, bk, bv, k_newc, v_newc, mc);
  inner_gemm_kernel<<<dim3((TT + 63) / 64, 6), 256, 0, stream>>>(dpp, w1T, mrowlist, mc, partI);
  reduce_inner_kernel<<<(TT * INNER_D + 255) / 256, 256, 0, stream>>>(partI, mc, inner_c);
  cls_gather_kernel<<<FB_N, 256, 0, stream>>>(hs, hqkv, xbf, bq, w2, inner_c, gidx, mask,
                                              remap, mremap, h_cls, qbase, Xq);
  // q0s = (qbase + Xq @ wq) * SCALE   (zero Xq rows for cached fb's)
  pgemm_kernel<<<dim3(12, 12), 256, 0, stream>>>(Xq, wq, partQ, DIM, DIM, 64);
  reduce_q_kernel<<<192, 256, 0, stream>>>(qbase, partQ, q0s);
  attn_cls_kernel<<<FB_N * NH, 512, 0, stream>>>(hqkv, k_newc, v_newc, w2, inner_c, gidx, mask,
                                                 remap, mremap, q0s, precls);
  // out0 = h_cls + precls@wo + bo ; yln = LN2(out0)
  pgemm_kernel<<<dim3(12, 12), 256, 0, stream>>>(precls, wo, partW, DIM, DIM, 64);
  reduce_wo_ln_kernel<<<FB_N, 256, 0, stream>>>(partW, bo, h_cls, ln2g, ln2b, out0, yln);
  // t1 = qgelu(yln@fc1w + fc1b)
  pgemm_kernel<<<dim3(48, 6), 256, 0, stream>>>(yln, fc1w, partF1, FF, DIM, 128);
  reduce_gelu_kernel<<<768, 256, 0, stream>>>(partF1, fc1b, t1);
  // d_out = out0 + t1@fc2w + fc2b
  pgemm_kernel<<<dim3(12, 24), 256, 0, stream>>>(t1, fc2w, partF2, DIM, FF, 128);
  final_reduce_kernel<<<192, 256, 0, stream>>>(out0, fc2b, partF2, outp);
}